// Round 23
// baseline (479.137 us; speedup 1.0000x reference)
//
#include <hip/hip_runtime.h>
#include <hip/hip_bf16.h>
#include <math.h>

#define HW 65536
#define NPIX 262144

// ---- workspace layout (float offsets) ----
#define OFF_FFTW 0            // 64x64 spatial fft kernel
#define OFF_FLAG 4096         // 1
#define OFF_GSUM 4097         // 1    (zeroed in k0)
#define OFF_POOL 4098         // 128  (zeroed in k0)  -- pooled(loc) sums
#define OFF_GRAM 4226         // 1280 (zeroed in k0)
#define OFF_THR  5506         // 32   (written by k4a_red)
#define OFF_BAD  5538         // 1    (zeroed in k0)  -- k1 checker flag
#define OFF_A    5539         // 1024
#define OFF_CW   6563         // 128
#define OFF_QKVL 8192         // 96ch * 262144 px bf16 = 12582912 float-slots (SGSA phase)
#define OFF_MQKV 12591104     // 96*64 fp32 composed qkv matrix
#define OFF_MG1  (OFF_MQKV + 6144)     // 16*64 fp32  (ends 12598272)
#define OFF_MPRE 12598272     // 32*64 fp32 composed pre matrix (ends 12600320)
#define OFF_PREB 12600320     // [4][65536][32] bf16 px-major = 4194304 slots (ends 16794624)
#define OFF_LOCB 16794624     // [4][65536][32] bf16 px-major = 4194304 slots (ends 20988928)
#define OFF_PART 20988928     // 2048 blk * 4 waves * 4 g = 32768 (ends 21021696)
#define OFF_W96  21021696     // 64*96 fp32 composed out_proj|post matrix (SGSA phase only)
#define OFF_CB   (OFF_W96 + 6144)      // 64 fp32 (ends 21027904)
// bf16 weight tables (inside Z region, above SGSA max 21027904):
//  WK1/WB96 consumed in SGSA phase only (before any Z write, even in fallback).
//  WF5/WF6 consumed in MFFN only on identity path (flag==1 -> Z never written);
//  fallback path re-converts from fp32 sources, so Z-clobber is harmless.
#define OFF_WB96 21027904     // 64*96 bf16 = 3072 float-slots (ends 21030976)
#define OFF_WF5  21030976     // 256*64 bf16 = 8192 slots (ends 21039168)
#define OFF_WF6  21039168     // 64*128 bf16 = 4096 slots (ends 21043264)
#define OFF_WK1  21043264     // 176*64 bf16 = 5632 slots (ends 21048896 < 25174016)
// MFFN phase (per-batch, overlaps QKVL/PREB/LOCB/W96 which are dead by then):
#define OFF_T    8192                      // 256ch * 65536 bf16
#define OFF_Y    (OFF_T + 16777216)        // 128ch * 65536 bf16
#define OFF_Z    (OFF_Y + 4194304)         // 64ch * 65536 fp32
// peak ws usage = 25174016 floats = 100.7 MB (unchanged proven footprint)

typedef __attribute__((ext_vector_type(8))) short short8v;
typedef __attribute__((ext_vector_type(4))) float f32x4;

__device__ __forceinline__ float sigm(float v) { return 1.f / (1.f + expf(-v)); }
__device__ __forceinline__ float wredsum(float v) {
#pragma unroll
  for (int off = 32; off >= 1; off >>= 1) v += __shfl_xor(v, off);
  return v;
}
__device__ __forceinline__ unsigned short f2bf(float f) {
  union { float f; unsigned u; } x; x.f = f;
  unsigned r = x.u + 0x7fffu + ((x.u >> 16) & 1u);
  return (unsigned short)(r >> 16);
}
__device__ __forceinline__ float bf2f(unsigned short u) {
  union { unsigned u; float f; } x; x.u = ((unsigned)u) << 16;
  return x.f;
}

// ---------------- K0: zero accumulators + fft kernel + composed matrices + bf16 tables ----------------
__global__ __launch_bounds__(256) void k0_setup(
    const float* __restrict__ fft_W, const float* __restrict__ in_proj_w,
    const float* __restrict__ qkv_w, const float* __restrict__ g1w,
    const float* __restrict__ pre_w, const float* __restrict__ out_proj_w,
    const float* __restrict__ post_w, const float* __restrict__ post_b,
    const float* __restrict__ ffn_in_w, const float* __restrict__ ffn_out_w,
    float* __restrict__ ws)
{
  __shared__ float ct8[8];
  __shared__ int sbad;
  const int tid = threadIdx.x;
  if (tid < 8) ct8[tid] = cosf((float)tid * 0.78539816339744831f); // cos(k*pi/4)
  if (tid == 0) sbad = 0;
  for (int i = tid; i < 1442; i += 256) ws[OFF_GSUM + i] = 0.f;    // gsum,pool,gram,thr,bad
  for (int i = tid; i < 96 * 64; i += 256) {
    int o = i >> 6, c = i & 63;
    float s = 0.f;
    for (int j = 0; j < 32; ++j) s += qkv_w[o * 32 + j] * in_proj_w[(32 + j) * 64 + c];
    ws[OFF_MQKV + i] = s;
  }
  for (int i = tid; i < 16 * 64; i += 256) {
    int o = i >> 6, c = i & 63;
    float s = 0.f;
    for (int j = 0; j < 32; ++j) s += g1w[o * 32 + j] * in_proj_w[(32 + j) * 64 + c];
    ws[OFF_MG1 + i] = s;
  }
  for (int i = tid; i < 32 * 64; i += 256) {
    int o = i >> 6, c = i & 63;
    float s = 0.f;
    for (int j = 0; j < 32; ++j) s += pre_w[o * 32 + j] * in_proj_w[j * 64 + c];
    ws[OFF_MPRE + i] = s;
  }
  for (int i = tid; i < 64 * 96; i += 256) {
    int o = i / 96, c = i - o * 96;
    float s;
    if (c < 32) s = out_proj_w[o * 64 + c];
    else if (c < 64) {
      s = 0.f;
      for (int k = 0; k < 32; ++k) s += out_proj_w[o * 64 + 32 + k] * post_w[k * 32 + (c - 32)];
    } else s = out_proj_w[o * 64 + (c - 32)];
    ws[OFF_W96 + i] = s;
  }
  for (int i = tid; i < 64; i += 256) {
    float s = 0.f;
    for (int k = 0; k < 32; ++k) s += out_proj_w[i * 64 + 32 + k] * post_b[k];
    ws[OFF_CB + i] = s;
  }
  __syncthreads();   // composed matrices ready
  // ---- bf16 weight tables ----
  {
    unsigned short* wk1 = (unsigned short*)(ws + OFF_WK1);
    for (int i = tid; i < 176 * 64; i += 256) {
      int o = i >> 6, c = i & 63;
      float v = (o < 32) ? in_proj_w[o * 64 + c]
              : (o < 128) ? ws[OFF_MQKV + (o - 32) * 64 + c]
              : (o < 160) ? ws[OFF_MPRE + (o - 128) * 64 + c]
                          : ws[OFF_MG1 + (o - 160) * 64 + c];
      wk1[i] = f2bf(v);
    }
    unsigned short* wb96 = (unsigned short*)(ws + OFF_WB96);
    for (int i = tid; i < 64 * 96; i += 256) wb96[i] = f2bf(ws[OFF_W96 + i]);
    unsigned short* wf5 = (unsigned short*)(ws + OFF_WF5);
    for (int i = tid; i < 256 * 64; i += 256) wf5[i] = f2bf(ffn_in_w[i]);
    unsigned short* wf6 = (unsigned short*)(ws + OFF_WF6);
    for (int i = tid; i < 64 * 128; i += 256) wf6[i] = f2bf(ffn_out_w[i]);
  }
  bool ok = true;
  for (int i = tid; i < 64 * 64; i += 256) {
    int ch = i >> 6, ab = i & 63;
    int a = ab >> 3, b2 = ab & 7;
    float s = 0.f;
    for (int u = 0; u < 8; ++u)
      for (int v = 0; v < 8; ++v) {
        float Wf;
        if (v == 0 || v == 4)
          Wf = 0.5f * (fft_W[ch * 40 + u * 5 + v] + fft_W[ch * 40 + ((8 - u) & 7) * 5 + v]);
        else if (v < 5)
          Wf = fft_W[ch * 40 + u * 5 + v];
        else
          Wf = fft_W[ch * 40 + ((8 - u) & 7) * 5 + (8 - v)];
        s += Wf * ct8[(u * a + v * b2) & 7];
      }
    s *= (1.f / 64.f);
    ws[OFF_FFTW + i] = s;
    float expect = ((i & 63) == 0) ? 1.f : 0.f;
    if (fabsf(s - expect) > 1e-4f) ok = false;
  }
  if (!ok) atomicOr(&sbad, 1);
  __syncthreads();
  if (tid == 0) ws[OFF_FLAG] = sbad ? 0.f : 1.f;
}

// ---------------- K1 (MFMA, 128px blocks, gate via MFMA tile 10, bf16 weight table) ----------------
__global__ __launch_bounds__(256) void k1_mfma(
    const float* __restrict__ x, const float* __restrict__ ln1_w, const float* __restrict__ ln1_b,
    const unsigned short* __restrict__ wk1, const float* __restrict__ pre_b,
    const float* __restrict__ g1b, const float* __restrict__ g2w, const float* __restrict__ g2b,
    unsigned short* __restrict__ qkvl, unsigned short* __restrict__ LOCB,
    unsigned short* __restrict__ PREB, float* __restrict__ pooled, float* __restrict__ gsum)
{
  __shared__ unsigned short sXnb[128][68];   // 17.4 KB
  __shared__ unsigned short sStg[4][16][68]; // 8.7 KB
  __shared__ float sGateH[16][65];           // 4.2 KB  fp32 gate h staging
  __shared__ float sPoolL[32];
  const int tid = threadIdx.x;
  const int p0 = blockIdx.x * 128;
  const int b = p0 >> 16;
  const int hw0 = p0 & (HW - 1);
  if (tid < 32) sPoolL[tid] = 0.f;
  // ---- Phase A: register LN, float4 loads ----
  {
    const int px4 = tid >> 3;
    const int e8 = tid & 7;
    const float* xb = x + (size_t)(b * 64 + e8 * 8) * HW + hw0 + px4 * 4;
    float xv[8][4];
    float mu[4] = {0.f, 0.f, 0.f, 0.f};
#pragma unroll
    for (int j = 0; j < 8; ++j) {
      float4 v = *reinterpret_cast<const float4*>(xb + (size_t)j * HW);
      xv[j][0] = v.x; xv[j][1] = v.y; xv[j][2] = v.z; xv[j][3] = v.w;
      mu[0] += v.x; mu[1] += v.y; mu[2] += v.z; mu[3] += v.w;
    }
#pragma unroll
    for (int p = 0; p < 4; ++p) {
      mu[p] += __shfl_xor(mu[p], 1);
      mu[p] += __shfl_xor(mu[p], 2);
      mu[p] += __shfl_xor(mu[p], 4);
      mu[p] *= (1.f / 64.f);
    }
    float var[4] = {0.f, 0.f, 0.f, 0.f};
#pragma unroll
    for (int j = 0; j < 8; ++j)
#pragma unroll
      for (int p = 0; p < 4; ++p) {
        float d = xv[j][p] - mu[p];
        var[p] += d * d;
      }
    float rs[4];
#pragma unroll
    for (int p = 0; p < 4; ++p) {
      var[p] += __shfl_xor(var[p], 1);
      var[p] += __shfl_xor(var[p], 2);
      var[p] += __shfl_xor(var[p], 4);
      rs[p] = rsqrtf(var[p] * (1.f / 64.f) + 1e-5f);
    }
    float lw[8], lb[8];
#pragma unroll
    for (int j = 0; j < 8; ++j) { lw[j] = ln1_w[e8 * 8 + j]; lb[j] = ln1_b[e8 * 8 + j]; }
#pragma unroll
    for (int p = 0; p < 4; ++p) {
      union { short8v v; unsigned short s[8]; } u;
#pragma unroll
      for (int j = 0; j < 8; ++j)
        u.s[j] = f2bf((xv[j][p] - mu[p]) * rs[p] * lw[j] + lb[j]);
      *reinterpret_cast<short8v*>(&sXnb[px4 * 4 + p][e8 * 8]) = u.v;
    }
  }
  __syncthreads();
  const int w = tid >> 6, lane = tid & 63;
  const int col = lane & 15, kgrp = lane >> 4;
  float gateAcc = 0.f;
#pragma unroll
  for (int pass = 0; pass < 3; ++pass) {
    const int tile = pass * 4 + w;
    if (tile >= 11) continue;                 // wave-uniform
    const int og = tile * 16 + col;           // 0..175
    const unsigned short* wr = wk1 + og * 64;
    union { short8v v; unsigned short s[8]; } bw[2];
#pragma unroll
    for (int kk = 0; kk < 2; ++kk)
      bw[kk].v = *reinterpret_cast<const short8v*>(wr + kk * 32 + kgrp * 8);
    const float bias = (og >= 128 && og < 160) ? pre_b[og - 128] : 0.f;
    float poolAcc = 0.f;
#pragma unroll
    for (int pxsub = 0; pxsub < 2; ++pxsub) {
      f32x4 acc[4];
#pragma unroll
      for (int s = 0; s < 4; ++s) acc[s] = (f32x4){0.f, 0.f, 0.f, 0.f};
#pragma unroll
      for (int kk = 0; kk < 2; ++kk) {
        const int c0 = kk * 32 + kgrp * 8;
#pragma unroll
        for (int s = 0; s < 4; ++s) {
          short8v av = *reinterpret_cast<const short8v*>(&sXnb[pxsub * 64 + s * 16 + col][c0]);
          acc[s] = __builtin_amdgcn_mfma_f32_16x16x32_bf16(av, bw[kk].v, acc[s], 0, 0, 0);
        }
      }
      if (tile == 10) {
        const float gb = g1b[col];
#pragma unroll
        for (int s = 0; s < 4; ++s)
#pragma unroll
          for (int r = 0; r < 4; ++r)
            sGateH[col][s * 16 + kgrp * 4 + r] = acc[s][r] + gb;
        float gacc = g2b[0];
#pragma unroll
        for (int i = 0; i < 16; ++i)
          gacc += g2w[i] * fmaxf(sGateH[i][lane], 0.f);
        gateAcc += sigm(gacc);
      } else {
#pragma unroll
        for (int s = 0; s < 4; ++s) {
#pragma unroll
          for (int r = 0; r < 4; ++r) {
            float v = acc[s][r] + bias;
            sStg[w][col][s * 16 + kgrp * 4 + r] = f2bf(v);
            if (og < 32) poolAcc += v;
          }
        }
        if (og >= 32 && og < 128) {
          const int row = lane >> 2, seg = lane & 3;
          const unsigned short* src = &sStg[w][row][seg * 16];
          unsigned short* dst = qkvl + (size_t)(b * 96 + (tile - 2) * 16 + row) * HW
                                + hw0 + pxsub * 64 + seg * 16;
          *reinterpret_cast<short8v*>(dst) = *reinterpret_cast<const short8v*>(src);
          *reinterpret_cast<short8v*>(dst + 8) = *reinterpret_cast<const short8v*>(src + 8);
        } else {
          const int pxl = lane;
          union { short8v v; unsigned short s[8]; } u0, u1;
#pragma unroll
          for (int o = 0; o < 8; ++o) { u0.s[o] = sStg[w][o][pxl]; u1.s[o] = sStg[w][8 + o][pxl]; }
          unsigned short* base = (og < 32) ? LOCB : PREB;
          const int choff = (og < 32) ? (tile * 16) : ((tile - 8) * 16);
          unsigned short* dst = base + ((size_t)b * HW + hw0 + pxsub * 64 + pxl) * 32 + choff;
          *reinterpret_cast<short8v*>(dst) = u0.v;
          *reinterpret_cast<short8v*>(dst + 8) = u1.v;
        }
      }
    }
    if (og < 32) {
      poolAcc += __shfl_xor(poolAcc, 16);
      poolAcc += __shfl_xor(poolAcc, 32);
      if (kgrp == 0) sPoolL[og] = poolAcc;
    }
  }
  if (w == 2) {
    float gv = wredsum(gateAcc);
    if (lane == 0) atomicAdd(gsum, gv);
  }
  __syncthreads();
  if (tid < 32) atomicAdd(&pooled[b * 32 + tid], sPoolL[tid]);
}

// ---------------- K1 checker (parallel): 256 blocks x 1 sampled px ----------------
__global__ __launch_bounds__(256) void k1_check(
    const float* __restrict__ x, const float* __restrict__ ln1_w, const float* __restrict__ ln1_b,
    const float* __restrict__ in_proj_w, const float* __restrict__ qkv_w,
    const float* __restrict__ pre_w, const float* __restrict__ pre_b,
    const unsigned short* __restrict__ LOCB, const unsigned short* __restrict__ qkvl,
    const unsigned short* __restrict__ PREB, float* __restrict__ bad)
{
  __shared__ float sXv[64];
  __shared__ float sLc[32], sGl[32];
  const int blk = blockIdx.x;
  const int b = blk & 3;
  const int px = (blk * 1031) & (HW - 1);
  const int tid = threadIdx.x;
  if (tid < 64) sXv[tid] = x[(size_t)(b * 64 + tid) * HW + px];
  __syncthreads();
  if (tid < 64) {
    float v = sXv[tid];
    float mu = wredsum(v) * (1.f / 64.f);
    float d = v - mu;
    float var = wredsum(d * d) * (1.f / 64.f);
    float rs = rsqrtf(var + 1e-5f);
    sXv[tid] = d * rs * ln1_w[tid] + ln1_b[tid];
  }
  __syncthreads();
  if (tid < 64) {
    const int o = tid & 31;
    const int hi = tid >> 5;
    float s = 0.f;
#pragma unroll
    for (int c = 0; c < 64; ++c) s += in_proj_w[(hi * 32 + o) * 64 + c] * sXv[c];
    if (hi) sGl[o] = s; else sLc[o] = s;
  }
  __syncthreads();
  bool fail = false;
  if (tid < 32) {
    float s = sLc[tid];
    float got = bf2f(LOCB[((size_t)b * HW + px) * 32 + tid]);
    if (fabsf(got - s) > 0.05f + 0.05f * fabsf(s)) fail = true;
  } else if (tid < 128) {
    const int o = tid - 32;
    float s = 0.f;
#pragma unroll
    for (int j = 0; j < 32; ++j) s += qkv_w[o * 32 + j] * sGl[j];
    float got = bf2f(qkvl[(size_t)(b * 96 + o) * HW + px]);
    if (fabsf(got - s) > 0.05f + 0.05f * fabsf(s)) fail = true;
  } else if (tid < 160) {
    const int o = tid - 128;
    float s = pre_b[o];
#pragma unroll
    for (int j = 0; j < 32; ++j) s += pre_w[o * 32 + j] * sLc[j];
    float got = bf2f(PREB[((size_t)b * HW + px) * 32 + o]);
    if (fabsf(got - s) > 0.05f + 0.05f * fabsf(s)) fail = true;
  }
  if (fail) atomicExch(bad, 1.f);
}

// ---------------- K1 reset (only if checker failed) ----------------
__global__ __launch_bounds__(256) void k1r_reset(const float* __restrict__ bad, float* __restrict__ gsum)
{
  if (bad[0] < 0.5f) return;
  const int tid = threadIdx.x;
  if (tid < 129) gsum[tid] = 0.f;
}

// ---------------- K1 fallback (only if checker failed) ----------------
__global__ __launch_bounds__(256) void k1_fb(
    const float* __restrict__ x, const float* __restrict__ ln1_w, const float* __restrict__ ln1_b,
    const float* __restrict__ in_proj_w, const float* __restrict__ qkv_w,
    const float* __restrict__ pre_w, const float* __restrict__ pre_b,
    const float* __restrict__ g1w, const float* __restrict__ g1b,
    const float* __restrict__ g2w, const float* __restrict__ g2b,
    const float* __restrict__ bad,
    unsigned short* __restrict__ qkvl, unsigned short* __restrict__ LOCB,
    unsigned short* __restrict__ PREB, float* __restrict__ pooled, float* __restrict__ gsum)
{
  if (bad[0] < 0.5f) return;
  __shared__ float sPool[4][32];
  __shared__ float sRed[4];
  const int tid = threadIdx.x;
  const int p = blockIdx.x * 256 + tid;
  const int b = p >> 16;
  const int hw = p & (HW - 1);
  const int wave = tid >> 6, lane = tid & 63;
  const float* xb = x + (size_t)(b * 64) * HW + hw;
  float xv[64];
  float mu = 0.f;
#pragma unroll
  for (int c = 0; c < 64; ++c) { xv[c] = xb[(size_t)c * HW]; mu += xv[c]; }
  mu *= (1.f / 64.f);
  float var = 0.f;
#pragma unroll
  for (int c = 0; c < 64; ++c) { float d = xv[c] - mu; var += d * d; }
  var *= (1.f / 64.f);
  const float rs = rsqrtf(var + 1e-5f);
#pragma unroll
  for (int c = 0; c < 64; ++c) xv[c] = (xv[c] - mu) * rs * ln1_w[c] + ln1_b[c];
  float loc[32];
  for (int o = 0; o < 32; ++o) {
    float s = 0.f;
#pragma unroll
    for (int c = 0; c < 64; ++c) s += in_proj_w[o * 64 + c] * xv[c];
    loc[o] = s;
    LOCB[((size_t)b * HW + hw) * 32 + o] = f2bf(s);
    float r = wredsum(s);
    if (lane == 0) sPool[wave][o] = r;
  }
  for (int o = 0; o < 32; ++o) {
    float s = pre_b[o];
#pragma unroll
    for (int j = 0; j < 32; ++j) s += pre_w[o * 32 + j] * loc[j];
    PREB[((size_t)b * HW + hw) * 32 + o] = f2bf(s);
  }
  float gl[32];
  for (int o = 0; o < 32; ++o) {
    float s = 0.f;
#pragma unroll
    for (int c = 0; c < 64; ++c) s += in_proj_w[(32 + o) * 64 + c] * xv[c];
    gl[o] = s;
  }
  for (int o = 0; o < 96; ++o) {
    float s = 0.f;
#pragma unroll
    for (int j = 0; j < 32; ++j) s += qkv_w[o * 32 + j] * gl[j];
    qkvl[(size_t)(b * 96 + o) * HW + hw] = f2bf(s);
  }
  float gacc = g2b[0];
  for (int o = 0; o < 16; ++o) {
    float h = g1b[o];
#pragma unroll
    for (int j = 0; j < 32; ++j) h += g1w[o * 32 + j] * gl[j];
    gacc += g2w[o] * fmaxf(h, 0.f);
  }
  float gv = wredsum(sigm(gacc));
  if (lane == 0) sRed[wave] = gv;
  __syncthreads();
  if (tid == 0) atomicAdd(gsum, sRed[0] + sRed[1] + sRed[2] + sRed[3]);
  if (tid < 32) {
    float s = sPool[0][tid] + sPool[1][tid] + sPool[2][tid] + sPool[3][tid];
    atomicAdd(&pooled[b * 32 + tid], s);
  }
}

// ---------------- K2 (MFMA): dwconv(q,k) + Gram via V·V^T — vectorized row loads ----------------
__global__ __launch_bounds__(256) void k2_mfma(
    const unsigned short* __restrict__ qkvl, const float* __restrict__ qkv_dw, float* __restrict__ gram)
{
  __shared__ float sred[4][256];
  const int tid = threadIdx.x;
  const int slab = blockIdx.x;
  const int h = blockIdx.y, b = blockIdx.z;
  const int w = tid >> 6, lane = tid & 63;
  const int ch = lane & 15, grp = lane >> 4;
  const int gch = (ch < 8) ? (h * 8 + ch) : (32 + h * 8 + (ch - 8));
  const unsigned short* plane = qkvl + (size_t)(b * 96 + gch) * HW;
  const float* wt = qkv_dw + gch * 9;
  float w9[9];
#pragma unroll
  for (int t = 0; t < 9; ++t) w9[t] = wt[t];
  f32x4 acc = (f32x4){0.f, 0.f, 0.f, 0.f};
#pragma unroll
  for (int iter = 0; iter < 4; ++iter) {
    const int pxbase = slab * 512 + w * 128 + iter * 32 + grp * 8;
    const int y = pxbase >> 8;
    const int x0 = pxbase & 255;
    float row[3][10];
#pragma unroll
    for (int dy = 0; dy < 3; ++dy) {
      const int yy = y + dy - 1;
      if ((unsigned)yy >= 256u) {
#pragma unroll
        for (int j = 0; j < 10; ++j) row[dy][j] = 0.f;
        continue;
      }
      const unsigned short* rp = plane + yy * 256;
      union { short8v v; unsigned short s[8]; } cu;
      cu.v = *reinterpret_cast<const short8v*>(rp + x0);
#pragma unroll
      for (int j = 0; j < 8; ++j) row[dy][j + 1] = bf2f(cu.s[j]);
      row[dy][0] = (x0 > 0) ? bf2f(rp[x0 - 1]) : 0.f;
      row[dy][9] = (x0 < 248) ? bf2f(rp[x0 + 8]) : 0.f;
    }
    union { short8v v; unsigned short s[8]; } frag;
#pragma unroll
    for (int j = 0; j < 8; ++j) {
      float a = 0.f;
#pragma unroll
      for (int dy = 0; dy < 3; ++dy)
#pragma unroll
        for (int dx = 0; dx < 3; ++dx)
          a += row[dy][j + dx] * w9[dy * 3 + dx];
      frag.s[j] = f2bf(a);
    }
    acc = __builtin_amdgcn_mfma_f32_16x16x32_bf16(frag.v, frag.v, acc, 0, 0, 0);
  }
#pragma unroll
  for (int r = 0; r < 4; ++r) sred[w][(grp * 4 + r) * 16 + ch] = acc[r];
  __syncthreads();
  if (tid < 256) {
    float g = sred[0][tid] + sred[1][tid] + sred[2][tid] + sred[3][tid];
    const int row_ = tid >> 4, col_ = tid & 15;
    int idx = -1;
    if (row_ < 8 && col_ >= 8) idx = row_ * 8 + (col_ - 8);
    else if (row_ == col_ && row_ < 8) idx = 64 + row_;
    else if (row_ == col_) idx = 72 + (row_ - 8);
    if (idx >= 0) atomicAdd(&gram[(b * 4 + h) * 80 + idx], g);
  }
}

// ---------------- K3: dk, CBAM weights, attention matrices ----------------
__global__ __launch_bounds__(256) void k3_final(
    const float* __restrict__ m1w, const float* __restrict__ m1b,
    const float* __restrict__ m2w, const float* __restrict__ m2b,
    const float* __restrict__ temperature, const float* __restrict__ attn_scales,
    const float* __restrict__ pre_w, const float* __restrict__ pre_b,
    const float* __restrict__ gsum, const float* __restrict__ pooled,
    const float* __restrict__ gram, float* __restrict__ Abuf, float* __restrict__ cwbuf)
{
  __shared__ int s_dk;
  __shared__ float s_scale;
  const int tid = threadIdx.x;
  if (tid == 0) {
    float gmean = gsum[0] / (float)NPIX;
    int dk = (int)floorf(8.f * gmean);
    if (dk < 1) dk = 1;
    if (dk > 8) dk = 8;
    s_dk = dk;
    s_scale = attn_scales[0] + attn_scales[1] + attn_scales[2] + attn_scales[3];
  }
  __syncthreads();
  if (tid < 128) {
    int b = tid >> 5, ch = tid & 31, g = ch >> 2, c = ch & 3;
    float h1 = m1b[g];
#pragma unroll
    for (int cc = 0; cc < 4; ++cc) {
      int row = g * 4 + cc;
      float pp = pre_b[row];
#pragma unroll
      for (int j = 0; j < 32; ++j)
        pp += pre_w[row * 32 + j] * (pooled[b * 32 + j] * (1.f / 65536.f));
      h1 += pp * m1w[g * 4 + cc];
    }
    h1 = fmaxf(h1, 0.f);
    cwbuf[tid] = sigm(h1 * m2w[g * 4 + c] + m2b[g * 4 + c]);

    int r = tid, h = (r >> 3) & 3, c8 = r & 7;
    const float* gm = gram + (b * 4 + h) * 80;
    float qn = fmaxf(sqrtf(gm[64 + c8]), 1e-12f);
    float temp = temperature[h];
    float a[8];
#pragma unroll
    for (int d = 0; d < 8; ++d) {
      float kn = fmaxf(sqrtf(gm[72 + d]), 1e-12f);
      a[d] = gm[c8 * 8 + d] / (qn * kn) * temp;
    }
    float t[8];
#pragma unroll
    for (int d = 0; d < 8; ++d) t[d] = a[d];
#pragma unroll
    for (int i = 0; i < 8; ++i)
#pragma unroll
      for (int j = 0; j < 8; ++j)
        if (j > i && t[j] > t[i]) { float tmp = t[i]; t[i] = t[j]; t[j] = tmp; }
    float kth = t[s_dk - 1];
    float mx = t[0];
    float e[8]; float sum = 0.f;
#pragma unroll
    for (int d = 0; d < 8; ++d) {
      e[d] = (a[d] >= kth) ? expf(a[d] - mx) : 0.f;
      sum += e[d];
    }
    float inv = s_scale / sum;
#pragma unroll
    for (int d = 0; d < 8; ++d) Abuf[r * 8 + d] = e[d] * inv;
  }
}

// ---------------- K4a: resp partial sums (atomic-free), PREB bf16 ----------------
__global__ __launch_bounds__(256) void k4a_thr(
    const float* __restrict__ spw, const float* __restrict__ spb,
    const float* __restrict__ cwbuf, const unsigned short* __restrict__ PREB,
    float* __restrict__ wpart)
{
  const int tid = threadIdx.x;
  const int pxb = blockIdx.x >> 1;
  const int gh = blockIdx.x & 1;
  const int px = pxb * 256 + tid;
  const int b = px >> 16, hw = px & (HW - 1);
  const int w = tid >> 6, lane = tid & 63;
  const float* cw = cwbuf + b * 32;
  const unsigned short* pp = PREB + ((size_t)b * HW + hw) * 32 + gh * 16;
  union { short8v v; unsigned short s[8]; } u0, u1;
  u0.v = *reinterpret_cast<const short8v*>(pp);
  u1.v = *reinterpret_cast<const short8v*>(pp + 8);
  float pv[16];
#pragma unroll
  for (int k = 0; k < 8; ++k) { pv[k] = bf2f(u0.s[k]); pv[8 + k] = bf2f(u1.s[k]); }
  float racc[4];
#pragma unroll
  for (int g4 = 0; g4 < 4; ++g4) {
    const int g = gh * 4 + g4;
    float xa[4];
    float sdot = spb[g];
#pragma unroll
    for (int c = 0; c < 4; ++c) {
      xa[c] = pv[g4 * 4 + c] * cw[g * 4 + c];
      sdot += xa[c] * spw[g * 4 + c];
    }
    float sgv = sigm(sdot);
    float r = 0.f;
#pragma unroll
    for (int c = 0; c < 4; ++c) r += sigm(xa[c] * sgv);
    racc[g4] = r;
  }
#pragma unroll
  for (int g4 = 0; g4 < 4; ++g4) {
    float v = wredsum(racc[g4]);
    if (lane == 0) wpart[(blockIdx.x * 4 + w) * 4 + g4] = v;
  }
}

// ---------------- K4a_red: reduce wpart -> thrbuf ----------------
__global__ __launch_bounds__(256) void k4a_red(
    const float* __restrict__ wpart, float* __restrict__ thrbuf)
{
  __shared__ float sr[256];
  const int tid = threadIdx.x;
  const int b = blockIdx.x >> 3, g = blockIdx.x & 7;
  const int gh = g >> 2, gl = g & 3;
  float s = 0.f;
#pragma unroll
  for (int w = 0; w < 4; ++w)
    s += wpart[((((size_t)(b * 256 + tid) * 2 + gh) * 4) + w) * 4 + gl];
  sr[tid] = s;
  __syncthreads();
  for (int st = 128; st >= 1; st >>= 1) {
    if (tid < st) sr[tid] += sr[tid + st];
    __syncthreads();
  }
  if (tid == 0) thrbuf[b * 8 + g] = sr[0];
}

// ---------------- K4b (MFMA): V-dwconv + LGCE finish + attn -> A96 MFMA (bf16 W96 table) ----------------
__global__ __launch_bounds__(256) void k4b_fuse(
    const float* __restrict__ x, const float* __restrict__ spw, const float* __restrict__ spb,
    const float* __restrict__ qkv_dw, const unsigned short* __restrict__ qkvl,
    const unsigned short* __restrict__ LOCB, const unsigned short* __restrict__ PREB,
    const float* __restrict__ Abuf, const float* __restrict__ cwbuf, const float* __restrict__ thrbuf,
    const unsigned short* __restrict__ wb96, const float* __restrict__ cb,
    float* __restrict__ dout)
{
  __shared__ float sV[64][33];
  __shared__ unsigned short sA[64][104];
  __shared__ float sOut[64][65];
  const int tid = threadIdx.x;
  const int p0 = blockIdx.x * 64;
  const int b = p0 >> 16;
  const int hw0 = p0 & (HW - 1);
  const int yrow = hw0 >> 8;
  const int x0b = hw0 & 255;
  {
    const int j = tid >> 3;
    const int seg = tid & 7;
    const int x0 = x0b + seg * 8;
    const unsigned short* plane = qkvl + (size_t)(b * 96 + 64 + j) * HW;
    const float* wt = qkv_dw + (64 + j) * 9;
    float w9[9];
#pragma unroll
    for (int t = 0; t < 9; ++t) w9[t] = wt[t];
    float row[3][10];
#pragma unroll
    for (int dy = 0; dy < 3; ++dy) {
      const int yy = yrow + dy - 1;
      if ((unsigned)yy >= 256u) {
#pragma unroll
        for (int k = 0; k < 10; ++k) row[dy][k] = 0.f;
        continue;
      }
      const unsigned short* rp = plane + yy * 256;
      union { short8v v; unsigned short s[8]; } cu;
      cu.v = *reinterpret_cast<const short8v*>(rp + x0);
#pragma unroll
      for (int k = 0; k < 8; ++k) row[dy][k + 1] = bf2f(cu.s[k]);
      row[dy][0] = (x0 > 0) ? bf2f(rp[x0 - 1]) : 0.f;
      row[dy][9] = (x0 < 248) ? bf2f(rp[x0 + 8]) : 0.f;
    }
#pragma unroll
    for (int p = 0; p < 8; ++p) {
      float s = 0.f;
#pragma unroll
      for (int dy = 0; dy < 3; ++dy)
#pragma unroll
        for (int dx = 0; dx < 3; ++dx)
          s += row[dy][p + dx] * w9[dy * 3 + dx];
      sV[seg * 8 + p][j] = s;
    }
  }
  __syncthreads();
  const int px_l = tid & 63, q = tid >> 6;
  const int hw = hw0 + px_l;
  const float* cw = cwbuf + b * 32;
  const float* A = Abuf + b * 256;
  union { short8v v; unsigned short s[8]; } lv, pvv;
  lv.v = *reinterpret_cast<const short8v*>(LOCB + ((size_t)b * HW + hw) * 32 + q * 8);
  pvv.v = *reinterpret_cast<const short8v*>(PREB + ((size_t)b * HW + hw) * 32 + q * 8);
  float pre8[8];
#pragma unroll
  for (int j = 0; j < 8; ++j) pre8[j] = bf2f(pvv.s[j]);
  union { short8v v; unsigned short s[8]; } mxv;
#pragma unroll
  for (int g2 = 0; g2 < 2; ++g2) {
    const int g = 2 * q + g2;
    float xa[4];
    float sdot = spb[g];
#pragma unroll
    for (int c = 0; c < 4; ++c) {
      xa[c] = pre8[g2 * 4 + c] * cw[g * 4 + c];
      sdot += xa[c] * spw[g * 4 + c];
    }
    float sgv = sigm(sdot);
    float thr = thrbuf[b * 8 + g] * (1.f / (4.f * 65536.f));
#pragma unroll
    for (int c = 0; c < 4; ++c) {
      float resp = sigm(xa[c] * sgv);
      float m = (resp > thr) ? 1.f : resp;
      mxv.s[g2 * 4 + c] = f2bf(pre8[g2 * 4 + c] * m);
    }
  }
  float v8[8];
#pragma unroll
  for (int j = 0; j < 8; ++j) v8[j] = sV[px_l][q * 8 + j];
  union { short8v v; unsigned short s[8]; } attv;
#pragma unroll
  for (int j = 0; j < 8; ++j) {
    float s = 0.f;
#pragma unroll
    for (int d = 0; d < 8; ++d) s += A[(q * 8 + j) * 8 + d] * v8[d];
    attv.s[j] = f2bf(s);
  }
  *reinterpret_cast<short8v*>(&sA[px_l][q * 8]) = attv.v;
  *reinterpret_cast<short8v*>(&sA[px_l][32 + q * 8]) = mxv.v;
  *reinterpret_cast<short8v*>(&sA[px_l][64 + q * 8]) = lv.v;
  __syncthreads();
  const int w = q, lane = tid & 63;
  const int col = lane & 15, kgrp = lane >> 4;
  const int og = w * 16 + col;
  f32x4 acc[4];
#pragma unroll
  for (int s = 0; s < 4; ++s) acc[s] = (f32x4){0.f, 0.f, 0.f, 0.f};
#pragma unroll
  for (int kk = 0; kk < 3; ++kk) {
    const int c0 = kk * 32 + kgrp * 8;
    union { short8v v; unsigned short s[8]; } bw;
    bw.v = *reinterpret_cast<const short8v*>(wb96 + og * 96 + c0);
#pragma unroll
    for (int s = 0; s < 4; ++s) {
      short8v av = *reinterpret_cast<const short8v*>(&sA[s * 16 + col][c0]);
      acc[s] = __builtin_amdgcn_mfma_f32_16x16x32_bf16(av, bw.v, acc[s], 0, 0, 0);
    }
  }
#pragma unroll
  for (int s = 0; s < 4; ++s) {
#pragma unroll
    for (int r = 0; r < 4; ++r) {
      int pxl = s * 16 + kgrp * 4 + r;
      sOut[og][pxl] = acc[s][r];
    }
  }
  __syncthreads();
  const float* xb = x + (size_t)(b * 64) * HW + hw0;
  float* db = dout + (size_t)(b * 64) * HW + hw0;
#pragma unroll
  for (int i = 0; i < 16; ++i) {
    int idx = tid + i * 256;
    int o = idx >> 6, px = idx & 63;
    db[(size_t)o * HW + px] = sOut[o][px] + cb[o] + xb[(size_t)o * HW + px];
  }
}

// ---------------- K5 (MFMA): LN2 + ffn_in (64->256), bf16 weight table on identity path ----------------
__global__ __launch_bounds__(256) void k5_mfma(
    const float* __restrict__ ln2_w, const float* __restrict__ ln2_b,
    const float* __restrict__ ffn_in_w, const unsigned short* __restrict__ wf5,
    const float* __restrict__ flag, const float* __restrict__ dout,
    unsigned short* __restrict__ Tb, int b)
{
  __shared__ float sShared[4352];            // sStage (fp32), later reused as sOutB (bf16, 128 rows)
  __shared__ unsigned short sXnb[64][68];
  __shared__ float sMu[64], sRs[64];
  float (*sStage)[65] = reinterpret_cast<float(*)[65]>(sShared);
  unsigned short (*sOutB)[68] = reinterpret_cast<unsigned short(*)[68]>(sShared);
  const int tid = threadIdx.x;
  const int px0 = blockIdx.x * 64;
  const bool idf = flag[0] > 0.5f;
  const float* db = dout + (size_t)(b * 64) * HW + px0;
#pragma unroll
  for (int i = 0; i < 4; ++i) {
    int idx = tid + i * 256;                 // 0..1023
    int c = idx >> 4, px4 = (idx & 15) * 4;
    float4 v = *reinterpret_cast<const float4*>(db + (size_t)c * HW + px4);
    sStage[px4][c] = v.x;
    sStage[px4 + 1][c] = v.y;
    sStage[px4 + 2][c] = v.z;
    sStage[px4 + 3][c] = v.w;
  }
  __syncthreads();
  if (tid < 64) {
    float mu = 0.f;
#pragma unroll
    for (int c = 0; c < 64; ++c) mu += sStage[tid][c];
    mu *= (1.f / 64.f);
    float var = 0.f;
#pragma unroll
    for (int c = 0; c < 64; ++c) { float d = sStage[tid][c] - mu; var += d * d; }
    var *= (1.f / 64.f);
    sMu[tid] = mu;
    sRs[tid] = rsqrtf(var + 1e-5f);
  }
  __syncthreads();
#pragma unroll
  for (int i = 0; i < 16; ++i) {
    int idx = tid + i * 256;
    int px = idx >> 6, c = idx & 63;
    float xn = (sStage[px][c] - sMu[px]) * sRs[px] * ln2_w[c] + ln2_b[c];
    sXnb[px][c] = f2bf(xn);
  }
  __syncthreads();   // sStage dead; sOutB takes over the region
  const int w = tid >> 6, lane = tid & 63;
  const int col = lane & 15, kgrp = lane >> 4;
#pragma unroll
  for (int mp = 0; mp < 2; ++mp) {
#pragma unroll
    for (int pass = 0; pass < 2; ++pass) {
      const int o_l = pass * 64 + w * 16 + col;   // 0..127 within macro-pass
      const int og = mp * 128 + o_l;
      f32x4 acc[4];
#pragma unroll
      for (int s = 0; s < 4; ++s) acc[s] = (f32x4){0.f, 0.f, 0.f, 0.f};
#pragma unroll
      for (int kk = 0; kk < 2; ++kk) {
        const int c0 = kk * 32 + kgrp * 8;
        union { short8v v; unsigned short s[8]; } bw;
        if (idf) {
          bw.v = *reinterpret_cast<const short8v*>(wf5 + (size_t)og * 64 + c0);
        } else {
          const float* wp = ffn_in_w + (size_t)og * 64 + c0;
#pragma unroll
          for (int j = 0; j < 8; ++j) bw.s[j] = f2bf(wp[j]);
        }
#pragma unroll
        for (int s = 0; s < 4; ++s) {
          short8v av = *reinterpret_cast<const short8v*>(&sXnb[s * 16 + col][c0]);
          acc[s] = __builtin_amdgcn_mfma_f32_16x16x32_bf16(av, bw.v, acc[s], 0, 0, 0);
        }
      }
#pragma unroll
      for (int s = 0; s < 4; ++s) {
#pragma unroll
        for (int r = 0; r < 4; ++r) {
          int px_l = s * 16 + kgrp * 4 + r;
          sOutB[o_l][px_l] = f2bf(acc[s][r]);
        }
      }
    }
    __syncthreads();
    for (int i = tid; i < 1024; i += 256) {
      int o = i >> 3, seg = i & 7;
      *reinterpret_cast<short8v*>(Tb + (size_t)(mp * 128 + o) * HW + px0 + seg * 8) =
          *reinterpret_cast<const short8v*>(&sOutB[o][seg * 8]);
    }
    __syncthreads();   // before next macro-pass overwrites sOutB
  }
}

// ---------------- K6a: dwconv3/dwconv5 + gelu*mul -> Y (bf16), 1 ch x 2 rows per thread ----------------
__global__ __launch_bounds__(256) void k6a_dw(
    const float* __restrict__ dw3_w, const float* __restrict__ dw5_w,
    const unsigned short* __restrict__ T, unsigned short* __restrict__ Y)
{
  const int idx = blockIdx.x * 256 + threadIdx.x;  // 524288 threads (grid 2048)
  const int j = idx >> 12;          // channel 0..127 (wave-uniform)
  const int rem = idx & 4095;
  const int y0 = (rem >> 5) * 2;    // output row pair base 0,2,..,254
  const int x0 = (rem & 31) * 8;    // col start, multiple of 8
  float m[2][8];
  const unsigned short* pm = T + (size_t)(128 + j) * HW;
  if (j < 64) {
    const float* wt = dw3_w + (128 + j) * 9;
    float w9[9];
#pragma unroll
    for (int t = 0; t < 9; ++t) w9[t] = wt[t];
    float row[4][10];
#pragma unroll
    for (int r = 0; r < 4; ++r) {
      const int yy = y0 + r - 1;
      if ((unsigned)yy >= 256u) {
#pragma unroll
        for (int k = 0; k < 10; ++k) row[r][k] = 0.f;
        continue;
      }
      const unsigned short* rp = pm + yy * 256;
      union { short8v v; unsigned short s[8]; } cu;
      cu.v = *reinterpret_cast<const short8v*>(rp + x0);
#pragma unroll
      for (int k = 0; k < 8; ++k) row[r][k + 1] = bf2f(cu.s[k]);
      row[r][0] = (x0 > 0) ? bf2f(rp[x0 - 1]) : 0.f;
      row[r][9] = (x0 < 248) ? bf2f(rp[x0 + 8]) : 0.f;
    }
#pragma unroll
    for (int t = 0; t < 2; ++t)
#pragma unroll
      for (int p = 0; p < 8; ++p) {
        float s = 0.f;
#pragma unroll
        for (int dy = 0; dy < 3; ++dy)
#pragma unroll
          for (int dx = 0; dx < 3; ++dx)
            s += row[t + dy][p + dx] * w9[dy * 3 + dx];
        m[t][p] = s;
      }
  } else {
    const float* wt = dw5_w + (j - 64) * 25;
    float w25[25];
#pragma unroll
    for (int t = 0; t < 25; ++t) w25[t] = wt[t];
    float row[6][12];
#pragma unroll
    for (int r = 0; r < 6; ++r) {
      const int yy = y0 + r - 2;
      if ((unsigned)yy >= 256u) {
#pragma unroll
        for (int k = 0; k < 12; ++k) row[r][k] = 0.f;
        continue;
      }
      const unsigned short* rp = pm + yy * 256;
      union { short8v v; unsigned short s[8]; } cu;
      cu.v = *reinterpret_cast<const short8v*>(rp + x0);
#pragma unroll
      for (int k = 0; k < 8; ++k) row[r][k + 2] = bf2f(cu.s[k]);
      row[r][0] = (x0 > 0) ? bf2f(rp[x0 - 2]) : 0.f;
      row[r][1] = (x0 > 0) ? bf2f(rp[x0 - 1]) : 0.f;
      row[r][10] = (x0 < 248) ? bf2f(rp[x0 + 8]) : 0.f;
      row[r][11] = (x0 < 248) ? bf2f(rp[x0 + 9]) : 0.f;
    }
#pragma unroll
    for (int t = 0; t < 2; ++t)
#pragma unroll
      for (int p = 0; p < 8; ++p) {
        float s = 0.f;
#pragma unroll
        for (int dy = 0; dy < 5; ++dy)
#pragma unroll
          for (int dx = 0; dx < 5; ++dx)
            s += row[t + dy][p + dx] * w25[dy * 5 + dx];
        m[t][p] = s;
      }
  }
  float a[2][8];
  {
    const unsigned short* pa = T + (size_t)j * HW;
    const float* wt = dw3_w + j * 9;
    float w9[9];
#pragma unroll
    for (int t = 0; t < 9; ++t) w9[t] = wt[t];
    float row[4][10];
#pragma unroll
    for (int r = 0; r < 4; ++r) {
      const int yy = y0 + r - 1;
      if ((unsigned)yy >= 256u) {
#pragma unroll
        for (int k = 0; k < 10; ++k) row[r][k] = 0.f;
        continue;
      }
      const unsigned short* rp = pa + yy * 256;
      union { short8v v; unsigned short s[8]; } cu;
      cu.v = *reinterpret_cast<const short8v*>(rp + x0);
#pragma unroll
      for (int k = 0; k < 8; ++k) row[r][k + 1] = bf2f(cu.s[k]);
      row[r][0] = (x0 > 0) ? bf2f(rp[x0 - 1]) : 0.f;
      row[r][9] = (x0 < 248) ? bf2f(rp[x0 + 8]) : 0.f;
    }
#pragma unroll
    for (int t = 0; t < 2; ++t)
#pragma unroll
      for (int p = 0; p < 8; ++p) {
        float s = 0.f;
#pragma unroll
        for (int dy = 0; dy < 3; ++dy)
#pragma unroll
          for (int dx = 0; dx < 3; ++dx)
            s += row[t + dy][p + dx] * w9[dy * 3 + dx];
        a[t][p] = s;
      }
  }
#pragma unroll
  for (int t = 0; t < 2; ++t) {
    union { short8v v; unsigned short s[8]; } out;
#pragma unroll
    for (int p = 0; p < 8; ++p) {
      float gl = 0.5f * a[t][p] * (1.f + erff(a[t][p] * 0.70710678118654752f));
      out.s[p] = f2bf(gl * m[t][p]);
    }
    *reinterpret_cast<short8v*>(Y + (size_t)j * HW + (y0 + t) * 256 + x0) = out.v;
  }
}

// ---------------- K6b (MFMA): ffn_out (128->64), Y staged once in LDS, K=128 ----------------
__global__ __launch_bounds__(256) void k6b_mfma(
    const float* __restrict__ ffn_out_w, const unsigned short* __restrict__ wf6,
    const unsigned short* __restrict__ Y,
    const float* __restrict__ flag, float* __restrict__ dout, float* __restrict__ Z, int b)
{
  __shared__ unsigned short sY[64][136];   // 17.4 KB [px][128ch]
  __shared__ float sOut[64][65];           // 16.6 KB
  const int tid = threadIdx.x;
  const int px0 = blockIdx.x * 64;
  const bool idf = flag[0] > 0.5f;
#pragma unroll
  for (int i = 0; i < 4; ++i) {
    const int t = tid + i * 256;
    const int ch = t >> 3, seg = t & 7;
    union { short8v v; unsigned short s[8]; } u;
    u.v = *reinterpret_cast<const short8v*>(Y + (size_t)ch * HW + px0 + seg * 8);
#pragma unroll
    for (int p = 0; p < 8; ++p) sY[seg * 8 + p][ch] = u.s[p];
  }
  __syncthreads();
  const int w = tid >> 6, lane = tid & 63;
  const int col = lane & 15, kgrp = lane >> 4;
  const int og = w * 16 + col;               // 0..63
  f32x4 acc[4];
#pragma unroll
  for (int s = 0; s < 4; ++s) acc[s] = (f32x4){0.f, 0.f, 0.f, 0.f};
#pragma unroll
  for (int kk = 0; kk < 4; ++kk) {
    const int c0 = kk * 32 + kgrp * 8;
    union { short8v v; unsigned short s[8]; } bw;
    if (idf) {
      bw.v = *reinterpret_cast<const short8v*>(wf6 + (size_t)og * 128 + c0);
    } else {
      const float* wp = ffn_out_w + (size_t)og * 128 + c0;
#pragma unroll
      for (int j = 0; j < 8; ++j) bw.s[j] = f2bf(wp[j]);
    }
#pragma unroll
    for (int s = 0; s < 4; ++s) {
      short8v av = *reinterpret_cast<const short8v*>(&sY[s * 16 + col][c0]);
      acc[s] = __builtin_amdgcn_mfma_f32_16x16x32_bf16(av, bw.v, acc[s], 0, 0, 0);
    }
  }
#pragma unroll
  for (int s = 0; s < 4; ++s) {
#pragma unroll
    for (int r = 0; r < 4; ++r) {
      int pxl = s * 16 + kgrp * 4 + r;
      sOut[og][pxl] = acc[s][r];
    }
  }
  __syncthreads();
  if (idf) {
    float* db = dout + (size_t)(b * 64) * HW + px0;
#pragma unroll
    for (int i = 0; i < 16; ++i) {
      int idx = tid + i * 256;
      int o = idx >> 6, px = idx & 63;
      db[(size_t)o * HW + px] += sOut[o][px];
    }
  } else {
    float* zb = Z + px0;
#pragma unroll
    for (int i = 0; i < 16; ++i) {
      int idx = tid + i * 256;
      int o = idx >> 6, px = idx & 63;
      zb[(size_t)o * HW + px] = sOut[o][px];
    }
  }
}

// ---------------- K7: general fft path, 8 patch-groups per block (early-exit if identity) ----------------
__global__ __launch_bounds__(256) void k7_fft(
    const float* __restrict__ fftw, const float* __restrict__ flag,
    const float* __restrict__ Z, float* __restrict__ dout, int b)
{
  if (flag[0] > 0.5f) return;
  __shared__ float swv[64];
  __shared__ float spatch[4][64];
  const int tid = threadIdx.x;
  const int c = blockIdx.x >> 5;        // channel 0..63 (grid 2048)
  const int pblk0 = (blockIdx.x & 31) * 8;
  if (tid < 64) swv[tid] = fftw[c * 64 + tid];
  const int lp = tid >> 6, e = tid & 63;
  const int i = e >> 3, jj = e & 7;
  for (int pg = 0; pg < 8; ++pg) {
    const int patch = (pblk0 + pg) * 4 + lp;
    const int pi = patch >> 5, pj = patch & 31;
    const int gidx = (pi * 8 + i) * 256 + pj * 8 + jj;
    const float zv = Z[(size_t)c * HW + gidx];
    spatch[lp][e] = zv;
    __syncthreads();
    float s = 0.f;
#pragma unroll
    for (int a = 0; a < 8; ++a)
#pragma unroll
      for (int b2 = 0; b2 < 8; ++b2)
        s += swv[a * 8 + b2] * spatch[lp][((i - a) & 7) * 8 + ((jj - b2) & 7)];
    dout[(size_t)(b * 64 + c) * HW + gidx] += s;
    __syncthreads();
  }
}

extern "C" void kernel_launch(void* const* d_in, const int* in_sizes, int n_in,
                              void* d_out, int out_size, void* d_ws, size_t ws_size,
                              hipStream_t stream) {
  const float* x          = (const float*)d_in[0];
  const float* ln1_w      = (const float*)d_in[1];
  const float* ln1_b      = (const float*)d_in[2];
  const float* in_proj_w  = (const float*)d_in[3];
  const float* qkv_w      = (const float*)d_in[4];
  const float* qkv_dw     = (const float*)d_in[5];
  const float* out_proj_w = (const float*)d_in[6];
  const float* temperature= (const float*)d_in[7];
  const float* attn_scales= (const float*)d_in[8];
  const float* gate_w1    = (const float*)d_in[9];
  const float* gate_b1    = (const float*)d_in[10];
  const float* gate_w2    = (const float*)d_in[11];
  const float* gate_b2    = (const float*)d_in[12];
  const float* lgce_pre_w = (const float*)d_in[13];
  const float* lgce_pre_b = (const float*)d_in[14];
  const float* lgce_post_w= (const float*)d_in[15];
  const float* lgce_post_b= (const float*)d_in[16];
  const float* cbam_m1w   = (const float*)d_in[17];
  const float* cbam_m1b   = (const float*)d_in[18];
  const float* cbam_m2w   = (const float*)d_in[19];
  const float* cbam_m2b   = (const float*)d_in[20];
  const float* cbam_spw   = (const float*)d_in[21];
  const float* cbam_spb   = (const float*)d_in[22];
  const float* ln2_w      = (const float*)d_in[23];
  const float* ln2_b      = (const float*)d_in[24];
  const float* ffn_in_w   = (const float*)d_in[25];
  const float* dw3_w      = (const float*)d_in[26];
  const float* dw5_w      = (const float*)d_in[27];
  const float* ffn_out_w  = (const float*)d_in[28];
  const float* fft_W      = (const float*)d_in[29];
  float* ws = (float*)d_ws;
  float* out = (float*)d_out;
  unsigned short* qkvlp = (unsigned short*)(ws + OFF_QKVL);
  unsigned short* LOCB = (unsigned short*)(ws + OFF_LOCB);
  unsigned short* PREB = (unsigned short*)(ws + OFF_PREB);
  unsigned short* Tb = (unsigned short*)(ws + OFF_T);
  unsigned short* Ybuf = (unsigned short*)(ws + OFF_Y);

  hipLaunchKernelGGL(k0_setup, dim3(1), dim3(256), 0, stream,
                     fft_W, in_proj_w, qkv_w, gate_w1, lgce_pre_w,
                     out_proj_w, lgce_post_w, lgce_post_b, ffn_in_w, ffn_out_w, ws);
  hipLaunchKernelGGL(k1_mfma, dim3(2048), dim3(256), 0, stream,
                     x, ln1_w, ln1_b, (unsigned short*)(ws + OFF_WK1), lgce_pre_b,
                     gate_b1, gate_w2, gate_b2,
                     qkvlp, LOCB, PREB, ws + OFF_POOL, ws + OFF_GSUM);
  hipLaunchKernelGGL(k1_check, dim3(256), dim3(256), 0, stream,
                     x, ln1_w, ln1_b, in_proj_w, qkv_w, lgce_pre_w, lgce_pre_b,
                     LOCB, qkvlp, PREB, ws + OFF_BAD);
  hipLaunchKernelGGL(k1r_reset, dim3(1), dim3(256), 0, stream,
                     ws + OFF_BAD, ws + OFF_GSUM);
  hipLaunchKernelGGL(k1_fb, dim3(1024), dim3(256), 0, stream,
                     x, ln1_w, ln1_b, in_proj_w, qkv_w, lgce_pre_w, lgce_pre_b,
                     gate_w1, gate_b1, gate_w2, gate_b2,
                     ws + OFF_BAD, qkvlp, LOCB, PREB, ws + OFF_POOL, ws + OFF_GSUM);
  hipLaunchKernelGGL(k2_mfma, dim3(128, 4, 4), dim3(256), 0, stream,
                     qkvlp, qkv_dw, ws + OFF_GRAM);
  hipLaunchKernelGGL(k3_final, dim3(1), dim3(256), 0, stream,
                     cbam_m1w, cbam_m1b, cbam_m2w, cbam_m2b, temperature, attn_scales,
                     lgce_pre_w, lgce_pre_b,
                     ws + OFF_GSUM, ws + OFF_POOL, ws + OFF_GRAM, ws + OFF_A, ws + OFF_CW);
  hipLaunchKernelGGL(k4a_thr, dim3(2048), dim3(256), 0, stream,
                     cbam_spw, cbam_spb, ws + OFF_CW, PREB, ws + OFF_PART);
  hipLaunchKernelGGL(k4a_red, dim3(32), dim3(256), 0, stream,
                     ws + OFF_PART, ws + OFF_THR);
  hipLaunchKernelGGL(k4b_fuse, dim3(4096), dim3(256), 0, stream,
                     x, cbam_spw, cbam_spb, qkv_dw, qkvlp, LOCB, PREB,
                     ws + OFF_A, ws + OFF_CW, ws + OFF_THR,
                     (unsigned short*)(ws + OFF_WB96), ws + OFF_CB, out);

  for (int b = 0; b < 4; ++b) {
    hipLaunchKernelGGL(k5_mfma, dim3(1024), dim3(256), 0, stream,
                       ln2_w, ln2_b, ffn_in_w, (unsigned short*)(ws + OFF_WF5),
                       ws + OFF_FLAG, out, Tb, b);
    hipLaunchKernelGGL(k6a_dw, dim3(2048), dim3(256), 0, stream,
                       dw3_w, dw5_w, Tb, Ybuf);
    hipLaunchKernelGGL(k6b_mfma, dim3(1024), dim3(256), 0, stream,
                       ffn_out_w, (unsigned short*)(ws + OFF_WF6), Ybuf,
                       ws + OFF_FLAG, out, ws + OFF_Z, b);
    hipLaunchKernelGGL(k7_fft, dim3(2048), dim3(256), 0, stream,
                       ws + OFF_FFTW, ws + OFF_FLAG, ws + OFF_Z, out, b);
  }
}

// Round 24
// 456.503 us; speedup vs baseline: 1.0496x; 1.0496x over previous
//
#include <hip/hip_runtime.h>
#include <hip/hip_bf16.h>
#include <math.h>

#define HW 65536
#define NPIX 262144

// ---- workspace layout (float offsets) ----
#define OFF_FFTW 0            // 64x64 spatial fft kernel
#define OFF_FLAG 4096         // 1
#define OFF_GSUM 4097         // 1    (zeroed in k0)
#define OFF_POOL 4098         // 128  (zeroed in k0)  -- pooled(loc) sums
#define OFF_GRAM 4226         // 1280 (zeroed in k0)
#define OFF_THR  5506         // 32   (written by k4a_red)
#define OFF_BAD  5538         // 1    (zeroed in k0)  -- k1 checker flag
#define OFF_A    5539         // 1024
#define OFF_CW   6563         // 128
#define OFF_QKVL 8192         // 96ch * 262144 px bf16 = 12582912 float-slots (SGSA phase)
#define OFF_MQKV 12591104     // 96*64 fp32 composed qkv matrix
#define OFF_MG1  (OFF_MQKV + 6144)     // 16*64 fp32  (ends 12598272)
#define OFF_MPRE 12598272     // 32*64 fp32 composed pre matrix (ends 12600320)
#define OFF_PREB 12600320     // [4][65536][32] bf16 px-major = 4194304 slots (ends 16794624)
#define OFF_LOCB 16794624     // [4][65536][32] bf16 px-major = 4194304 slots (ends 20988928)
#define OFF_PART 20988928     // 2048 blk * 4 waves * 4 g = 32768 (ends 21021696)
#define OFF_W96  21021696     // 64*96 fp32 composed out_proj|post matrix (SGSA phase only)
#define OFF_CB   (OFF_W96 + 6144)      // 64 fp32 (ends 21027904)
// bf16 weight tables (inside Z region, above SGSA max 21027904):
//  WK1/WB96 consumed in SGSA phase only (before any Z write, even in fallback).
//  WF5/WF6 consumed in MFFN only on identity path (flag==1 -> Z never written);
//  fallback path re-converts from fp32 sources, so Z-clobber is harmless.
#define OFF_WB96 21027904     // 64*96 bf16 = 3072 float-slots (ends 21030976)
#define OFF_WF5  21030976     // 256*64 bf16 = 8192 slots (ends 21039168)
#define OFF_WF6  21039168     // 64*128 bf16 = 4096 slots (ends 21043264)
#define OFF_WK1  21043264     // 176*64 bf16 = 5632 slots (ends 21048896 < 25174016)
// MFFN phase (per-batch, overlaps QKVL/PREB/LOCB/W96 which are dead by then):
#define OFF_T    8192                      // 256ch * 65536 bf16
#define OFF_Y    (OFF_T + 16777216)        // 128ch * 65536 bf16
#define OFF_Z    (OFF_Y + 4194304)         // 64ch * 65536 fp32
// peak ws usage = 25174016 floats = 100.7 MB (unchanged proven footprint)

typedef __attribute__((ext_vector_type(8))) short short8v;
typedef __attribute__((ext_vector_type(4))) float f32x4;

__device__ __forceinline__ float sigm(float v) { return 1.f / (1.f + expf(-v)); }
__device__ __forceinline__ float wredsum(float v) {
#pragma unroll
  for (int off = 32; off >= 1; off >>= 1) v += __shfl_xor(v, off);
  return v;
}
__device__ __forceinline__ unsigned short f2bf(float f) {
  union { float f; unsigned u; } x; x.f = f;
  unsigned r = x.u + 0x7fffu + ((x.u >> 16) & 1u);
  return (unsigned short)(r >> 16);
}
__device__ __forceinline__ float bf2f(unsigned short u) {
  union { unsigned u; float f; } x; x.u = ((unsigned)u) << 16;
  return x.f;
}

// ---------------- K0: zero accumulators + fft kernel + composed matrices ----------------
__global__ __launch_bounds__(256) void k0_setup(
    const float* __restrict__ fft_W, const float* __restrict__ in_proj_w,
    const float* __restrict__ qkv_w, const float* __restrict__ g1w,
    const float* __restrict__ pre_w, const float* __restrict__ out_proj_w,
    const float* __restrict__ post_w, const float* __restrict__ post_b,
    float* __restrict__ ws)
{
  __shared__ float ct8[8];
  __shared__ int sbad;
  const int tid = threadIdx.x;
  if (tid < 8) ct8[tid] = cosf((float)tid * 0.78539816339744831f); // cos(k*pi/4)
  if (tid == 0) sbad = 0;
  for (int i = tid; i < 1442; i += 256) ws[OFF_GSUM + i] = 0.f;    // gsum,pool,gram,thr,bad
  for (int i = tid; i < 96 * 64; i += 256) {
    int o = i >> 6, c = i & 63;
    float s = 0.f;
    for (int j = 0; j < 32; ++j) s += qkv_w[o * 32 + j] * in_proj_w[(32 + j) * 64 + c];
    ws[OFF_MQKV + i] = s;
  }
  for (int i = tid; i < 16 * 64; i += 256) {
    int o = i >> 6, c = i & 63;
    float s = 0.f;
    for (int j = 0; j < 32; ++j) s += g1w[o * 32 + j] * in_proj_w[(32 + j) * 64 + c];
    ws[OFF_MG1 + i] = s;
  }
  for (int i = tid; i < 32 * 64; i += 256) {
    int o = i >> 6, c = i & 63;
    float s = 0.f;
    for (int j = 0; j < 32; ++j) s += pre_w[o * 32 + j] * in_proj_w[j * 64 + c];
    ws[OFF_MPRE + i] = s;
  }
  for (int i = tid; i < 64 * 96; i += 256) {
    int o = i / 96, c = i - o * 96;
    float s;
    if (c < 32) s = out_proj_w[o * 64 + c];
    else if (c < 64) {
      s = 0.f;
      for (int k = 0; k < 32; ++k) s += out_proj_w[o * 64 + 32 + k] * post_w[k * 32 + (c - 32)];
    } else s = out_proj_w[o * 64 + (c - 32)];
    ws[OFF_W96 + i] = s;
  }
  for (int i = tid; i < 64; i += 256) {
    float s = 0.f;
    for (int k = 0; k < 32; ++k) s += out_proj_w[i * 64 + 32 + k] * post_b[k];
    ws[OFF_CB + i] = s;
  }
  __syncthreads();
  bool ok = true;
  for (int i = tid; i < 64 * 64; i += 256) {
    int ch = i >> 6, ab = i & 63;
    int a = ab >> 3, b2 = ab & 7;
    float s = 0.f;
    for (int u = 0; u < 8; ++u)
      for (int v = 0; v < 8; ++v) {
        float Wf;
        if (v == 0 || v == 4)
          Wf = 0.5f * (fft_W[ch * 40 + u * 5 + v] + fft_W[ch * 40 + ((8 - u) & 7) * 5 + v]);
        else if (v < 5)
          Wf = fft_W[ch * 40 + u * 5 + v];
        else
          Wf = fft_W[ch * 40 + ((8 - u) & 7) * 5 + (8 - v)];
        s += Wf * ct8[(u * a + v * b2) & 7];
      }
    s *= (1.f / 64.f);
    ws[OFF_FFTW + i] = s;
    float expect = ((i & 63) == 0) ? 1.f : 0.f;
    if (fabsf(s - expect) > 1e-4f) ok = false;
  }
  if (!ok) atomicOr(&sbad, 1);
  __syncthreads();
  if (tid == 0) ws[OFF_FLAG] = sbad ? 0.f : 1.f;
}

// ---------------- K0b: bf16 weight tables (parallel, 164x256 = 41984 elements) ----------------
__global__ __launch_bounds__(256) void k0b_tables(
    const float* __restrict__ in_proj_w, const float* __restrict__ ffn_in_w,
    const float* __restrict__ ffn_out_w, float* __restrict__ ws)
{
  const int idx = blockIdx.x * 256 + threadIdx.x;
  if (idx < 11264) {                       // WK1: 176x64
    int o = idx >> 6, c = idx & 63;
    float v = (o < 32) ? in_proj_w[o * 64 + c]
            : (o < 128) ? ws[OFF_MQKV + (o - 32) * 64 + c]
            : (o < 160) ? ws[OFF_MPRE + (o - 128) * 64 + c]
                        : ws[OFF_MG1 + (o - 160) * 64 + c];
    ((unsigned short*)(ws + OFF_WK1))[idx] = f2bf(v);
  } else if (idx < 11264 + 6144) {         // WB96: 64x96
    int i = idx - 11264;
    ((unsigned short*)(ws + OFF_WB96))[i] = f2bf(ws[OFF_W96 + i]);
  } else if (idx < 11264 + 6144 + 16384) { // WF5: 256x64
    int i = idx - 11264 - 6144;
    ((unsigned short*)(ws + OFF_WF5))[i] = f2bf(ffn_in_w[i]);
  } else {                                 // WF6: 64x128
    int i = idx - 11264 - 6144 - 16384;
    ((unsigned short*)(ws + OFF_WF6))[i] = f2bf(ffn_out_w[i]);
  }
}

// ---------------- K1 (MFMA, 128px blocks, gate via MFMA tile 10, bf16 weight table) ----------------
__global__ __launch_bounds__(256) void k1_mfma(
    const float* __restrict__ x, const float* __restrict__ ln1_w, const float* __restrict__ ln1_b,
    const unsigned short* __restrict__ wk1, const float* __restrict__ pre_b,
    const float* __restrict__ g1b, const float* __restrict__ g2w, const float* __restrict__ g2b,
    unsigned short* __restrict__ qkvl, unsigned short* __restrict__ LOCB,
    unsigned short* __restrict__ PREB, float* __restrict__ pooled, float* __restrict__ gsum)
{
  __shared__ unsigned short sXnb[128][68];   // 17.4 KB
  __shared__ unsigned short sStg[4][16][68]; // 8.7 KB
  __shared__ float sGateH[16][65];           // 4.2 KB  fp32 gate h staging
  __shared__ float sPoolL[32];
  const int tid = threadIdx.x;
  const int p0 = blockIdx.x * 128;
  const int b = p0 >> 16;
  const int hw0 = p0 & (HW - 1);
  if (tid < 32) sPoolL[tid] = 0.f;
  // ---- Phase A: register LN, float4 loads ----
  {
    const int px4 = tid >> 3;
    const int e8 = tid & 7;
    const float* xb = x + (size_t)(b * 64 + e8 * 8) * HW + hw0 + px4 * 4;
    float xv[8][4];
    float mu[4] = {0.f, 0.f, 0.f, 0.f};
#pragma unroll
    for (int j = 0; j < 8; ++j) {
      float4 v = *reinterpret_cast<const float4*>(xb + (size_t)j * HW);
      xv[j][0] = v.x; xv[j][1] = v.y; xv[j][2] = v.z; xv[j][3] = v.w;
      mu[0] += v.x; mu[1] += v.y; mu[2] += v.z; mu[3] += v.w;
    }
#pragma unroll
    for (int p = 0; p < 4; ++p) {
      mu[p] += __shfl_xor(mu[p], 1);
      mu[p] += __shfl_xor(mu[p], 2);
      mu[p] += __shfl_xor(mu[p], 4);
      mu[p] *= (1.f / 64.f);
    }
    float var[4] = {0.f, 0.f, 0.f, 0.f};
#pragma unroll
    for (int j = 0; j < 8; ++j)
#pragma unroll
      for (int p = 0; p < 4; ++p) {
        float d = xv[j][p] - mu[p];
        var[p] += d * d;
      }
    float rs[4];
#pragma unroll
    for (int p = 0; p < 4; ++p) {
      var[p] += __shfl_xor(var[p], 1);
      var[p] += __shfl_xor(var[p], 2);
      var[p] += __shfl_xor(var[p], 4);
      rs[p] = rsqrtf(var[p] * (1.f / 64.f) + 1e-5f);
    }
    float lw[8], lb[8];
#pragma unroll
    for (int j = 0; j < 8; ++j) { lw[j] = ln1_w[e8 * 8 + j]; lb[j] = ln1_b[e8 * 8 + j]; }
#pragma unroll
    for (int p = 0; p < 4; ++p) {
      union { short8v v; unsigned short s[8]; } u;
#pragma unroll
      for (int j = 0; j < 8; ++j)
        u.s[j] = f2bf((xv[j][p] - mu[p]) * rs[p] * lw[j] + lb[j]);
      *reinterpret_cast<short8v*>(&sXnb[px4 * 4 + p][e8 * 8]) = u.v;
    }
  }
  __syncthreads();
  const int w = tid >> 6, lane = tid & 63;
  const int col = lane & 15, kgrp = lane >> 4;
  float gateAcc = 0.f;
#pragma unroll
  for (int pass = 0; pass < 3; ++pass) {
    const int tile = pass * 4 + w;
    if (tile >= 11) continue;                 // wave-uniform
    const int og = tile * 16 + col;           // 0..175
    const unsigned short* wr = wk1 + og * 64;
    union { short8v v; unsigned short s[8]; } bw[2];
#pragma unroll
    for (int kk = 0; kk < 2; ++kk)
      bw[kk].v = *reinterpret_cast<const short8v*>(wr + kk * 32 + kgrp * 8);
    const float bias = (og >= 128 && og < 160) ? pre_b[og - 128] : 0.f;
    float poolAcc = 0.f;
#pragma unroll
    for (int pxsub = 0; pxsub < 2; ++pxsub) {
      f32x4 acc[4];
#pragma unroll
      for (int s = 0; s < 4; ++s) acc[s] = (f32x4){0.f, 0.f, 0.f, 0.f};
#pragma unroll
      for (int kk = 0; kk < 2; ++kk) {
        const int c0 = kk * 32 + kgrp * 8;
#pragma unroll
        for (int s = 0; s < 4; ++s) {
          short8v av = *reinterpret_cast<const short8v*>(&sXnb[pxsub * 64 + s * 16 + col][c0]);
          acc[s] = __builtin_amdgcn_mfma_f32_16x16x32_bf16(av, bw[kk].v, acc[s], 0, 0, 0);
        }
      }
      if (tile == 10) {
        const float gb = g1b[col];
#pragma unroll
        for (int s = 0; s < 4; ++s)
#pragma unroll
          for (int r = 0; r < 4; ++r)
            sGateH[col][s * 16 + kgrp * 4 + r] = acc[s][r] + gb;
        float gacc = g2b[0];
#pragma unroll
        for (int i = 0; i < 16; ++i)
          gacc += g2w[i] * fmaxf(sGateH[i][lane], 0.f);
        gateAcc += sigm(gacc);
      } else {
#pragma unroll
        for (int s = 0; s < 4; ++s) {
#pragma unroll
          for (int r = 0; r < 4; ++r) {
            float v = acc[s][r] + bias;
            sStg[w][col][s * 16 + kgrp * 4 + r] = f2bf(v);
            if (og < 32) poolAcc += v;
          }
        }
        if (og >= 32 && og < 128) {
          const int row = lane >> 2, seg = lane & 3;
          const unsigned short* src = &sStg[w][row][seg * 16];
          unsigned short* dst = qkvl + (size_t)(b * 96 + (tile - 2) * 16 + row) * HW
                                + hw0 + pxsub * 64 + seg * 16;
          *reinterpret_cast<short8v*>(dst) = *reinterpret_cast<const short8v*>(src);
          *reinterpret_cast<short8v*>(dst + 8) = *reinterpret_cast<const short8v*>(src + 8);
        } else {
          const int pxl = lane;
          union { short8v v; unsigned short s[8]; } u0, u1;
#pragma unroll
          for (int o = 0; o < 8; ++o) { u0.s[o] = sStg[w][o][pxl]; u1.s[o] = sStg[w][8 + o][pxl]; }
          unsigned short* base = (og < 32) ? LOCB : PREB;
          const int choff = (og < 32) ? (tile * 16) : ((tile - 8) * 16);
          unsigned short* dst = base + ((size_t)b * HW + hw0 + pxsub * 64 + pxl) * 32 + choff;
          *reinterpret_cast<short8v*>(dst) = u0.v;
          *reinterpret_cast<short8v*>(dst + 8) = u1.v;
        }
      }
    }
    if (og < 32) {
      poolAcc += __shfl_xor(poolAcc, 16);
      poolAcc += __shfl_xor(poolAcc, 32);
      if (kgrp == 0) sPoolL[og] = poolAcc;
    }
  }
  if (w == 2) {
    float gv = wredsum(gateAcc);
    if (lane == 0) atomicAdd(gsum, gv);
  }
  __syncthreads();
  if (tid < 32) atomicAdd(&pooled[b * 32 + tid], sPoolL[tid]);
}

// ---------------- K1 checker (parallel): 256 blocks x 1 sampled px ----------------
__global__ __launch_bounds__(256) void k1_check(
    const float* __restrict__ x, const float* __restrict__ ln1_w, const float* __restrict__ ln1_b,
    const float* __restrict__ in_proj_w, const float* __restrict__ qkv_w,
    const float* __restrict__ pre_w, const float* __restrict__ pre_b,
    const unsigned short* __restrict__ LOCB, const unsigned short* __restrict__ qkvl,
    const unsigned short* __restrict__ PREB, float* __restrict__ bad)
{
  __shared__ float sXv[64];
  __shared__ float sLc[32], sGl[32];
  const int blk = blockIdx.x;
  const int b = blk & 3;
  const int px = (blk * 1031) & (HW - 1);
  const int tid = threadIdx.x;
  if (tid < 64) sXv[tid] = x[(size_t)(b * 64 + tid) * HW + px];
  __syncthreads();
  if (tid < 64) {
    float v = sXv[tid];
    float mu = wredsum(v) * (1.f / 64.f);
    float d = v - mu;
    float var = wredsum(d * d) * (1.f / 64.f);
    float rs = rsqrtf(var + 1e-5f);
    sXv[tid] = d * rs * ln1_w[tid] + ln1_b[tid];
  }
  __syncthreads();
  if (tid < 64) {
    const int o = tid & 31;
    const int hi = tid >> 5;
    float s = 0.f;
#pragma unroll
    for (int c = 0; c < 64; ++c) s += in_proj_w[(hi * 32 + o) * 64 + c] * sXv[c];
    if (hi) sGl[o] = s; else sLc[o] = s;
  }
  __syncthreads();
  bool fail = false;
  if (tid < 32) {
    float s = sLc[tid];
    float got = bf2f(LOCB[((size_t)b * HW + px) * 32 + tid]);
    if (fabsf(got - s) > 0.05f + 0.05f * fabsf(s)) fail = true;
  } else if (tid < 128) {
    const int o = tid - 32;
    float s = 0.f;
#pragma unroll
    for (int j = 0; j < 32; ++j) s += qkv_w[o * 32 + j] * sGl[j];
    float got = bf2f(qkvl[(size_t)(b * 96 + o) * HW + px]);
    if (fabsf(got - s) > 0.05f + 0.05f * fabsf(s)) fail = true;
  } else if (tid < 160) {
    const int o = tid - 128;
    float s = pre_b[o];
#pragma unroll
    for (int j = 0; j < 32; ++j) s += pre_w[o * 32 + j] * sLc[j];
    float got = bf2f(PREB[((size_t)b * HW + px) * 32 + o]);
    if (fabsf(got - s) > 0.05f + 0.05f * fabsf(s)) fail = true;
  }
  if (fail) atomicExch(bad, 1.f);
}

// ---------------- K1 reset (only if checker failed) ----------------
__global__ __launch_bounds__(256) void k1r_reset(const float* __restrict__ bad, float* __restrict__ gsum)
{
  if (bad[0] < 0.5f) return;
  const int tid = threadIdx.x;
  if (tid < 129) gsum[tid] = 0.f;
}

// ---------------- K1 fallback (only if checker failed) ----------------
__global__ __launch_bounds__(256) void k1_fb(
    const float* __restrict__ x, const float* __restrict__ ln1_w, const float* __restrict__ ln1_b,
    const float* __restrict__ in_proj_w, const float* __restrict__ qkv_w,
    const float* __restrict__ pre_w, const float* __restrict__ pre_b,
    const float* __restrict__ g1w, const float* __restrict__ g1b,
    const float* __restrict__ g2w, const float* __restrict__ g2b,
    const float* __restrict__ bad,
    unsigned short* __restrict__ qkvl, unsigned short* __restrict__ LOCB,
    unsigned short* __restrict__ PREB, float* __restrict__ pooled, float* __restrict__ gsum)
{
  if (bad[0] < 0.5f) return;
  __shared__ float sPool[4][32];
  __shared__ float sRed[4];
  const int tid = threadIdx.x;
  const int p = blockIdx.x * 256 + tid;
  const int b = p >> 16;
  const int hw = p & (HW - 1);
  const int wave = tid >> 6, lane = tid & 63;
  const float* xb = x + (size_t)(b * 64) * HW + hw;
  float xv[64];
  float mu = 0.f;
#pragma unroll
  for (int c = 0; c < 64; ++c) { xv[c] = xb[(size_t)c * HW]; mu += xv[c]; }
  mu *= (1.f / 64.f);
  float var = 0.f;
#pragma unroll
  for (int c = 0; c < 64; ++c) { float d = xv[c] - mu; var += d * d; }
  var *= (1.f / 64.f);
  const float rs = rsqrtf(var + 1e-5f);
#pragma unroll
  for (int c = 0; c < 64; ++c) xv[c] = (xv[c] - mu) * rs * ln1_w[c] + ln1_b[c];
  float loc[32];
  for (int o = 0; o < 32; ++o) {
    float s = 0.f;
#pragma unroll
    for (int c = 0; c < 64; ++c) s += in_proj_w[o * 64 + c] * xv[c];
    loc[o] = s;
    LOCB[((size_t)b * HW + hw) * 32 + o] = f2bf(s);
    float r = wredsum(s);
    if (lane == 0) sPool[wave][o] = r;
  }
  for (int o = 0; o < 32; ++o) {
    float s = pre_b[o];
#pragma unroll
    for (int j = 0; j < 32; ++j) s += pre_w[o * 32 + j] * loc[j];
    PREB[((size_t)b * HW + hw) * 32 + o] = f2bf(s);
  }
  float gl[32];
  for (int o = 0; o < 32; ++o) {
    float s = 0.f;
#pragma unroll
    for (int c = 0; c < 64; ++c) s += in_proj_w[(32 + o) * 64 + c] * xv[c];
    gl[o] = s;
  }
  for (int o = 0; o < 96; ++o) {
    float s = 0.f;
#pragma unroll
    for (int j = 0; j < 32; ++j) s += qkv_w[o * 32 + j] * gl[j];
    qkvl[(size_t)(b * 96 + o) * HW + hw] = f2bf(s);
  }
  float gacc = g2b[0];
  for (int o = 0; o < 16; ++o) {
    float h = g1b[o];
#pragma unroll
    for (int j = 0; j < 32; ++j) h += g1w[o * 32 + j] * gl[j];
    gacc += g2w[o] * fmaxf(h, 0.f);
  }
  float gv = wredsum(sigm(gacc));
  if (lane == 0) sRed[wave] = gv;
  __syncthreads();
  if (tid == 0) atomicAdd(gsum, sRed[0] + sRed[1] + sRed[2] + sRed[3]);
  if (tid < 32) {
    float s = sPool[0][tid] + sPool[1][tid] + sPool[2][tid] + sPool[3][tid];
    atomicAdd(&pooled[b * 32 + tid], s);
  }
}

// ---------------- K2 (MFMA): dwconv(q,k) + Gram via V·V^T — vectorized row loads ----------------
__global__ __launch_bounds__(256) void k2_mfma(
    const unsigned short* __restrict__ qkvl, const float* __restrict__ qkv_dw, float* __restrict__ gram)
{
  __shared__ float sred[4][256];
  const int tid = threadIdx.x;
  const int slab = blockIdx.x;
  const int h = blockIdx.y, b = blockIdx.z;
  const int w = tid >> 6, lane = tid & 63;
  const int ch = lane & 15, grp = lane >> 4;
  const int gch = (ch < 8) ? (h * 8 + ch) : (32 + h * 8 + (ch - 8));
  const unsigned short* plane = qkvl + (size_t)(b * 96 + gch) * HW;
  const float* wt = qkv_dw + gch * 9;
  float w9[9];
#pragma unroll
  for (int t = 0; t < 9; ++t) w9[t] = wt[t];
  f32x4 acc = (f32x4){0.f, 0.f, 0.f, 0.f};
#pragma unroll
  for (int iter = 0; iter < 4; ++iter) {
    const int pxbase = slab * 512 + w * 128 + iter * 32 + grp * 8;
    const int y = pxbase >> 8;
    const int x0 = pxbase & 255;
    float row[3][10];
#pragma unroll
    for (int dy = 0; dy < 3; ++dy) {
      const int yy = y + dy - 1;
      if ((unsigned)yy >= 256u) {
#pragma unroll
        for (int j = 0; j < 10; ++j) row[dy][j] = 0.f;
        continue;
      }
      const unsigned short* rp = plane + yy * 256;
      union { short8v v; unsigned short s[8]; } cu;
      cu.v = *reinterpret_cast<const short8v*>(rp + x0);
#pragma unroll
      for (int j = 0; j < 8; ++j) row[dy][j + 1] = bf2f(cu.s[j]);
      row[dy][0] = (x0 > 0) ? bf2f(rp[x0 - 1]) : 0.f;
      row[dy][9] = (x0 < 248) ? bf2f(rp[x0 + 8]) : 0.f;
    }
    union { short8v v; unsigned short s[8]; } frag;
#pragma unroll
    for (int j = 0; j < 8; ++j) {
      float a = 0.f;
#pragma unroll
      for (int dy = 0; dy < 3; ++dy)
#pragma unroll
        for (int dx = 0; dx < 3; ++dx)
          a += row[dy][j + dx] * w9[dy * 3 + dx];
      frag.s[j] = f2bf(a);
    }
    acc = __builtin_amdgcn_mfma_f32_16x16x32_bf16(frag.v, frag.v, acc, 0, 0, 0);
  }
#pragma unroll
  for (int r = 0; r < 4; ++r) sred[w][(grp * 4 + r) * 16 + ch] = acc[r];
  __syncthreads();
  if (tid < 256) {
    float g = sred[0][tid] + sred[1][tid] + sred[2][tid] + sred[3][tid];
    const int row_ = tid >> 4, col_ = tid & 15;
    int idx = -1;
    if (row_ < 8 && col_ >= 8) idx = row_ * 8 + (col_ - 8);
    else if (row_ == col_ && row_ < 8) idx = 64 + row_;
    else if (row_ == col_) idx = 72 + (row_ - 8);
    if (idx >= 0) atomicAdd(&gram[(b * 4 + h) * 80 + idx], g);
  }
}

// ---------------- K3: dk, CBAM weights, attention matrices ----------------
__global__ __launch_bounds__(256) void k3_final(
    const float* __restrict__ m1w, const float* __restrict__ m1b,
    const float* __restrict__ m2w, const float* __restrict__ m2b,
    const float* __restrict__ temperature, const float* __restrict__ attn_scales,
    const float* __restrict__ pre_w, const float* __restrict__ pre_b,
    const float* __restrict__ gsum, const float* __restrict__ pooled,
    const float* __restrict__ gram, float* __restrict__ Abuf, float* __restrict__ cwbuf)
{
  __shared__ int s_dk;
  __shared__ float s_scale;
  const int tid = threadIdx.x;
  if (tid == 0) {
    float gmean = gsum[0] / (float)NPIX;
    int dk = (int)floorf(8.f * gmean);
    if (dk < 1) dk = 1;
    if (dk > 8) dk = 8;
    s_dk = dk;
    s_scale = attn_scales[0] + attn_scales[1] + attn_scales[2] + attn_scales[3];
  }
  __syncthreads();
  if (tid < 128) {
    int b = tid >> 5, ch = tid & 31, g = ch >> 2, c = ch & 3;
    float h1 = m1b[g];
#pragma unroll
    for (int cc = 0; cc < 4; ++cc) {
      int row = g * 4 + cc;
      float pp = pre_b[row];
#pragma unroll
      for (int j = 0; j < 32; ++j)
        pp += pre_w[row * 32 + j] * (pooled[b * 32 + j] * (1.f / 65536.f));
      h1 += pp * m1w[g * 4 + cc];
    }
    h1 = fmaxf(h1, 0.f);
    cwbuf[tid] = sigm(h1 * m2w[g * 4 + c] + m2b[g * 4 + c]);

    int r = tid, h = (r >> 3) & 3, c8 = r & 7;
    const float* gm = gram + (b * 4 + h) * 80;
    float qn = fmaxf(sqrtf(gm[64 + c8]), 1e-12f);
    float temp = temperature[h];
    float a[8];
#pragma unroll
    for (int d = 0; d < 8; ++d) {
      float kn = fmaxf(sqrtf(gm[72 + d]), 1e-12f);
      a[d] = gm[c8 * 8 + d] / (qn * kn) * temp;
    }
    float t[8];
#pragma unroll
    for (int d = 0; d < 8; ++d) t[d] = a[d];
#pragma unroll
    for (int i = 0; i < 8; ++i)
#pragma unroll
      for (int j = 0; j < 8; ++j)
        if (j > i && t[j] > t[i]) { float tmp = t[i]; t[i] = t[j]; t[j] = tmp; }
    float kth = t[s_dk - 1];
    float mx = t[0];
    float e[8]; float sum = 0.f;
#pragma unroll
    for (int d = 0; d < 8; ++d) {
      e[d] = (a[d] >= kth) ? expf(a[d] - mx) : 0.f;
      sum += e[d];
    }
    float inv = s_scale / sum;
#pragma unroll
    for (int d = 0; d < 8; ++d) Abuf[r * 8 + d] = e[d] * inv;
  }
}

// ---------------- K4a: resp partial sums (atomic-free), PREB bf16 ----------------
__global__ __launch_bounds__(256) void k4a_thr(
    const float* __restrict__ spw, const float* __restrict__ spb,
    const float* __restrict__ cwbuf, const unsigned short* __restrict__ PREB,
    float* __restrict__ wpart)
{
  const int tid = threadIdx.x;
  const int pxb = blockIdx.x >> 1;
  const int gh = blockIdx.x & 1;
  const int px = pxb * 256 + tid;
  const int b = px >> 16, hw = px & (HW - 1);
  const int w = tid >> 6, lane = tid & 63;
  const float* cw = cwbuf + b * 32;
  const unsigned short* pp = PREB + ((size_t)b * HW + hw) * 32 + gh * 16;
  union { short8v v; unsigned short s[8]; } u0, u1;
  u0.v = *reinterpret_cast<const short8v*>(pp);
  u1.v = *reinterpret_cast<const short8v*>(pp + 8);
  float pv[16];
#pragma unroll
  for (int k = 0; k < 8; ++k) { pv[k] = bf2f(u0.s[k]); pv[8 + k] = bf2f(u1.s[k]); }
  float racc[4];
#pragma unroll
  for (int g4 = 0; g4 < 4; ++g4) {
    const int g = gh * 4 + g4;
    float xa[4];
    float sdot = spb[g];
#pragma unroll
    for (int c = 0; c < 4; ++c) {
      xa[c] = pv[g4 * 4 + c] * cw[g * 4 + c];
      sdot += xa[c] * spw[g * 4 + c];
    }
    float sgv = sigm(sdot);
    float r = 0.f;
#pragma unroll
    for (int c = 0; c < 4; ++c) r += sigm(xa[c] * sgv);
    racc[g4] = r;
  }
#pragma unroll
  for (int g4 = 0; g4 < 4; ++g4) {
    float v = wredsum(racc[g4]);
    if (lane == 0) wpart[(blockIdx.x * 4 + w) * 4 + g4] = v;
  }
}

// ---------------- K4a_red: reduce wpart -> thrbuf ----------------
__global__ __launch_bounds__(256) void k4a_red(
    const float* __restrict__ wpart, float* __restrict__ thrbuf)
{
  __shared__ float sr[256];
  const int tid = threadIdx.x;
  const int b = blockIdx.x >> 3, g = blockIdx.x & 7;
  const int gh = g >> 2, gl = g & 3;
  float s = 0.f;
#pragma unroll
  for (int w = 0; w < 4; ++w)
    s += wpart[((((size_t)(b * 256 + tid) * 2 + gh) * 4) + w) * 4 + gl];
  sr[tid] = s;
  __syncthreads();
  for (int st = 128; st >= 1; st >>= 1) {
    if (tid < st) sr[tid] += sr[tid + st];
    __syncthreads();
  }
  if (tid == 0) thrbuf[b * 8 + g] = sr[0];
}

// ---------------- K4b (MFMA): V-dwconv + LGCE finish + attn -> A96 MFMA (bf16 W96 table) ----------------
__global__ __launch_bounds__(256) void k4b_fuse(
    const float* __restrict__ x, const float* __restrict__ spw, const float* __restrict__ spb,
    const float* __restrict__ qkv_dw, const unsigned short* __restrict__ qkvl,
    const unsigned short* __restrict__ LOCB, const unsigned short* __restrict__ PREB,
    const float* __restrict__ Abuf, const float* __restrict__ cwbuf, const float* __restrict__ thrbuf,
    const unsigned short* __restrict__ wb96, const float* __restrict__ cb,
    float* __restrict__ dout)
{
  __shared__ float sV[64][33];
  __shared__ unsigned short sA[64][104];
  __shared__ float sOut[64][65];
  const int tid = threadIdx.x;
  const int p0 = blockIdx.x * 64;
  const int b = p0 >> 16;
  const int hw0 = p0 & (HW - 1);
  const int yrow = hw0 >> 8;
  const int x0b = hw0 & 255;
  {
    const int j = tid >> 3;
    const int seg = tid & 7;
    const int x0 = x0b + seg * 8;
    const unsigned short* plane = qkvl + (size_t)(b * 96 + 64 + j) * HW;
    const float* wt = qkv_dw + (64 + j) * 9;
    float w9[9];
#pragma unroll
    for (int t = 0; t < 9; ++t) w9[t] = wt[t];
    float row[3][10];
#pragma unroll
    for (int dy = 0; dy < 3; ++dy) {
      const int yy = yrow + dy - 1;
      if ((unsigned)yy >= 256u) {
#pragma unroll
        for (int k = 0; k < 10; ++k) row[dy][k] = 0.f;
        continue;
      }
      const unsigned short* rp = plane + yy * 256;
      union { short8v v; unsigned short s[8]; } cu;
      cu.v = *reinterpret_cast<const short8v*>(rp + x0);
#pragma unroll
      for (int k = 0; k < 8; ++k) row[dy][k + 1] = bf2f(cu.s[k]);
      row[dy][0] = (x0 > 0) ? bf2f(rp[x0 - 1]) : 0.f;
      row[dy][9] = (x0 < 248) ? bf2f(rp[x0 + 8]) : 0.f;
    }
#pragma unroll
    for (int p = 0; p < 8; ++p) {
      float s = 0.f;
#pragma unroll
      for (int dy = 0; dy < 3; ++dy)
#pragma unroll
        for (int dx = 0; dx < 3; ++dx)
          s += row[dy][p + dx] * w9[dy * 3 + dx];
      sV[seg * 8 + p][j] = s;
    }
  }
  __syncthreads();
  const int px_l = tid & 63, q = tid >> 6;
  const int hw = hw0 + px_l;
  const float* cw = cwbuf + b * 32;
  const float* A = Abuf + b * 256;
  union { short8v v; unsigned short s[8]; } lv, pvv;
  lv.v = *reinterpret_cast<const short8v*>(LOCB + ((size_t)b * HW + hw) * 32 + q * 8);
  pvv.v = *reinterpret_cast<const short8v*>(PREB + ((size_t)b * HW + hw) * 32 + q * 8);
  float pre8[8];
#pragma unroll
  for (int j = 0; j < 8; ++j) pre8[j] = bf2f(pvv.s[j]);
  union { short8v v; unsigned short s[8]; } mxv;
#pragma unroll
  for (int g2 = 0; g2 < 2; ++g2) {
    const int g = 2 * q + g2;
    float xa[4];
    float sdot = spb[g];
#pragma unroll
    for (int c = 0; c < 4; ++c) {
      xa[c] = pre8[g2 * 4 + c] * cw[g * 4 + c];
      sdot += xa[c] * spw[g * 4 + c];
    }
    float sgv = sigm(sdot);
    float thr = thrbuf[b * 8 + g] * (1.f / (4.f * 65536.f));
#pragma unroll
    for (int c = 0; c < 4; ++c) {
      float resp = sigm(xa[c] * sgv);
      float m = (resp > thr) ? 1.f : resp;
      mxv.s[g2 * 4 + c] = f2bf(pre8[g2 * 4 + c] * m);
    }
  }
  float v8[8];
#pragma unroll
  for (int j = 0; j < 8; ++j) v8[j] = sV[px_l][q * 8 + j];
  union { short8v v; unsigned short s[8]; } attv;
#pragma unroll
  for (int j = 0; j < 8; ++j) {
    float s = 0.f;
#pragma unroll
    for (int d = 0; d < 8; ++d) s += A[(q * 8 + j) * 8 + d] * v8[d];
    attv.s[j] = f2bf(s);
  }
  *reinterpret_cast<short8v*>(&sA[px_l][q * 8]) = attv.v;
  *reinterpret_cast<short8v*>(&sA[px_l][32 + q * 8]) = mxv.v;
  *reinterpret_cast<short8v*>(&sA[px_l][64 + q * 8]) = lv.v;
  __syncthreads();
  const int w = q, lane = tid & 63;
  const int col = lane & 15, kgrp = lane >> 4;
  const int og = w * 16 + col;
  f32x4 acc[4];
#pragma unroll
  for (int s = 0; s < 4; ++s) acc[s] = (f32x4){0.f, 0.f, 0.f, 0.f};
#pragma unroll
  for (int kk = 0; kk < 3; ++kk) {
    const int c0 = kk * 32 + kgrp * 8;
    union { short8v v; unsigned short s[8]; } bw;
    bw.v = *reinterpret_cast<const short8v*>(wb96 + og * 96 + c0);
#pragma unroll
    for (int s = 0; s < 4; ++s) {
      short8v av = *reinterpret_cast<const short8v*>(&sA[s * 16 + col][c0]);
      acc[s] = __builtin_amdgcn_mfma_f32_16x16x32_bf16(av, bw.v, acc[s], 0, 0, 0);
    }
  }
#pragma unroll
  for (int s = 0; s < 4; ++s) {
#pragma unroll
    for (int r = 0; r < 4; ++r) {
      int pxl = s * 16 + kgrp * 4 + r;
      sOut[og][pxl] = acc[s][r];
    }
  }
  __syncthreads();
  const float* xb = x + (size_t)(b * 64) * HW + hw0;
  float* db = dout + (size_t)(b * 64) * HW + hw0;
#pragma unroll
  for (int i = 0; i < 16; ++i) {
    int idx = tid + i * 256;
    int o = idx >> 6, px = idx & 63;
    db[(size_t)o * HW + px] = sOut[o][px] + cb[o] + xb[(size_t)o * HW + px];
  }
}

// ---------------- K5 (MFMA): LN2 + ffn_in (64->256), bf16 weight table on identity path ----------------
__global__ __launch_bounds__(256) void k5_mfma(
    const float* __restrict__ ln2_w, const float* __restrict__ ln2_b,
    const float* __restrict__ ffn_in_w, const unsigned short* __restrict__ wf5,
    const float* __restrict__ flag, const float* __restrict__ dout,
    unsigned short* __restrict__ Tb, int b)
{
  __shared__ float sShared[4352];            // sStage (fp32), later reused as sOutB (bf16, 128 rows)
  __shared__ unsigned short sXnb[64][68];
  __shared__ float sMu[64], sRs[64];
  float (*sStage)[65] = reinterpret_cast<float(*)[65]>(sShared);
  unsigned short (*sOutB)[68] = reinterpret_cast<unsigned short(*)[68]>(sShared);
  const int tid = threadIdx.x;
  const int px0 = blockIdx.x * 64;
  const bool idf = flag[0] > 0.5f;
  const float* db = dout + (size_t)(b * 64) * HW + px0;
#pragma unroll
  for (int i = 0; i < 4; ++i) {
    int idx = tid + i * 256;                 // 0..1023
    int c = idx >> 4, px4 = (idx & 15) * 4;
    float4 v = *reinterpret_cast<const float4*>(db + (size_t)c * HW + px4);
    sStage[px4][c] = v.x;
    sStage[px4 + 1][c] = v.y;
    sStage[px4 + 2][c] = v.z;
    sStage[px4 + 3][c] = v.w;
  }
  __syncthreads();
  if (tid < 64) {
    float mu = 0.f;
#pragma unroll
    for (int c = 0; c < 64; ++c) mu += sStage[tid][c];
    mu *= (1.f / 64.f);
    float var = 0.f;
#pragma unroll
    for (int c = 0; c < 64; ++c) { float d = sStage[tid][c] - mu; var += d * d; }
    var *= (1.f / 64.f);
    sMu[tid] = mu;
    sRs[tid] = rsqrtf(var + 1e-5f);
  }
  __syncthreads();
#pragma unroll
  for (int i = 0; i < 16; ++i) {
    int idx = tid + i * 256;
    int px = idx >> 6, c = idx & 63;
    float xn = (sStage[px][c] - sMu[px]) * sRs[px] * ln2_w[c] + ln2_b[c];
    sXnb[px][c] = f2bf(xn);
  }
  __syncthreads();   // sStage dead; sOutB takes over the region
  const int w = tid >> 6, lane = tid & 63;
  const int col = lane & 15, kgrp = lane >> 4;
#pragma unroll
  for (int mp = 0; mp < 2; ++mp) {
#pragma unroll
    for (int pass = 0; pass < 2; ++pass) {
      const int o_l = pass * 64 + w * 16 + col;   // 0..127 within macro-pass
      const int og = mp * 128 + o_l;
      f32x4 acc[4];
#pragma unroll
      for (int s = 0; s < 4; ++s) acc[s] = (f32x4){0.f, 0.f, 0.f, 0.f};
#pragma unroll
      for (int kk = 0; kk < 2; ++kk) {
        const int c0 = kk * 32 + kgrp * 8;
        union { short8v v; unsigned short s[8]; } bw;
        if (idf) {
          bw.v = *reinterpret_cast<const short8v*>(wf5 + (size_t)og * 64 + c0);
        } else {
          const float* wp = ffn_in_w + (size_t)og * 64 + c0;
#pragma unroll
          for (int j = 0; j < 8; ++j) bw.s[j] = f2bf(wp[j]);
        }
#pragma unroll
        for (int s = 0; s < 4; ++s) {
          short8v av = *reinterpret_cast<const short8v*>(&sXnb[s * 16 + col][c0]);
          acc[s] = __builtin_amdgcn_mfma_f32_16x16x32_bf16(av, bw.v, acc[s], 0, 0, 0);
        }
      }
#pragma unroll
      for (int s = 0; s < 4; ++s) {
#pragma unroll
        for (int r = 0; r < 4; ++r) {
          int px_l = s * 16 + kgrp * 4 + r;
          sOutB[o_l][px_l] = f2bf(acc[s][r]);
        }
      }
    }
    __syncthreads();
    for (int i = tid; i < 1024; i += 256) {
      int o = i >> 3, seg = i & 7;
      *reinterpret_cast<short8v*>(Tb + (size_t)(mp * 128 + o) * HW + px0 + seg * 8) =
          *reinterpret_cast<const short8v*>(&sOutB[o][seg * 8]);
    }
    __syncthreads();   // before next macro-pass overwrites sOutB
  }
}

// ---------------- K6a: dwconv3/dwconv5 + gelu*mul -> Y (bf16), 1 ch x 2 rows per thread ----------------
__global__ __launch_bounds__(256) void k6a_dw(
    const float* __restrict__ dw3_w, const float* __restrict__ dw5_w,
    const unsigned short* __restrict__ T, unsigned short* __restrict__ Y)
{
  const int idx = blockIdx.x * 256 + threadIdx.x;  // 524288 threads (grid 2048)
  const int j = idx >> 12;          // channel 0..127 (wave-uniform)
  const int rem = idx & 4095;
  const int y0 = (rem >> 5) * 2;    // output row pair base 0,2,..,254
  const int x0 = (rem & 31) * 8;    // col start, multiple of 8
  float m[2][8];
  const unsigned short* pm = T + (size_t)(128 + j) * HW;
  if (j < 64) {
    const float* wt = dw3_w + (128 + j) * 9;
    float w9[9];
#pragma unroll
    for (int t = 0; t < 9; ++t) w9[t] = wt[t];
    float row[4][10];
#pragma unroll
    for (int r = 0; r < 4; ++r) {
      const int yy = y0 + r - 1;
      if ((unsigned)yy >= 256u) {
#pragma unroll
        for (int k = 0; k < 10; ++k) row[r][k] = 0.f;
        continue;
      }
      const unsigned short* rp = pm + yy * 256;
      union { short8v v; unsigned short s[8]; } cu;
      cu.v = *reinterpret_cast<const short8v*>(rp + x0);
#pragma unroll
      for (int k = 0; k < 8; ++k) row[r][k + 1] = bf2f(cu.s[k]);
      row[r][0] = (x0 > 0) ? bf2f(rp[x0 - 1]) : 0.f;
      row[r][9] = (x0 < 248) ? bf2f(rp[x0 + 8]) : 0.f;
    }
#pragma unroll
    for (int t = 0; t < 2; ++t)
#pragma unroll
      for (int p = 0; p < 8; ++p) {
        float s = 0.f;
#pragma unroll
        for (int dy = 0; dy < 3; ++dy)
#pragma unroll
          for (int dx = 0; dx < 3; ++dx)
            s += row[t + dy][p + dx] * w9[dy * 3 + dx];
        m[t][p] = s;
      }
  } else {
    const float* wt = dw5_w + (j - 64) * 25;
    float w25[25];
#pragma unroll
    for (int t = 0; t < 25; ++t) w25[t] = wt[t];
    float row[6][12];
#pragma unroll
    for (int r = 0; r < 6; ++r) {
      const int yy = y0 + r - 2;
      if ((unsigned)yy >= 256u) {
#pragma unroll
        for (int k = 0; k < 12; ++k) row[r][k] = 0.f;
        continue;
      }
      const unsigned short* rp = pm + yy * 256;
      union { short8v v; unsigned short s[8]; } cu;
      cu.v = *reinterpret_cast<const short8v*>(rp + x0);
#pragma unroll
      for (int k = 0; k < 8; ++k) row[r][k + 2] = bf2f(cu.s[k]);
      row[r][0] = (x0 > 0) ? bf2f(rp[x0 - 2]) : 0.f;
      row[r][1] = (x0 > 0) ? bf2f(rp[x0 - 1]) : 0.f;
      row[r][10] = (x0 < 248) ? bf2f(rp[x0 + 8]) : 0.f;
      row[r][11] = (x0 < 248) ? bf2f(rp[x0 + 9]) : 0.f;
    }
#pragma unroll
    for (int t = 0; t < 2; ++t)
#pragma unroll
      for (int p = 0; p < 8; ++p) {
        float s = 0.f;
#pragma unroll
        for (int dy = 0; dy < 5; ++dy)
#pragma unroll
          for (int dx = 0; dx < 5; ++dx)
            s += row[t + dy][p + dx] * w25[dy * 5 + dx];
        m[t][p] = s;
      }
  }
  float a[2][8];
  {
    const unsigned short* pa = T + (size_t)j * HW;
    const float* wt = dw3_w + j * 9;
    float w9[9];
#pragma unroll
    for (int t = 0; t < 9; ++t) w9[t] = wt[t];
    float row[4][10];
#pragma unroll
    for (int r = 0; r < 4; ++r) {
      const int yy = y0 + r - 1;
      if ((unsigned)yy >= 256u) {
#pragma unroll
        for (int k = 0; k < 10; ++k) row[r][k] = 0.f;
        continue;
      }
      const unsigned short* rp = pa + yy * 256;
      union { short8v v; unsigned short s[8]; } cu;
      cu.v = *reinterpret_cast<const short8v*>(rp + x0);
#pragma unroll
      for (int k = 0; k < 8; ++k) row[r][k + 1] = bf2f(cu.s[k]);
      row[r][0] = (x0 > 0) ? bf2f(rp[x0 - 1]) : 0.f;
      row[r][9] = (x0 < 248) ? bf2f(rp[x0 + 8]) : 0.f;
    }
#pragma unroll
    for (int t = 0; t < 2; ++t)
#pragma unroll
      for (int p = 0; p < 8; ++p) {
        float s = 0.f;
#pragma unroll
        for (int dy = 0; dy < 3; ++dy)
#pragma unroll
          for (int dx = 0; dx < 3; ++dx)
            s += row[t + dy][p + dx] * w9[dy * 3 + dx];
        a[t][p] = s;
      }
  }
#pragma unroll
  for (int t = 0; t < 2; ++t) {
    union { short8v v; unsigned short s[8]; } out;
#pragma unroll
    for (int p = 0; p < 8; ++p) {
      float gl = 0.5f * a[t][p] * (1.f + erff(a[t][p] * 0.70710678118654752f));
      out.s[p] = f2bf(gl * m[t][p]);
    }
    *reinterpret_cast<short8v*>(Y + (size_t)j * HW + (y0 + t) * 256 + x0) = out.v;
  }
}

// ---------------- K6b (MFMA): ffn_out (128->64), Y staged once in LDS, K=128 ----------------
__global__ __launch_bounds__(256) void k6b_mfma(
    const float* __restrict__ ffn_out_w, const unsigned short* __restrict__ wf6,
    const unsigned short* __restrict__ Y,
    const float* __restrict__ flag, float* __restrict__ dout, float* __restrict__ Z, int b)
{
  __shared__ unsigned short sY[64][136];   // 17.4 KB [px][128ch]
  __shared__ float sOut[64][65];           // 16.6 KB
  const int tid = threadIdx.x;
  const int px0 = blockIdx.x * 64;
  const bool idf = flag[0] > 0.5f;
#pragma unroll
  for (int i = 0; i < 4; ++i) {
    const int t = tid + i * 256;
    const int ch = t >> 3, seg = t & 7;
    union { short8v v; unsigned short s[8]; } u;
    u.v = *reinterpret_cast<const short8v*>(Y + (size_t)ch * HW + px0 + seg * 8);
#pragma unroll
    for (int p = 0; p < 8; ++p) sY[seg * 8 + p][ch] = u.s[p];
  }
  __syncthreads();
  const int w = tid >> 6, lane = tid & 63;
  const int col = lane & 15, kgrp = lane >> 4;
  const int og = w * 16 + col;               // 0..63
  f32x4 acc[4];
#pragma unroll
  for (int s = 0; s < 4; ++s) acc[s] = (f32x4){0.f, 0.f, 0.f, 0.f};
#pragma unroll
  for (int kk = 0; kk < 4; ++kk) {
    const int c0 = kk * 32 + kgrp * 8;
    union { short8v v; unsigned short s[8]; } bw;
    if (idf) {
      bw.v = *reinterpret_cast<const short8v*>(wf6 + (size_t)og * 128 + c0);
    } else {
      const float* wp = ffn_out_w + (size_t)og * 128 + c0;
#pragma unroll
      for (int j = 0; j < 8; ++j) bw.s[j] = f2bf(wp[j]);
    }
#pragma unroll
    for (int s = 0; s < 4; ++s) {
      short8v av = *reinterpret_cast<const short8v*>(&sY[s * 16 + col][c0]);
      acc[s] = __builtin_amdgcn_mfma_f32_16x16x32_bf16(av, bw.v, acc[s], 0, 0, 0);
    }
  }
#pragma unroll
  for (int s = 0; s < 4; ++s) {
#pragma unroll
    for (int r = 0; r < 4; ++r) {
      int pxl = s * 16 + kgrp * 4 + r;
      sOut[og][pxl] = acc[s][r];
    }
  }
  __syncthreads();
  if (idf) {
    float* db = dout + (size_t)(b * 64) * HW + px0;
#pragma unroll
    for (int i = 0; i < 16; ++i) {
      int idx = tid + i * 256;
      int o = idx >> 6, px = idx & 63;
      db[(size_t)o * HW + px] += sOut[o][px];
    }
  } else {
    float* zb = Z + px0;
#pragma unroll
    for (int i = 0; i < 16; ++i) {
      int idx = tid + i * 256;
      int o = idx >> 6, px = idx & 63;
      zb[(size_t)o * HW + px] = sOut[o][px];
    }
  }
}

// ---------------- K7: general fft path, 8 patch-groups per block (early-exit if identity) ----------------
__global__ __launch_bounds__(256) void k7_fft(
    const float* __restrict__ fftw, const float* __restrict__ flag,
    const float* __restrict__ Z, float* __restrict__ dout, int b)
{
  if (flag[0] > 0.5f) return;
  __shared__ float swv[64];
  __shared__ float spatch[4][64];
  const int tid = threadIdx.x;
  const int c = blockIdx.x >> 5;        // channel 0..63 (grid 2048)
  const int pblk0 = (blockIdx.x & 31) * 8;
  if (tid < 64) swv[tid] = fftw[c * 64 + tid];
  const int lp = tid >> 6, e = tid & 63;
  const int i = e >> 3, jj = e & 7;
  for (int pg = 0; pg < 8; ++pg) {
    const int patch = (pblk0 + pg) * 4 + lp;
    const int pi = patch >> 5, pj = patch & 31;
    const int gidx = (pi * 8 + i) * 256 + pj * 8 + jj;
    const float zv = Z[(size_t)c * HW + gidx];
    spatch[lp][e] = zv;
    __syncthreads();
    float s = 0.f;
#pragma unroll
    for (int a = 0; a < 8; ++a)
#pragma unroll
      for (int b2 = 0; b2 < 8; ++b2)
        s += swv[a * 8 + b2] * spatch[lp][((i - a) & 7) * 8 + ((jj - b2) & 7)];
    dout[(size_t)(b * 64 + c) * HW + gidx] += s;
    __syncthreads();
  }
}

extern "C" void kernel_launch(void* const* d_in, const int* in_sizes, int n_in,
                              void* d_out, int out_size, void* d_ws, size_t ws_size,
                              hipStream_t stream) {
  const float* x          = (const float*)d_in[0];
  const float* ln1_w      = (const float*)d_in[1];
  const float* ln1_b      = (const float*)d_in[2];
  const float* in_proj_w  = (const float*)d_in[3];
  const float* qkv_w      = (const float*)d_in[4];
  const float* qkv_dw     = (const float*)d_in[5];
  const float* out_proj_w = (const float*)d_in[6];
  const float* temperature= (const float*)d_in[7];
  const float* attn_scales= (const float*)d_in[8];
  const float* gate_w1    = (const float*)d_in[9];
  const float* gate_b1    = (const float*)d_in[10];
  const float* gate_w2    = (const float*)d_in[11];
  const float* gate_b2    = (const float*)d_in[12];
  const float* lgce_pre_w = (const float*)d_in[13];
  const float* lgce_pre_b = (const float*)d_in[14];
  const float* lgce_post_w= (const float*)d_in[15];
  const float* lgce_post_b= (const float*)d_in[16];
  const float* cbam_m1w   = (const float*)d_in[17];
  const float* cbam_m1b   = (const float*)d_in[18];
  const float* cbam_m2w   = (const float*)d_in[19];
  const float* cbam_m2b   = (const float*)d_in[20];
  const float* cbam_spw   = (const float*)d_in[21];
  const float* cbam_spb   = (const float*)d_in[22];
  const float* ln2_w      = (const float*)d_in[23];
  const float* ln2_b      = (const float*)d_in[24];
  const float* ffn_in_w   = (const float*)d_in[25];
  const float* dw3_w      = (const float*)d_in[26];
  const float* dw5_w      = (const float*)d_in[27];
  const float* ffn_out_w  = (const float*)d_in[28];
  const float* fft_W      = (const float*)d_in[29];
  float* ws = (float*)d_ws;
  float* out = (float*)d_out;
  unsigned short* qkvlp = (unsigned short*)(ws + OFF_QKVL);
  unsigned short* LOCB = (unsigned short*)(ws + OFF_LOCB);
  unsigned short* PREB = (unsigned short*)(ws + OFF_PREB);
  unsigned short* Tb = (unsigned short*)(ws + OFF_T);
  unsigned short* Ybuf = (unsigned short*)(ws + OFF_Y);

  hipLaunchKernelGGL(k0_setup, dim3(1), dim3(256), 0, stream,
                     fft_W, in_proj_w, qkv_w, gate_w1, lgce_pre_w,
                     out_proj_w, lgce_post_w, lgce_post_b, ws);
  hipLaunchKernelGGL(k0b_tables, dim3(164), dim3(256), 0, stream,
                     in_proj_w, ffn_in_w, ffn_out_w, ws);
  hipLaunchKernelGGL(k1_mfma, dim3(2048), dim3(256), 0, stream,
                     x, ln1_w, ln1_b, (unsigned short*)(ws + OFF_WK1), lgce_pre_b,
                     gate_b1, gate_w2, gate_b2,
                     qkvlp, LOCB, PREB, ws + OFF_POOL, ws + OFF_GSUM);
  hipLaunchKernelGGL(k1_check, dim3(256), dim3(256), 0, stream,
                     x, ln1_w, ln1_b, in_proj_w, qkv_w, lgce_pre_w, lgce_pre_b,
                     LOCB, qkvlp, PREB, ws + OFF_BAD);
  hipLaunchKernelGGL(k1r_reset, dim3(1), dim3(256), 0, stream,
                     ws + OFF_BAD, ws + OFF_GSUM);
  hipLaunchKernelGGL(k1_fb, dim3(1024), dim3(256), 0, stream,
                     x, ln1_w, ln1_b, in_proj_w, qkv_w, lgce_pre_w, lgce_pre_b,
                     gate_w1, gate_b1, gate_w2, gate_b2,
                     ws + OFF_BAD, qkvlp, LOCB, PREB, ws + OFF_POOL, ws + OFF_GSUM);
  hipLaunchKernelGGL(k2_mfma, dim3(128, 4, 4), dim3(256), 0, stream,
                     qkvlp, qkv_dw, ws + OFF_GRAM);
  hipLaunchKernelGGL(k3_final, dim3(1), dim3(256), 0, stream,
                     cbam_m1w, cbam_m1b, cbam_m2w, cbam_m2b, temperature, attn_scales,
                     lgce_pre_w, lgce_pre_b,
                     ws + OFF_GSUM, ws + OFF_POOL, ws + OFF_GRAM, ws + OFF_A, ws + OFF_CW);
  hipLaunchKernelGGL(k4a_thr, dim3(2048), dim3(256), 0, stream,
                     cbam_spw, cbam_spb, ws + OFF_CW, PREB, ws + OFF_PART);
  hipLaunchKernelGGL(k4a_red, dim3(32), dim3(256), 0, stream,
                     ws + OFF_PART, ws + OFF_THR);
  hipLaunchKernelGGL(k4b_fuse, dim3(4096), dim3(256), 0, stream,
                     x, cbam_spw, cbam_spb, qkv_dw, qkvlp, LOCB, PREB,
                     ws + OFF_A, ws + OFF_CW, ws + OFF_THR,
                     (unsigned short*)(ws + OFF_WB96), ws + OFF_CB, out);

  for (int b = 0; b < 4; ++b) {
    hipLaunchKernelGGL(k5_mfma, dim3(1024), dim3(256), 0, stream,
                       ln2_w, ln2_b, ffn_in_w, (unsigned short*)(ws + OFF_WF5),
                       ws + OFF_FLAG, out, Tb, b);
    hipLaunchKernelGGL(k6a_dw, dim3(2048), dim3(256), 0, stream,
                       dw3_w, dw5_w, Tb, Ybuf);
    hipLaunchKernelGGL(k6b_mfma, dim3(1024), dim3(256), 0, stream,
                       ffn_out_w, (unsigned short*)(ws + OFF_WF6), Ybuf,
                       ws + OFF_FLAG, out, ws + OFF_Z, b);
    hipLaunchKernelGGL(k7_fft, dim3(2048), dim3(256), 0, stream,
                       ws + OFF_FFTW, ws + OFF_FLAG, ws + OFF_Z, out, b);
  }
}

// Round 25
// 422.143 us; speedup vs baseline: 1.1350x; 1.0814x over previous
//
#include <hip/hip_runtime.h>
#include <hip/hip_bf16.h>
#include <math.h>

#define HW 65536
#define NPIX 262144

// ---- workspace layout (float offsets) ----
#define OFF_FFTW 0            // 64x64 spatial fft kernel
#define OFF_FLAG 4096         // 1
#define OFF_GSUM 4097         // 1    (zeroed in k0_par blk8)
#define OFF_POOL 4098         // 128
#define OFF_GRAM 4226         // 1280
#define OFF_THR  5506         // 32
#define OFF_BAD  5538         // 1
#define OFF_A    5539         // 1024 (k3 output; slots 0..7 reused transiently as k0 okslots)
#define OFF_CW   6563         // 128
#define OFF_QKVL 8192         // 96ch * 262144 px bf16 = 12582912 float-slots (SGSA phase)
#define OFF_MQKV 12591104     // 96*64 fp32 composed qkv matrix
#define OFF_MG1  (OFF_MQKV + 6144)     // 16*64 fp32  (ends 12598272)
#define OFF_MPRE 12598272     // 32*64 fp32 composed pre matrix (ends 12600320)
#define OFF_PREB 12600320     // [4][65536][32] bf16 px-major = 4194304 slots (ends 16794624)
#define OFF_LOCB 16794624     // [4][65536][32] bf16 px-major = 4194304 slots (ends 20988928)
#define OFF_PART 20988928     // 2048 blk * 4 waves * 4 g = 32768 (ends 21021696)
#define OFF_W96  21021696     // 64*96 fp32 composed out_proj|post matrix (SGSA phase only)
#define OFF_CB   (OFF_W96 + 6144)      // 64 fp32 (ends 21027904)
// bf16 weight tables (inside Z region, above SGSA max 21027904):
//  WK1/WB96 consumed in SGSA phase only. WF5/WF6 consumed in MFFN only on
//  identity path (flag==1 -> Z never written); fallback re-converts from fp32.
#define OFF_WB96 21027904     // 64*96 bf16 = 3072 float-slots (ends 21030976)
#define OFF_WF5  21030976     // 256*64 bf16 = 8192 slots (ends 21039168)
#define OFF_WF6  21039168     // 64*128 bf16 = 4096 slots (ends 21043264)
#define OFF_WK1  21043264     // 176*64 bf16 = 5632 slots (ends 21048896 < 25174016)
// MFFN phase (per-batch, overlaps QKVL/PREB/LOCB/W96 which are dead by then):
#define OFF_T    8192                      // 256ch * 65536 bf16
#define OFF_Y    (OFF_T + 16777216)        // 128ch * 65536 bf16
#define OFF_Z    (OFF_Y + 4194304)         // 64ch * 65536 fp32
// peak ws usage = 25174016 floats = 100.7 MB (unchanged proven footprint)

typedef __attribute__((ext_vector_type(8))) short short8v;
typedef __attribute__((ext_vector_type(4))) float f32x4;

__device__ __forceinline__ float sigm(float v) { return 1.f / (1.f + expf(-v)); }
__device__ __forceinline__ float wredsum(float v) {
#pragma unroll
  for (int off = 32; off >= 1; off >>= 1) v += __shfl_xor(v, off);
  return v;
}
__device__ __forceinline__ unsigned short f2bf(float f) {
  union { float f; unsigned u; } x; x.f = f;
  unsigned r = x.u + 0x7fffu + ((x.u >> 16) & 1u);
  return (unsigned short)(r >> 16);
}
__device__ __forceinline__ float bf2f(unsigned short u) {
  union { unsigned u; float f; } x; x.u = ((unsigned)u) << 16;
  return x.f;
}

// ---------------- K0 (parallel, grid 15): zero + composed matrices + fft kernel/check ----------------
// blocks 0..7: FFTW 512 elems each + per-block ok -> okslot ws[OFF_A + blk]
// block 8: zero accumulators; 9..10: MQKV; 11: MG1+MPRE; 12..13: W96; 14: CB
__global__ __launch_bounds__(256) void k0_par(
    const float* __restrict__ fft_W, const float* __restrict__ in_proj_w,
    const float* __restrict__ qkv_w, const float* __restrict__ g1w,
    const float* __restrict__ pre_w, const float* __restrict__ out_proj_w,
    const float* __restrict__ post_w, const float* __restrict__ post_b,
    float* __restrict__ ws)
{
  const int tid = threadIdx.x;
  const int blk = blockIdx.x;
  if (blk < 8) {
    __shared__ float ct8[8];
    __shared__ int sbad;
    if (tid < 8) ct8[tid] = cosf((float)tid * 0.78539816339744831f);
    if (tid == 0) sbad = 0;
    __syncthreads();
    bool ok = true;
#pragma unroll
    for (int k = 0; k < 2; ++k) {
      const int i = blk * 512 + k * 256 + tid;
      const int ch = i >> 6, ab = i & 63;
      const int a = ab >> 3, b2 = ab & 7;
      float s = 0.f;
      for (int u = 0; u < 8; ++u)
        for (int v = 0; v < 8; ++v) {
          float Wf;
          if (v == 0 || v == 4)
            Wf = 0.5f * (fft_W[ch * 40 + u * 5 + v] + fft_W[ch * 40 + ((8 - u) & 7) * 5 + v]);
          else if (v < 5)
            Wf = fft_W[ch * 40 + u * 5 + v];
          else
            Wf = fft_W[ch * 40 + ((8 - u) & 7) * 5 + (8 - v)];
          s += Wf * ct8[(u * a + v * b2) & 7];
        }
      s *= (1.f / 64.f);
      ws[OFF_FFTW + i] = s;
      float expect = ((i & 63) == 0) ? 1.f : 0.f;
      if (fabsf(s - expect) > 1e-4f) ok = false;
    }
    if (!ok) atomicOr(&sbad, 1);
    __syncthreads();
    if (tid == 0) ws[OFF_A + blk] = sbad ? 0.f : 1.f;
  } else if (blk == 8) {
    for (int i = tid; i < 1442; i += 256) ws[OFF_GSUM + i] = 0.f;
  } else if (blk <= 10) {
    const int base = (blk - 9) * 3072;
    for (int t = tid; t < 3072; t += 256) {
      int i = base + t;
      int o = i >> 6, c = i & 63;
      float s = 0.f;
      for (int j = 0; j < 32; ++j) s += qkv_w[o * 32 + j] * in_proj_w[(32 + j) * 64 + c];
      ws[OFF_MQKV + i] = s;
    }
  } else if (blk == 11) {
    for (int i = tid; i < 16 * 64; i += 256) {
      int o = i >> 6, c = i & 63;
      float s = 0.f;
      for (int j = 0; j < 32; ++j) s += g1w[o * 32 + j] * in_proj_w[(32 + j) * 64 + c];
      ws[OFF_MG1 + i] = s;
    }
    for (int i = tid; i < 32 * 64; i += 256) {
      int o = i >> 6, c = i & 63;
      float s = 0.f;
      for (int j = 0; j < 32; ++j) s += pre_w[o * 32 + j] * in_proj_w[j * 64 + c];
      ws[OFF_MPRE + i] = s;
    }
  } else if (blk <= 13) {
    const int base = (blk - 12) * 3072;
    for (int t = tid; t < 3072; t += 256) {
      int i = base + t;
      int o = i / 96, c = i - o * 96;
      float s;
      if (c < 32) s = out_proj_w[o * 64 + c];
      else if (c < 64) {
        s = 0.f;
        for (int k = 0; k < 32; ++k) s += out_proj_w[o * 64 + 32 + k] * post_w[k * 32 + (c - 32)];
      } else s = out_proj_w[o * 64 + (c - 32)];
      ws[OFF_W96 + i] = s;
    }
  } else {
    if (tid < 64) {
      float s = 0.f;
      for (int k = 0; k < 32; ++k) s += out_proj_w[tid * 64 + 32 + k] * post_b[k];
      ws[OFF_CB + tid] = s;
    }
  }
}

// ---------------- K0b: bf16 weight tables (parallel) + FLAG from okslots ----------------
__global__ __launch_bounds__(256) void k0b_tables(
    const float* __restrict__ in_proj_w, const float* __restrict__ ffn_in_w,
    const float* __restrict__ ffn_out_w, float* __restrict__ ws)
{
  const int idx = blockIdx.x * 256 + threadIdx.x;
  if (idx == 0) {
    float f = 1.f;
#pragma unroll
    for (int k = 0; k < 8; ++k)
      if (ws[OFF_A + k] < 0.5f) f = 0.f;
    ws[OFF_FLAG] = f;
  }
  if (idx < 11264) {                       // WK1: 176x64
    int o = idx >> 6, c = idx & 63;
    float v = (o < 32) ? in_proj_w[o * 64 + c]
            : (o < 128) ? ws[OFF_MQKV + (o - 32) * 64 + c]
            : (o < 160) ? ws[OFF_MPRE + (o - 128) * 64 + c]
                        : ws[OFF_MG1 + (o - 160) * 64 + c];
    ((unsigned short*)(ws + OFF_WK1))[idx] = f2bf(v);
  } else if (idx < 11264 + 6144) {         // WB96: 64x96
    int i = idx - 11264;
    ((unsigned short*)(ws + OFF_WB96))[i] = f2bf(ws[OFF_W96 + i]);
  } else if (idx < 11264 + 6144 + 16384) { // WF5: 256x64
    int i = idx - 11264 - 6144;
    ((unsigned short*)(ws + OFF_WF5))[i] = f2bf(ffn_in_w[i]);
  } else {                                 // WF6: 64x128
    int i = idx - 11264 - 6144 - 16384;
    ((unsigned short*)(ws + OFF_WF6))[i] = f2bf(ffn_out_w[i]);
  }
}

// ---------------- K1 (MFMA, 128px blocks, gate via MFMA tile 10, bf16 weight table) ----------------
__global__ __launch_bounds__(256) void k1_mfma(
    const float* __restrict__ x, const float* __restrict__ ln1_w, const float* __restrict__ ln1_b,
    const unsigned short* __restrict__ wk1, const float* __restrict__ pre_b,
    const float* __restrict__ g1b, const float* __restrict__ g2w, const float* __restrict__ g2b,
    unsigned short* __restrict__ qkvl, unsigned short* __restrict__ LOCB,
    unsigned short* __restrict__ PREB, float* __restrict__ pooled, float* __restrict__ gsum)
{
  __shared__ unsigned short sXnb[128][68];   // 17.4 KB
  __shared__ unsigned short sStg[4][16][68]; // 8.7 KB
  __shared__ float sGateH[16][65];           // 4.2 KB  fp32 gate h staging
  __shared__ float sPoolL[32];
  const int tid = threadIdx.x;
  const int p0 = blockIdx.x * 128;
  const int b = p0 >> 16;
  const int hw0 = p0 & (HW - 1);
  if (tid < 32) sPoolL[tid] = 0.f;
  // ---- Phase A: register LN, float4 loads ----
  {
    const int px4 = tid >> 3;
    const int e8 = tid & 7;
    const float* xb = x + (size_t)(b * 64 + e8 * 8) * HW + hw0 + px4 * 4;
    float xv[8][4];
    float mu[4] = {0.f, 0.f, 0.f, 0.f};
#pragma unroll
    for (int j = 0; j < 8; ++j) {
      float4 v = *reinterpret_cast<const float4*>(xb + (size_t)j * HW);
      xv[j][0] = v.x; xv[j][1] = v.y; xv[j][2] = v.z; xv[j][3] = v.w;
      mu[0] += v.x; mu[1] += v.y; mu[2] += v.z; mu[3] += v.w;
    }
#pragma unroll
    for (int p = 0; p < 4; ++p) {
      mu[p] += __shfl_xor(mu[p], 1);
      mu[p] += __shfl_xor(mu[p], 2);
      mu[p] += __shfl_xor(mu[p], 4);
      mu[p] *= (1.f / 64.f);
    }
    float var[4] = {0.f, 0.f, 0.f, 0.f};
#pragma unroll
    for (int j = 0; j < 8; ++j)
#pragma unroll
      for (int p = 0; p < 4; ++p) {
        float d = xv[j][p] - mu[p];
        var[p] += d * d;
      }
    float rs[4];
#pragma unroll
    for (int p = 0; p < 4; ++p) {
      var[p] += __shfl_xor(var[p], 1);
      var[p] += __shfl_xor(var[p], 2);
      var[p] += __shfl_xor(var[p], 4);
      rs[p] = rsqrtf(var[p] * (1.f / 64.f) + 1e-5f);
    }
    float lw[8], lb[8];
#pragma unroll
    for (int j = 0; j < 8; ++j) { lw[j] = ln1_w[e8 * 8 + j]; lb[j] = ln1_b[e8 * 8 + j]; }
#pragma unroll
    for (int p = 0; p < 4; ++p) {
      union { short8v v; unsigned short s[8]; } u;
#pragma unroll
      for (int j = 0; j < 8; ++j)
        u.s[j] = f2bf((xv[j][p] - mu[p]) * rs[p] * lw[j] + lb[j]);
      *reinterpret_cast<short8v*>(&sXnb[px4 * 4 + p][e8 * 8]) = u.v;
    }
  }
  __syncthreads();
  const int w = tid >> 6, lane = tid & 63;
  const int col = lane & 15, kgrp = lane >> 4;
  float gateAcc = 0.f;
#pragma unroll
  for (int pass = 0; pass < 3; ++pass) {
    const int tile = pass * 4 + w;
    if (tile >= 11) continue;                 // wave-uniform
    const int og = tile * 16 + col;           // 0..175
    const unsigned short* wr = wk1 + og * 64;
    union { short8v v; unsigned short s[8]; } bw[2];
#pragma unroll
    for (int kk = 0; kk < 2; ++kk)
      bw[kk].v = *reinterpret_cast<const short8v*>(wr + kk * 32 + kgrp * 8);
    const float bias = (og >= 128 && og < 160) ? pre_b[og - 128] : 0.f;
    float poolAcc = 0.f;
#pragma unroll
    for (int pxsub = 0; pxsub < 2; ++pxsub) {
      f32x4 acc[4];
#pragma unroll
      for (int s = 0; s < 4; ++s) acc[s] = (f32x4){0.f, 0.f, 0.f, 0.f};
#pragma unroll
      for (int kk = 0; kk < 2; ++kk) {
        const int c0 = kk * 32 + kgrp * 8;
#pragma unroll
        for (int s = 0; s < 4; ++s) {
          short8v av = *reinterpret_cast<const short8v*>(&sXnb[pxsub * 64 + s * 16 + col][c0]);
          acc[s] = __builtin_amdgcn_mfma_f32_16x16x32_bf16(av, bw[kk].v, acc[s], 0, 0, 0);
        }
      }
      if (tile == 10) {
        const float gb = g1b[col];
#pragma unroll
        for (int s = 0; s < 4; ++s)
#pragma unroll
          for (int r = 0; r < 4; ++r)
            sGateH[col][s * 16 + kgrp * 4 + r] = acc[s][r] + gb;
        float gacc = g2b[0];
#pragma unroll
        for (int i = 0; i < 16; ++i)
          gacc += g2w[i] * fmaxf(sGateH[i][lane], 0.f);
        gateAcc += sigm(gacc);
      } else {
#pragma unroll
        for (int s = 0; s < 4; ++s) {
#pragma unroll
          for (int r = 0; r < 4; ++r) {
            float v = acc[s][r] + bias;
            sStg[w][col][s * 16 + kgrp * 4 + r] = f2bf(v);
            if (og < 32) poolAcc += v;
          }
        }
        if (og >= 32 && og < 128) {
          const int row = lane >> 2, seg = lane & 3;
          const unsigned short* src = &sStg[w][row][seg * 16];
          unsigned short* dst = qkvl + (size_t)(b * 96 + (tile - 2) * 16 + row) * HW
                                + hw0 + pxsub * 64 + seg * 16;
          *reinterpret_cast<short8v*>(dst) = *reinterpret_cast<const short8v*>(src);
          *reinterpret_cast<short8v*>(dst + 8) = *reinterpret_cast<const short8v*>(src + 8);
        } else {
          const int pxl = lane;
          union { short8v v; unsigned short s[8]; } u0, u1;
#pragma unroll
          for (int o = 0; o < 8; ++o) { u0.s[o] = sStg[w][o][pxl]; u1.s[o] = sStg[w][8 + o][pxl]; }
          unsigned short* base = (og < 32) ? LOCB : PREB;
          const int choff = (og < 32) ? (tile * 16) : ((tile - 8) * 16);
          unsigned short* dst = base + ((size_t)b * HW + hw0 + pxsub * 64 + pxl) * 32 + choff;
          *reinterpret_cast<short8v*>(dst) = u0.v;
          *reinterpret_cast<short8v*>(dst + 8) = u1.v;
        }
      }
    }
    if (og < 32) {
      poolAcc += __shfl_xor(poolAcc, 16);
      poolAcc += __shfl_xor(poolAcc, 32);
      if (kgrp == 0) sPoolL[og] = poolAcc;
    }
  }
  if (w == 2) {
    float gv = wredsum(gateAcc);
    if (lane == 0) atomicAdd(gsum, gv);
  }
  __syncthreads();
  if (tid < 32) atomicAdd(&pooled[b * 32 + tid], sPoolL[tid]);
}

// ---------------- K1 checker (parallel): 256 blocks x 1 sampled px ----------------
__global__ __launch_bounds__(256) void k1_check(
    const float* __restrict__ x, const float* __restrict__ ln1_w, const float* __restrict__ ln1_b,
    const float* __restrict__ in_proj_w, const float* __restrict__ qkv_w,
    const float* __restrict__ pre_w, const float* __restrict__ pre_b,
    const unsigned short* __restrict__ LOCB, const unsigned short* __restrict__ qkvl,
    const unsigned short* __restrict__ PREB, float* __restrict__ bad)
{
  __shared__ float sXv[64];
  __shared__ float sLc[32], sGl[32];
  const int blk = blockIdx.x;
  const int b = blk & 3;
  const int px = (blk * 1031) & (HW - 1);
  const int tid = threadIdx.x;
  if (tid < 64) sXv[tid] = x[(size_t)(b * 64 + tid) * HW + px];
  __syncthreads();
  if (tid < 64) {
    float v = sXv[tid];
    float mu = wredsum(v) * (1.f / 64.f);
    float d = v - mu;
    float var = wredsum(d * d) * (1.f / 64.f);
    float rs = rsqrtf(var + 1e-5f);
    sXv[tid] = d * rs * ln1_w[tid] + ln1_b[tid];
  }
  __syncthreads();
  if (tid < 64) {
    const int o = tid & 31;
    const int hi = tid >> 5;
    float s = 0.f;
#pragma unroll
    for (int c = 0; c < 64; ++c) s += in_proj_w[(hi * 32 + o) * 64 + c] * sXv[c];
    if (hi) sGl[o] = s; else sLc[o] = s;
  }
  __syncthreads();
  bool fail = false;
  if (tid < 32) {
    float s = sLc[tid];
    float got = bf2f(LOCB[((size_t)b * HW + px) * 32 + tid]);
    if (fabsf(got - s) > 0.05f + 0.05f * fabsf(s)) fail = true;
  } else if (tid < 128) {
    const int o = tid - 32;
    float s = 0.f;
#pragma unroll
    for (int j = 0; j < 32; ++j) s += qkv_w[o * 32 + j] * sGl[j];
    float got = bf2f(qkvl[(size_t)(b * 96 + o) * HW + px]);
    if (fabsf(got - s) > 0.05f + 0.05f * fabsf(s)) fail = true;
  } else if (tid < 160) {
    const int o = tid - 128;
    float s = pre_b[o];
#pragma unroll
    for (int j = 0; j < 32; ++j) s += pre_w[o * 32 + j] * sLc[j];
    float got = bf2f(PREB[((size_t)b * HW + px) * 32 + o]);
    if (fabsf(got - s) > 0.05f + 0.05f * fabsf(s)) fail = true;
  }
  if (fail) atomicExch(bad, 1.f);
}

// ---------------- K1 reset (only if checker failed) ----------------
__global__ __launch_bounds__(256) void k1r_reset(const float* __restrict__ bad, float* __restrict__ gsum)
{
  if (bad[0] < 0.5f) return;
  const int tid = threadIdx.x;
  if (tid < 129) gsum[tid] = 0.f;
}

// ---------------- K1 fallback (only if checker failed) ----------------
__global__ __launch_bounds__(256) void k1_fb(
    const float* __restrict__ x, const float* __restrict__ ln1_w, const float* __restrict__ ln1_b,
    const float* __restrict__ in_proj_w, const float* __restrict__ qkv_w,
    const float* __restrict__ pre_w, const float* __restrict__ pre_b,
    const float* __restrict__ g1w, const float* __restrict__ g1b,
    const float* __restrict__ g2w, const float* __restrict__ g2b,
    const float* __restrict__ bad,
    unsigned short* __restrict__ qkvl, unsigned short* __restrict__ LOCB,
    unsigned short* __restrict__ PREB, float* __restrict__ pooled, float* __restrict__ gsum)
{
  if (bad[0] < 0.5f) return;
  __shared__ float sPool[4][32];
  __shared__ float sRed[4];
  const int tid = threadIdx.x;
  const int p = blockIdx.x * 256 + tid;
  const int b = p >> 16;
  const int hw = p & (HW - 1);
  const int wave = tid >> 6, lane = tid & 63;
  const float* xb = x + (size_t)(b * 64) * HW + hw;
  float xv[64];
  float mu = 0.f;
#pragma unroll
  for (int c = 0; c < 64; ++c) { xv[c] = xb[(size_t)c * HW]; mu += xv[c]; }
  mu *= (1.f / 64.f);
  float var = 0.f;
#pragma unroll
  for (int c = 0; c < 64; ++c) { float d = xv[c] - mu; var += d * d; }
  var *= (1.f / 64.f);
  const float rs = rsqrtf(var + 1e-5f);
#pragma unroll
  for (int c = 0; c < 64; ++c) xv[c] = (xv[c] - mu) * rs * ln1_w[c] + ln1_b[c];
  float loc[32];
  for (int o = 0; o < 32; ++o) {
    float s = 0.f;
#pragma unroll
    for (int c = 0; c < 64; ++c) s += in_proj_w[o * 64 + c] * xv[c];
    loc[o] = s;
    LOCB[((size_t)b * HW + hw) * 32 + o] = f2bf(s);
    float r = wredsum(s);
    if (lane == 0) sPool[wave][o] = r;
  }
  for (int o = 0; o < 32; ++o) {
    float s = pre_b[o];
#pragma unroll
    for (int j = 0; j < 32; ++j) s += pre_w[o * 32 + j] * loc[j];
    PREB[((size_t)b * HW + hw) * 32 + o] = f2bf(s);
  }
  float gl[32];
  for (int o = 0; o < 32; ++o) {
    float s = 0.f;
#pragma unroll
    for (int c = 0; c < 64; ++c) s += in_proj_w[(32 + o) * 64 + c] * xv[c];
    gl[o] = s;
  }
  for (int o = 0; o < 96; ++o) {
    float s = 0.f;
#pragma unroll
    for (int j = 0; j < 32; ++j) s += qkv_w[o * 32 + j] * gl[j];
    qkvl[(size_t)(b * 96 + o) * HW + hw] = f2bf(s);
  }
  float gacc = g2b[0];
  for (int o = 0; o < 16; ++o) {
    float h = g1b[o];
#pragma unroll
    for (int j = 0; j < 32; ++j) h += g1w[o * 32 + j] * gl[j];
    gacc += g2w[o] * fmaxf(h, 0.f);
  }
  float gv = wredsum(sigm(gacc));
  if (lane == 0) sRed[wave] = gv;
  __syncthreads();
  if (tid == 0) atomicAdd(gsum, sRed[0] + sRed[1] + sRed[2] + sRed[3]);
  if (tid < 32) {
    float s = sPool[0][tid] + sPool[1][tid] + sPool[2][tid] + sPool[3][tid];
    atomicAdd(&pooled[b * 32 + tid], s);
  }
}

// ---------------- K2 (MFMA): dwconv(q,k) + Gram via V·V^T — vectorized row loads ----------------
__global__ __launch_bounds__(256) void k2_mfma(
    const unsigned short* __restrict__ qkvl, const float* __restrict__ qkv_dw, float* __restrict__ gram)
{
  __shared__ float sred[4][256];
  const int tid = threadIdx.x;
  const int slab = blockIdx.x;
  const int h = blockIdx.y, b = blockIdx.z;
  const int w = tid >> 6, lane = tid & 63;
  const int ch = lane & 15, grp = lane >> 4;
  const int gch = (ch < 8) ? (h * 8 + ch) : (32 + h * 8 + (ch - 8));
  const unsigned short* plane = qkvl + (size_t)(b * 96 + gch) * HW;
  const float* wt = qkv_dw + gch * 9;
  float w9[9];
#pragma unroll
  for (int t = 0; t < 9; ++t) w9[t] = wt[t];
  f32x4 acc = (f32x4){0.f, 0.f, 0.f, 0.f};
#pragma unroll
  for (int iter = 0; iter < 4; ++iter) {
    const int pxbase = slab * 512 + w * 128 + iter * 32 + grp * 8;
    const int y = pxbase >> 8;
    const int x0 = pxbase & 255;
    float row[3][10];
#pragma unroll
    for (int dy = 0; dy < 3; ++dy) {
      const int yy = y + dy - 1;
      if ((unsigned)yy >= 256u) {
#pragma unroll
        for (int j = 0; j < 10; ++j) row[dy][j] = 0.f;
        continue;
      }
      const unsigned short* rp = plane + yy * 256;
      union { short8v v; unsigned short s[8]; } cu;
      cu.v = *reinterpret_cast<const short8v*>(rp + x0);
#pragma unroll
      for (int j = 0; j < 8; ++j) row[dy][j + 1] = bf2f(cu.s[j]);
      row[dy][0] = (x0 > 0) ? bf2f(rp[x0 - 1]) : 0.f;
      row[dy][9] = (x0 < 248) ? bf2f(rp[x0 + 8]) : 0.f;
    }
    union { short8v v; unsigned short s[8]; } frag;
#pragma unroll
    for (int j = 0; j < 8; ++j) {
      float a = 0.f;
#pragma unroll
      for (int dy = 0; dy < 3; ++dy)
#pragma unroll
        for (int dx = 0; dx < 3; ++dx)
          a += row[dy][j + dx] * w9[dy * 3 + dx];
      frag.s[j] = f2bf(a);
    }
    acc = __builtin_amdgcn_mfma_f32_16x16x32_bf16(frag.v, frag.v, acc, 0, 0, 0);
  }
#pragma unroll
  for (int r = 0; r < 4; ++r) sred[w][(grp * 4 + r) * 16 + ch] = acc[r];
  __syncthreads();
  if (tid < 256) {
    float g = sred[0][tid] + sred[1][tid] + sred[2][tid] + sred[3][tid];
    const int row_ = tid >> 4, col_ = tid & 15;
    int idx = -1;
    if (row_ < 8 && col_ >= 8) idx = row_ * 8 + (col_ - 8);
    else if (row_ == col_ && row_ < 8) idx = 64 + row_;
    else if (row_ == col_) idx = 72 + (row_ - 8);
    if (idx >= 0) atomicAdd(&gram[(b * 4 + h) * 80 + idx], g);
  }
}

// ---------------- K3: dk, CBAM weights, attention matrices ----------------
__global__ __launch_bounds__(256) void k3_final(
    const float* __restrict__ m1w, const float* __restrict__ m1b,
    const float* __restrict__ m2w, const float* __restrict__ m2b,
    const float* __restrict__ temperature, const float* __restrict__ attn_scales,
    const float* __restrict__ pre_w, const float* __restrict__ pre_b,
    const float* __restrict__ gsum, const float* __restrict__ pooled,
    const float* __restrict__ gram, float* __restrict__ Abuf, float* __restrict__ cwbuf)
{
  __shared__ int s_dk;
  __shared__ float s_scale;
  const int tid = threadIdx.x;
  if (tid == 0) {
    float gmean = gsum[0] / (float)NPIX;
    int dk = (int)floorf(8.f * gmean);
    if (dk < 1) dk = 1;
    if (dk > 8) dk = 8;
    s_dk = dk;
    s_scale = attn_scales[0] + attn_scales[1] + attn_scales[2] + attn_scales[3];
  }
  __syncthreads();
  if (tid < 128) {
    int b = tid >> 5, ch = tid & 31, g = ch >> 2, c = ch & 3;
    float h1 = m1b[g];
#pragma unroll
    for (int cc = 0; cc < 4; ++cc) {
      int row = g * 4 + cc;
      float pp = pre_b[row];
#pragma unroll
      for (int j = 0; j < 32; ++j)
        pp += pre_w[row * 32 + j] * (pooled[b * 32 + j] * (1.f / 65536.f));
      h1 += pp * m1w[g * 4 + cc];
    }
    h1 = fmaxf(h1, 0.f);
    cwbuf[tid] = sigm(h1 * m2w[g * 4 + c] + m2b[g * 4 + c]);

    int r = tid, h = (r >> 3) & 3, c8 = r & 7;
    const float* gm = gram + (b * 4 + h) * 80;
    float qn = fmaxf(sqrtf(gm[64 + c8]), 1e-12f);
    float temp = temperature[h];
    float a[8];
#pragma unroll
    for (int d = 0; d < 8; ++d) {
      float kn = fmaxf(sqrtf(gm[72 + d]), 1e-12f);
      a[d] = gm[c8 * 8 + d] / (qn * kn) * temp;
    }
    float t[8];
#pragma unroll
    for (int d = 0; d < 8; ++d) t[d] = a[d];
#pragma unroll
    for (int i = 0; i < 8; ++i)
#pragma unroll
      for (int j = 0; j < 8; ++j)
        if (j > i && t[j] > t[i]) { float tmp = t[i]; t[i] = t[j]; t[j] = tmp; }
    float kth = t[s_dk - 1];
    float mx = t[0];
    float e[8]; float sum = 0.f;
#pragma unroll
    for (int d = 0; d < 8; ++d) {
      e[d] = (a[d] >= kth) ? expf(a[d] - mx) : 0.f;
      sum += e[d];
    }
    float inv = s_scale / sum;
#pragma unroll
    for (int d = 0; d < 8; ++d) Abuf[r * 8 + d] = e[d] * inv;
  }
}

// ---------------- K4a: resp partial sums (atomic-free), PREB bf16 ----------------
__global__ __launch_bounds__(256) void k4a_thr(
    const float* __restrict__ spw, const float* __restrict__ spb,
    const float* __restrict__ cwbuf, const unsigned short* __restrict__ PREB,
    float* __restrict__ wpart)
{
  const int tid = threadIdx.x;
  const int pxb = blockIdx.x >> 1;
  const int gh = blockIdx.x & 1;
  const int px = pxb * 256 + tid;
  const int b = px >> 16, hw = px & (HW - 1);
  const int w = tid >> 6, lane = tid & 63;
  const float* cw = cwbuf + b * 32;
  const unsigned short* pp = PREB + ((size_t)b * HW + hw) * 32 + gh * 16;
  union { short8v v; unsigned short s[8]; } u0, u1;
  u0.v = *reinterpret_cast<const short8v*>(pp);
  u1.v = *reinterpret_cast<const short8v*>(pp + 8);
  float pv[16];
#pragma unroll
  for (int k = 0; k < 8; ++k) { pv[k] = bf2f(u0.s[k]); pv[8 + k] = bf2f(u1.s[k]); }
  float racc[4];
#pragma unroll
  for (int g4 = 0; g4 < 4; ++g4) {
    const int g = gh * 4 + g4;
    float xa[4];
    float sdot = spb[g];
#pragma unroll
    for (int c = 0; c < 4; ++c) {
      xa[c] = pv[g4 * 4 + c] * cw[g * 4 + c];
      sdot += xa[c] * spw[g * 4 + c];
    }
    float sgv = sigm(sdot);
    float r = 0.f;
#pragma unroll
    for (int c = 0; c < 4; ++c) r += sigm(xa[c] * sgv);
    racc[g4] = r;
  }
#pragma unroll
  for (int g4 = 0; g4 < 4; ++g4) {
    float v = wredsum(racc[g4]);
    if (lane == 0) wpart[(blockIdx.x * 4 + w) * 4 + g4] = v;
  }
}

// ---------------- K4a_red: reduce wpart -> thrbuf ----------------
__global__ __launch_bounds__(256) void k4a_red(
    const float* __restrict__ wpart, float* __restrict__ thrbuf)
{
  __shared__ float sr[256];
  const int tid = threadIdx.x;
  const int b = blockIdx.x >> 3, g = blockIdx.x & 7;
  const int gh = g >> 2, gl = g & 3;
  float s = 0.f;
#pragma unroll
  for (int w = 0; w < 4; ++w)
    s += wpart[((((size_t)(b * 256 + tid) * 2 + gh) * 4) + w) * 4 + gl];
  sr[tid] = s;
  __syncthreads();
  for (int st = 128; st >= 1; st >>= 1) {
    if (tid < st) sr[tid] += sr[tid + st];
    __syncthreads();
  }
  if (tid == 0) thrbuf[b * 8 + g] = sr[0];
}

// ---------------- K4b (MFMA): V-dwconv + LGCE finish + attn -> A96 MFMA (bf16 W96 table) ----------------
__global__ __launch_bounds__(256) void k4b_fuse(
    const float* __restrict__ x, const float* __restrict__ spw, const float* __restrict__ spb,
    const float* __restrict__ qkv_dw, const unsigned short* __restrict__ qkvl,
    const unsigned short* __restrict__ LOCB, const unsigned short* __restrict__ PREB,
    const float* __restrict__ Abuf, const float* __restrict__ cwbuf, const float* __restrict__ thrbuf,
    const unsigned short* __restrict__ wb96, const float* __restrict__ cb,
    float* __restrict__ dout)
{
  __shared__ float sV[64][33];
  __shared__ unsigned short sA[64][104];
  __shared__ float sOut[64][65];
  const int tid = threadIdx.x;
  const int p0 = blockIdx.x * 64;
  const int b = p0 >> 16;
  const int hw0 = p0 & (HW - 1);
  const int yrow = hw0 >> 8;
  const int x0b = hw0 & 255;
  {
    const int j = tid >> 3;
    const int seg = tid & 7;
    const int x0 = x0b + seg * 8;
    const unsigned short* plane = qkvl + (size_t)(b * 96 + 64 + j) * HW;
    const float* wt = qkv_dw + (64 + j) * 9;
    float w9[9];
#pragma unroll
    for (int t = 0; t < 9; ++t) w9[t] = wt[t];
    float row[3][10];
#pragma unroll
    for (int dy = 0; dy < 3; ++dy) {
      const int yy = yrow + dy - 1;
      if ((unsigned)yy >= 256u) {
#pragma unroll
        for (int k = 0; k < 10; ++k) row[dy][k] = 0.f;
        continue;
      }
      const unsigned short* rp = plane + yy * 256;
      union { short8v v; unsigned short s[8]; } cu;
      cu.v = *reinterpret_cast<const short8v*>(rp + x0);
#pragma unroll
      for (int k = 0; k < 8; ++k) row[dy][k + 1] = bf2f(cu.s[k]);
      row[dy][0] = (x0 > 0) ? bf2f(rp[x0 - 1]) : 0.f;
      row[dy][9] = (x0 < 248) ? bf2f(rp[x0 + 8]) : 0.f;
    }
#pragma unroll
    for (int p = 0; p < 8; ++p) {
      float s = 0.f;
#pragma unroll
      for (int dy = 0; dy < 3; ++dy)
#pragma unroll
        for (int dx = 0; dx < 3; ++dx)
          s += row[dy][p + dx] * w9[dy * 3 + dx];
      sV[seg * 8 + p][j] = s;
    }
  }
  __syncthreads();
  const int px_l = tid & 63, q = tid >> 6;
  const int hw = hw0 + px_l;
  const float* cw = cwbuf + b * 32;
  const float* A = Abuf + b * 256;
  union { short8v v; unsigned short s[8]; } lv, pvv;
  lv.v = *reinterpret_cast<const short8v*>(LOCB + ((size_t)b * HW + hw) * 32 + q * 8);
  pvv.v = *reinterpret_cast<const short8v*>(PREB + ((size_t)b * HW + hw) * 32 + q * 8);
  float pre8[8];
#pragma unroll
  for (int j = 0; j < 8; ++j) pre8[j] = bf2f(pvv.s[j]);
  union { short8v v; unsigned short s[8]; } mxv;
#pragma unroll
  for (int g2 = 0; g2 < 2; ++g2) {
    const int g = 2 * q + g2;
    float xa[4];
    float sdot = spb[g];
#pragma unroll
    for (int c = 0; c < 4; ++c) {
      xa[c] = pre8[g2 * 4 + c] * cw[g * 4 + c];
      sdot += xa[c] * spw[g * 4 + c];
    }
    float sgv = sigm(sdot);
    float thr = thrbuf[b * 8 + g] * (1.f / (4.f * 65536.f));
#pragma unroll
    for (int c = 0; c < 4; ++c) {
      float resp = sigm(xa[c] * sgv);
      float m = (resp > thr) ? 1.f : resp;
      mxv.s[g2 * 4 + c] = f2bf(pre8[g2 * 4 + c] * m);
    }
  }
  float v8[8];
#pragma unroll
  for (int j = 0; j < 8; ++j) v8[j] = sV[px_l][q * 8 + j];
  union { short8v v; unsigned short s[8]; } attv;
#pragma unroll
  for (int j = 0; j < 8; ++j) {
    float s = 0.f;
#pragma unroll
    for (int d = 0; d < 8; ++d) s += A[(q * 8 + j) * 8 + d] * v8[d];
    attv.s[j] = f2bf(s);
  }
  *reinterpret_cast<short8v*>(&sA[px_l][q * 8]) = attv.v;
  *reinterpret_cast<short8v*>(&sA[px_l][32 + q * 8]) = mxv.v;
  *reinterpret_cast<short8v*>(&sA[px_l][64 + q * 8]) = lv.v;
  __syncthreads();
  const int w = q, lane = tid & 63;
  const int col = lane & 15, kgrp = lane >> 4;
  const int og = w * 16 + col;
  f32x4 acc[4];
#pragma unroll
  for (int s = 0; s < 4; ++s) acc[s] = (f32x4){0.f, 0.f, 0.f, 0.f};
#pragma unroll
  for (int kk = 0; kk < 3; ++kk) {
    const int c0 = kk * 32 + kgrp * 8;
    union { short8v v; unsigned short s[8]; } bw;
    bw.v = *reinterpret_cast<const short8v*>(wb96 + og * 96 + c0);
#pragma unroll
    for (int s = 0; s < 4; ++s) {
      short8v av = *reinterpret_cast<const short8v*>(&sA[s * 16 + col][c0]);
      acc[s] = __builtin_amdgcn_mfma_f32_16x16x32_bf16(av, bw.v, acc[s], 0, 0, 0);
    }
  }
#pragma unroll
  for (int s = 0; s < 4; ++s) {
#pragma unroll
    for (int r = 0; r < 4; ++r) {
      int pxl = s * 16 + kgrp * 4 + r;
      sOut[og][pxl] = acc[s][r];
    }
  }
  __syncthreads();
  const float* xb = x + (size_t)(b * 64) * HW + hw0;
  float* db = dout + (size_t)(b * 64) * HW + hw0;
#pragma unroll
  for (int i = 0; i < 16; ++i) {
    int idx = tid + i * 256;
    int o = idx >> 6, px = idx & 63;
    db[(size_t)o * HW + px] = sOut[o][px] + cb[o] + xb[(size_t)o * HW + px];
  }
}

// ---------------- K5 (MFMA): LN2 + ffn_in (64->256), bf16 weight table on identity path ----------------
__global__ __launch_bounds__(256) void k5_mfma(
    const float* __restrict__ ln2_w, const float* __restrict__ ln2_b,
    const float* __restrict__ ffn_in_w, const unsigned short* __restrict__ wf5,
    const float* __restrict__ flag, const float* __restrict__ dout,
    unsigned short* __restrict__ Tb, int b)
{
  __shared__ float sShared[4352];            // sStage (fp32), later reused as sOutB (bf16, 128 rows)
  __shared__ unsigned short sXnb[64][68];
  __shared__ float sMu[64], sRs[64];
  float (*sStage)[65] = reinterpret_cast<float(*)[65]>(sShared);
  unsigned short (*sOutB)[68] = reinterpret_cast<unsigned short(*)[68]>(sShared);
  const int tid = threadIdx.x;
  const int px0 = blockIdx.x * 64;
  const bool idf = flag[0] > 0.5f;
  const float* db = dout + (size_t)(b * 64) * HW + px0;
#pragma unroll
  for (int i = 0; i < 4; ++i) {
    int idx = tid + i * 256;                 // 0..1023
    int c = idx >> 4, px4 = (idx & 15) * 4;
    float4 v = *reinterpret_cast<const float4*>(db + (size_t)c * HW + px4);
    sStage[px4][c] = v.x;
    sStage[px4 + 1][c] = v.y;
    sStage[px4 + 2][c] = v.z;
    sStage[px4 + 3][c] = v.w;
  }
  __syncthreads();
  if (tid < 64) {
    float mu = 0.f;
#pragma unroll
    for (int c = 0; c < 64; ++c) mu += sStage[tid][c];
    mu *= (1.f / 64.f);
    float var = 0.f;
#pragma unroll
    for (int c = 0; c < 64; ++c) { float d = sStage[tid][c] - mu; var += d * d; }
    var *= (1.f / 64.f);
    sMu[tid] = mu;
    sRs[tid] = rsqrtf(var + 1e-5f);
  }
  __syncthreads();
#pragma unroll
  for (int i = 0; i < 16; ++i) {
    int idx = tid + i * 256;
    int px = idx >> 6, c = idx & 63;
    float xn = (sStage[px][c] - sMu[px]) * sRs[px] * ln2_w[c] + ln2_b[c];
    sXnb[px][c] = f2bf(xn);
  }
  __syncthreads();   // sStage dead; sOutB takes over the region
  const int w = tid >> 6, lane = tid & 63;
  const int col = lane & 15, kgrp = lane >> 4;
#pragma unroll
  for (int mp = 0; mp < 2; ++mp) {
#pragma unroll
    for (int pass = 0; pass < 2; ++pass) {
      const int o_l = pass * 64 + w * 16 + col;   // 0..127 within macro-pass
      const int og = mp * 128 + o_l;
      f32x4 acc[4];
#pragma unroll
      for (int s = 0; s < 4; ++s) acc[s] = (f32x4){0.f, 0.f, 0.f, 0.f};
#pragma unroll
      for (int kk = 0; kk < 2; ++kk) {
        const int c0 = kk * 32 + kgrp * 8;
        union { short8v v; unsigned short s[8]; } bw;
        if (idf) {
          bw.v = *reinterpret_cast<const short8v*>(wf5 + (size_t)og * 64 + c0);
        } else {
          const float* wp = ffn_in_w + (size_t)og * 64 + c0;
#pragma unroll
          for (int j = 0; j < 8; ++j) bw.s[j] = f2bf(wp[j]);
        }
#pragma unroll
        for (int s = 0; s < 4; ++s) {
          short8v av = *reinterpret_cast<const short8v*>(&sXnb[s * 16 + col][c0]);
          acc[s] = __builtin_amdgcn_mfma_f32_16x16x32_bf16(av, bw.v, acc[s], 0, 0, 0);
        }
      }
#pragma unroll
      for (int s = 0; s < 4; ++s) {
#pragma unroll
        for (int r = 0; r < 4; ++r) {
          int px_l = s * 16 + kgrp * 4 + r;
          sOutB[o_l][px_l] = f2bf(acc[s][r]);
        }
      }
    }
    __syncthreads();
    for (int i = tid; i < 1024; i += 256) {
      int o = i >> 3, seg = i & 7;
      *reinterpret_cast<short8v*>(Tb + (size_t)(mp * 128 + o) * HW + px0 + seg * 8) =
          *reinterpret_cast<const short8v*>(&sOutB[o][seg * 8]);
    }
    __syncthreads();   // before next macro-pass overwrites sOutB
  }
}

// ---------------- K6a: dwconv3/dwconv5 + gelu*mul -> Y (bf16), 1 ch x 2 rows per thread ----------------
__global__ __launch_bounds__(256) void k6a_dw(
    const float* __restrict__ dw3_w, const float* __restrict__ dw5_w,
    const unsigned short* __restrict__ T, unsigned short* __restrict__ Y)
{
  const int idx = blockIdx.x * 256 + threadIdx.x;  // 524288 threads (grid 2048)
  const int j = idx >> 12;          // channel 0..127 (wave-uniform)
  const int rem = idx & 4095;
  const int y0 = (rem >> 5) * 2;    // output row pair base 0,2,..,254
  const int x0 = (rem & 31) * 8;    // col start, multiple of 8
  float m[2][8];
  const unsigned short* pm = T + (size_t)(128 + j) * HW;
  if (j < 64) {
    const float* wt = dw3_w + (128 + j) * 9;
    float w9[9];
#pragma unroll
    for (int t = 0; t < 9; ++t) w9[t] = wt[t];
    float row[4][10];
#pragma unroll
    for (int r = 0; r < 4; ++r) {
      const int yy = y0 + r - 1;
      if ((unsigned)yy >= 256u) {
#pragma unroll
        for (int k = 0; k < 10; ++k) row[r][k] = 0.f;
        continue;
      }
      const unsigned short* rp = pm + yy * 256;
      union { short8v v; unsigned short s[8]; } cu;
      cu.v = *reinterpret_cast<const short8v*>(rp + x0);
#pragma unroll
      for (int k = 0; k < 8; ++k) row[r][k + 1] = bf2f(cu.s[k]);
      row[r][0] = (x0 > 0) ? bf2f(rp[x0 - 1]) : 0.f;
      row[r][9] = (x0 < 248) ? bf2f(rp[x0 + 8]) : 0.f;
    }
#pragma unroll
    for (int t = 0; t < 2; ++t)
#pragma unroll
      for (int p = 0; p < 8; ++p) {
        float s = 0.f;
#pragma unroll
        for (int dy = 0; dy < 3; ++dy)
#pragma unroll
          for (int dx = 0; dx < 3; ++dx)
            s += row[t + dy][p + dx] * w9[dy * 3 + dx];
        m[t][p] = s;
      }
  } else {
    const float* wt = dw5_w + (j - 64) * 25;
    float w25[25];
#pragma unroll
    for (int t = 0; t < 25; ++t) w25[t] = wt[t];
    float row[6][12];
#pragma unroll
    for (int r = 0; r < 6; ++r) {
      const int yy = y0 + r - 2;
      if ((unsigned)yy >= 256u) {
#pragma unroll
        for (int k = 0; k < 12; ++k) row[r][k] = 0.f;
        continue;
      }
      const unsigned short* rp = pm + yy * 256;
      union { short8v v; unsigned short s[8]; } cu;
      cu.v = *reinterpret_cast<const short8v*>(rp + x0);
#pragma unroll
      for (int k = 0; k < 8; ++k) row[r][k + 2] = bf2f(cu.s[k]);
      row[r][0] = (x0 > 0) ? bf2f(rp[x0 - 2]) : 0.f;
      row[r][1] = (x0 > 0) ? bf2f(rp[x0 - 1]) : 0.f;
      row[r][10] = (x0 < 248) ? bf2f(rp[x0 + 8]) : 0.f;
      row[r][11] = (x0 < 248) ? bf2f(rp[x0 + 9]) : 0.f;
    }
#pragma unroll
    for (int t = 0; t < 2; ++t)
#pragma unroll
      for (int p = 0; p < 8; ++p) {
        float s = 0.f;
#pragma unroll
        for (int dy = 0; dy < 5; ++dy)
#pragma unroll
          for (int dx = 0; dx < 5; ++dx)
            s += row[t + dy][p + dx] * w25[dy * 5 + dx];
        m[t][p] = s;
      }
  }
  float a[2][8];
  {
    const unsigned short* pa = T + (size_t)j * HW;
    const float* wt = dw3_w + j * 9;
    float w9[9];
#pragma unroll
    for (int t = 0; t < 9; ++t) w9[t] = wt[t];
    float row[4][10];
#pragma unroll
    for (int r = 0; r < 4; ++r) {
      const int yy = y0 + r - 1;
      if ((unsigned)yy >= 256u) {
#pragma unroll
        for (int k = 0; k < 10; ++k) row[r][k] = 0.f;
        continue;
      }
      const unsigned short* rp = pa + yy * 256;
      union { short8v v; unsigned short s[8]; } cu;
      cu.v = *reinterpret_cast<const short8v*>(rp + x0);
#pragma unroll
      for (int k = 0; k < 8; ++k) row[r][k + 1] = bf2f(cu.s[k]);
      row[r][0] = (x0 > 0) ? bf2f(rp[x0 - 1]) : 0.f;
      row[r][9] = (x0 < 248) ? bf2f(rp[x0 + 8]) : 0.f;
    }
#pragma unroll
    for (int t = 0; t < 2; ++t)
#pragma unroll
      for (int p = 0; p < 8; ++p) {
        float s = 0.f;
#pragma unroll
        for (int dy = 0; dy < 3; ++dy)
#pragma unroll
          for (int dx = 0; dx < 3; ++dx)
            s += row[t + dy][p + dx] * w9[dy * 3 + dx];
        a[t][p] = s;
      }
  }
#pragma unroll
  for (int t = 0; t < 2; ++t) {
    union { short8v v; unsigned short s[8]; } out;
#pragma unroll
    for (int p = 0; p < 8; ++p) {
      float gl = 0.5f * a[t][p] * (1.f + erff(a[t][p] * 0.70710678118654752f));
      out.s[p] = f2bf(gl * m[t][p]);
    }
    *reinterpret_cast<short8v*>(Y + (size_t)j * HW + (y0 + t) * 256 + x0) = out.v;
  }
}

// ---------------- K6b (MFMA): ffn_out (128->64), Y staged once in LDS, K=128 ----------------
__global__ __launch_bounds__(256) void k6b_mfma(
    const float* __restrict__ ffn_out_w, const unsigned short* __restrict__ wf6,
    const unsigned short* __restrict__ Y,
    const float* __restrict__ flag, float* __restrict__ dout, float* __restrict__ Z, int b)
{
  __shared__ unsigned short sY[64][136];   // 17.4 KB [px][128ch]
  __shared__ float sOut[64][65];           // 16.6 KB
  const int tid = threadIdx.x;
  const int px0 = blockIdx.x * 64;
  const bool idf = flag[0] > 0.5f;
#pragma unroll
  for (int i = 0; i < 4; ++i) {
    const int t = tid + i * 256;
    const int ch = t >> 3, seg = t & 7;
    union { short8v v; unsigned short s[8]; } u;
    u.v = *reinterpret_cast<const short8v*>(Y + (size_t)ch * HW + px0 + seg * 8);
#pragma unroll
    for (int p = 0; p < 8; ++p) sY[seg * 8 + p][ch] = u.s[p];
  }
  __syncthreads();
  const int w = tid >> 6, lane = tid & 63;
  const int col = lane & 15, kgrp = lane >> 4;
  const int og = w * 16 + col;               // 0..63
  f32x4 acc[4];
#pragma unroll
  for (int s = 0; s < 4; ++s) acc[s] = (f32x4){0.f, 0.f, 0.f, 0.f};
#pragma unroll
  for (int kk = 0; kk < 4; ++kk) {
    const int c0 = kk * 32 + kgrp * 8;
    union { short8v v; unsigned short s[8]; } bw;
    if (idf) {
      bw.v = *reinterpret_cast<const short8v*>(wf6 + (size_t)og * 128 + c0);
    } else {
      const float* wp = ffn_out_w + (size_t)og * 128 + c0;
#pragma unroll
      for (int j = 0; j < 8; ++j) bw.s[j] = f2bf(wp[j]);
    }
#pragma unroll
    for (int s = 0; s < 4; ++s) {
      short8v av = *reinterpret_cast<const short8v*>(&sY[s * 16 + col][c0]);
      acc[s] = __builtin_amdgcn_mfma_f32_16x16x32_bf16(av, bw.v, acc[s], 0, 0, 0);
    }
  }
#pragma unroll
  for (int s = 0; s < 4; ++s) {
#pragma unroll
    for (int r = 0; r < 4; ++r) {
      int pxl = s * 16 + kgrp * 4 + r;
      sOut[og][pxl] = acc[s][r];
    }
  }
  __syncthreads();
  if (idf) {
    float* db = dout + (size_t)(b * 64) * HW + px0;
#pragma unroll
    for (int i = 0; i < 16; ++i) {
      int idx = tid + i * 256;
      int o = idx >> 6, px = idx & 63;
      db[(size_t)o * HW + px] += sOut[o][px];
    }
  } else {
    float* zb = Z + px0;
#pragma unroll
    for (int i = 0; i < 16; ++i) {
      int idx = tid + i * 256;
      int o = idx >> 6, px = idx & 63;
      zb[(size_t)o * HW + px] = sOut[o][px];
    }
  }
}

// ---------------- K7: general fft path, 8 patch-groups per block (early-exit if identity) ----------------
__global__ __launch_bounds__(256) void k7_fft(
    const float* __restrict__ fftw, const float* __restrict__ flag,
    const float* __restrict__ Z, float* __restrict__ dout, int b)
{
  if (flag[0] > 0.5f) return;
  __shared__ float swv[64];
  __shared__ float spatch[4][64];
  const int tid = threadIdx.x;
  const int c = blockIdx.x >> 5;        // channel 0..63 (grid 2048)
  const int pblk0 = (blockIdx.x & 31) * 8;
  if (tid < 64) swv[tid] = fftw[c * 64 + tid];
  const int lp = tid >> 6, e = tid & 63;
  const int i = e >> 3, jj = e & 7;
  for (int pg = 0; pg < 8; ++pg) {
    const int patch = (pblk0 + pg) * 4 + lp;
    const int pi = patch >> 5, pj = patch & 31;
    const int gidx = (pi * 8 + i) * 256 + pj * 8 + jj;
    const float zv = Z[(size_t)c * HW + gidx];
    spatch[lp][e] = zv;
    __syncthreads();
    float s = 0.f;
#pragma unroll
    for (int a = 0; a < 8; ++a)
#pragma unroll
      for (int b2 = 0; b2 < 8; ++b2)
        s += swv[a * 8 + b2] * spatch[lp][((i - a) & 7) * 8 + ((jj - b2) & 7)];
    dout[(size_t)(b * 64 + c) * HW + gidx] += s;
    __syncthreads();
  }
}

extern "C" void kernel_launch(void* const* d_in, const int* in_sizes, int n_in,
                              void* d_out, int out_size, void* d_ws, size_t ws_size,
                              hipStream_t stream) {
  const float* x          = (const float*)d_in[0];
  const float* ln1_w      = (const float*)d_in[1];
  const float* ln1_b      = (const float*)d_in[2];
  const float* in_proj_w  = (const float*)d_in[3];
  const float* qkv_w      = (const float*)d_in[4];
  const float* qkv_dw     = (const float*)d_in[5];
  const float* out_proj_w = (const float*)d_in[6];
  const float* temperature= (const float*)d_in[7];
  const float* attn_scales= (const float*)d_in[8];
  const float* gate_w1    = (const float*)d_in[9];
  const float* gate_b1    = (const float*)d_in[10];
  const float* gate_w2    = (const float*)d_in[11];
  const float* gate_b2    = (const float*)d_in[12];
  const float* lgce_pre_w = (const float*)d_in[13];
  const float* lgce_pre_b = (const float*)d_in[14];
  const float* lgce_post_w= (const float*)d_in[15];
  const float* lgce_post_b= (const float*)d_in[16];
  const float* cbam_m1w   = (const float*)d_in[17];
  const float* cbam_m1b   = (const float*)d_in[18];
  const float* cbam_m2w   = (const float*)d_in[19];
  const float* cbam_m2b   = (const float*)d_in[20];
  const float* cbam_spw   = (const float*)d_in[21];
  const float* cbam_spb   = (const float*)d_in[22];
  const float* ln2_w      = (const float*)d_in[23];
  const float* ln2_b      = (const float*)d_in[24];
  const float* ffn_in_w   = (const float*)d_in[25];
  const float* dw3_w      = (const float*)d_in[26];
  const float* dw5_w      = (const float*)d_in[27];
  const float* ffn_out_w  = (const float*)d_in[28];
  const float* fft_W      = (const float*)d_in[29];
  float* ws = (float*)d_ws;
  float* out = (float*)d_out;
  unsigned short* qkvlp = (unsigned short*)(ws + OFF_QKVL);
  unsigned short* LOCB = (unsigned short*)(ws + OFF_LOCB);
  unsigned short* PREB = (unsigned short*)(ws + OFF_PREB);
  unsigned short* Tb = (unsigned short*)(ws + OFF_T);
  unsigned short* Ybuf = (unsigned short*)(ws + OFF_Y);

  hipLaunchKernelGGL(k0_par, dim3(15), dim3(256), 0, stream,
                     fft_W, in_proj_w, qkv_w, gate_w1, lgce_pre_w,
                     out_proj_w, lgce_post_w, lgce_post_b, ws);
  hipLaunchKernelGGL(k0b_tables, dim3(164), dim3(256), 0, stream,
                     in_proj_w, ffn_in_w, ffn_out_w, ws);
  hipLaunchKernelGGL(k1_mfma, dim3(2048), dim3(256), 0, stream,
                     x, ln1_w, ln1_b, (unsigned short*)(ws + OFF_WK1), lgce_pre_b,
                     gate_b1, gate_w2, gate_b2,
                     qkvlp, LOCB, PREB, ws + OFF_POOL, ws + OFF_GSUM);
  hipLaunchKernelGGL(k1_check, dim3(256), dim3(256), 0, stream,
                     x, ln1_w, ln1_b, in_proj_w, qkv_w, lgce_pre_w, lgce_pre_b,
                     LOCB, qkvlp, PREB, ws + OFF_BAD);
  hipLaunchKernelGGL(k1r_reset, dim3(1), dim3(256), 0, stream,
                     ws + OFF_BAD, ws + OFF_GSUM);
  hipLaunchKernelGGL(k1_fb, dim3(1024), dim3(256), 0, stream,
                     x, ln1_w, ln1_b, in_proj_w, qkv_w, lgce_pre_w, lgce_pre_b,
                     gate_w1, gate_b1, gate_w2, gate_b2,
                     ws + OFF_BAD, qkvlp, LOCB, PREB, ws + OFF_POOL, ws + OFF_GSUM);
  hipLaunchKernelGGL(k2_mfma, dim3(128, 4, 4), dim3(256), 0, stream,
                     qkvlp, qkv_dw, ws + OFF_GRAM);
  hipLaunchKernelGGL(k3_final, dim3(1), dim3(256), 0, stream,
                     cbam_m1w, cbam_m1b, cbam_m2w, cbam_m2b, temperature, attn_scales,
                     lgce_pre_w, lgce_pre_b,
                     ws + OFF_GSUM, ws + OFF_POOL, ws + OFF_GRAM, ws + OFF_A, ws + OFF_CW);
  hipLaunchKernelGGL(k4a_thr, dim3(2048), dim3(256), 0, stream,
                     cbam_spw, cbam_spb, ws + OFF_CW, PREB, ws + OFF_PART);
  hipLaunchKernelGGL(k4a_red, dim3(32), dim3(256), 0, stream,
                     ws + OFF_PART, ws + OFF_THR);
  hipLaunchKernelGGL(k4b_fuse, dim3(4096), dim3(256), 0, stream,
                     x, cbam_spw, cbam_spb, qkv_dw, qkvlp, LOCB, PREB,
                     ws + OFF_A, ws + OFF_CW, ws + OFF_THR,
                     (unsigned short*)(ws + OFF_WB96), ws + OFF_CB, out);

  for (int b = 0; b < 4; ++b) {
    hipLaunchKernelGGL(k5_mfma, dim3(1024), dim3(256), 0, stream,
                       ln2_w, ln2_b, ffn_in_w, (unsigned short*)(ws + OFF_WF5),
                       ws + OFF_FLAG, out, Tb, b);
    hipLaunchKernelGGL(k6a_dw, dim3(2048), dim3(256), 0, stream,
                       dw3_w, dw5_w, Tb, Ybuf);
    hipLaunchKernelGGL(k6b_mfma, dim3(1024), dim3(256), 0, stream,
                       ffn_out_w, (unsigned short*)(ws + OFF_WF6), Ybuf,
                       ws + OFF_FLAG, out, ws + OFF_Z, b);
    hipLaunchKernelGGL(k7_fft, dim3(2048), dim3(256), 0, stream,
                       ws + OFF_FFTW, ws + OFF_FLAG, ws + OFF_Z, out, b);
  }
}

// Round 26
// 412.805 us; speedup vs baseline: 1.1607x; 1.0226x over previous
//
#include <hip/hip_runtime.h>
#include <hip/hip_bf16.h>
#include <math.h>

#define HW 65536
#define NPIX 262144

// ---- workspace layout (float offsets) ----
#define OFF_FFTW 0            // 64x64 spatial fft kernel
#define OFF_FLAG 4096         // 1
#define OFF_GSUM 4097         // 1    (zeroed in k0_par blk8)
#define OFF_POOL 4098         // 128
#define OFF_GRAM 4226         // 1280
#define OFF_THR  5506         // 32
#define OFF_BAD  5538         // 1
#define OFF_A    5539         // 1024 (k3 output; slots 0..7 reused transiently as k0 okslots)
#define OFF_CW   6563         // 128
#define OFF_QKVL 8192         // 96ch * 262144 px bf16 = 12582912 float-slots (SGSA phase)
#define OFF_MQKV 12591104     // 96*64 fp32 composed qkv matrix
#define OFF_MG1  (OFF_MQKV + 6144)     // 16*64 fp32  (ends 12598272)
#define OFF_MPRE 12598272     // 32*64 fp32 composed pre matrix (ends 12600320)
#define OFF_PREB 12600320     // [4][65536][32] bf16 px-major = 4194304 slots (ends 16794624)
#define OFF_LOCB 16794624     // [4][65536][32] bf16 px-major = 4194304 slots (ends 20988928)
#define OFF_PART 20988928     // 2048 blk * 4 waves * 4 g = 32768 (ends 21021696)
#define OFF_W96  21021696     // 64*96 fp32 composed out_proj|post matrix (SGSA phase only)
#define OFF_CB   (OFF_W96 + 6144)      // 64 fp32 (ends 21027904)
// bf16 weight tables (inside Z region, above SGSA max 21027904):
//  WK1/WB96 consumed in SGSA phase only. WF5/WF6 consumed in MFFN only on
//  identity path (flag==1 -> Z never written); fallback re-converts from fp32.
#define OFF_WB96 21027904     // 64*96 bf16 = 3072 float-slots (ends 21030976)
#define OFF_WF5  21030976     // 256*64 bf16 = 8192 slots (ends 21039168)
#define OFF_WF6  21039168     // 64*128 bf16 = 4096 slots (ends 21043264)
#define OFF_WK1  21043264     // 176*64 bf16 = 5632 slots (ends 21048896 < 25174016)
// MFFN phase (per-batch, overlaps QKVL/PREB/LOCB/W96 which are dead by then):
#define OFF_T    8192                      // 256ch * 65536 bf16
#define OFF_Y    (OFF_T + 16777216)        // 128ch * 65536 bf16
#define OFF_Z    (OFF_Y + 4194304)         // 64ch * 65536 fp32
// peak ws usage = 25174016 floats = 100.7 MB (unchanged proven footprint)

typedef __attribute__((ext_vector_type(8))) short short8v;
typedef __attribute__((ext_vector_type(4))) float f32x4;

__device__ __forceinline__ float sigm(float v) { return 1.f / (1.f + expf(-v)); }
__device__ __forceinline__ float wredsum(float v) {
#pragma unroll
  for (int off = 32; off >= 1; off >>= 1) v += __shfl_xor(v, off);
  return v;
}
__device__ __forceinline__ unsigned short f2bf(float f) {
  union { float f; unsigned u; } x; x.f = f;
  unsigned r = x.u + 0x7fffu + ((x.u >> 16) & 1u);
  return (unsigned short)(r >> 16);
}
__device__ __forceinline__ float bf2f(unsigned short u) {
  union { unsigned u; float f; } x; x.u = ((unsigned)u) << 16;
  return x.f;
}

// ---------------- K0 (parallel, grid 15): zero + composed matrices + fft kernel/check ----------------
// blocks 0..7: FFTW 512 elems each + per-block ok -> okslot ws[OFF_A + blk]
// block 8: zero accumulators; 9..10: MQKV; 11: MG1+MPRE; 12..13: W96; 14: CB
__global__ __launch_bounds__(256) void k0_par(
    const float* __restrict__ fft_W, const float* __restrict__ in_proj_w,
    const float* __restrict__ qkv_w, const float* __restrict__ g1w,
    const float* __restrict__ pre_w, const float* __restrict__ out_proj_w,
    const float* __restrict__ post_w, const float* __restrict__ post_b,
    float* __restrict__ ws)
{
  const int tid = threadIdx.x;
  const int blk = blockIdx.x;
  if (blk < 8) {
    __shared__ float ct8[8];
    __shared__ int sbad;
    if (tid < 8) ct8[tid] = cosf((float)tid * 0.78539816339744831f);
    if (tid == 0) sbad = 0;
    __syncthreads();
    bool ok = true;
#pragma unroll
    for (int k = 0; k < 2; ++k) {
      const int i = blk * 512 + k * 256 + tid;
      const int ch = i >> 6, ab = i & 63;
      const int a = ab >> 3, b2 = ab & 7;
      float s = 0.f;
      for (int u = 0; u < 8; ++u)
        for (int v = 0; v < 8; ++v) {
          float Wf;
          if (v == 0 || v == 4)
            Wf = 0.5f * (fft_W[ch * 40 + u * 5 + v] + fft_W[ch * 40 + ((8 - u) & 7) * 5 + v]);
          else if (v < 5)
            Wf = fft_W[ch * 40 + u * 5 + v];
          else
            Wf = fft_W[ch * 40 + ((8 - u) & 7) * 5 + (8 - v)];
          s += Wf * ct8[(u * a + v * b2) & 7];
        }
      s *= (1.f / 64.f);
      ws[OFF_FFTW + i] = s;
      float expect = ((i & 63) == 0) ? 1.f : 0.f;
      if (fabsf(s - expect) > 1e-4f) ok = false;
    }
    if (!ok) atomicOr(&sbad, 1);
    __syncthreads();
    if (tid == 0) ws[OFF_A + blk] = sbad ? 0.f : 1.f;
  } else if (blk == 8) {
    for (int i = tid; i < 1442; i += 256) ws[OFF_GSUM + i] = 0.f;
  } else if (blk <= 10) {
    const int base = (blk - 9) * 3072;
    for (int t = tid; t < 3072; t += 256) {
      int i = base + t;
      int o = i >> 6, c = i & 63;
      float s = 0.f;
      for (int j = 0; j < 32; ++j) s += qkv_w[o * 32 + j] * in_proj_w[(32 + j) * 64 + c];
      ws[OFF_MQKV + i] = s;
    }
  } else if (blk == 11) {
    for (int i = tid; i < 16 * 64; i += 256) {
      int o = i >> 6, c = i & 63;
      float s = 0.f;
      for (int j = 0; j < 32; ++j) s += g1w[o * 32 + j] * in_proj_w[(32 + j) * 64 + c];
      ws[OFF_MG1 + i] = s;
    }
    for (int i = tid; i < 32 * 64; i += 256) {
      int o = i >> 6, c = i & 63;
      float s = 0.f;
      for (int j = 0; j < 32; ++j) s += pre_w[o * 32 + j] * in_proj_w[j * 64 + c];
      ws[OFF_MPRE + i] = s;
    }
  } else if (blk <= 13) {
    const int base = (blk - 12) * 3072;
    for (int t = tid; t < 3072; t += 256) {
      int i = base + t;
      int o = i / 96, c = i - o * 96;
      float s;
      if (c < 32) s = out_proj_w[o * 64 + c];
      else if (c < 64) {
        s = 0.f;
        for (int k = 0; k < 32; ++k) s += out_proj_w[o * 64 + 32 + k] * post_w[k * 32 + (c - 32)];
      } else s = out_proj_w[o * 64 + (c - 32)];
      ws[OFF_W96 + i] = s;
    }
  } else {
    if (tid < 64) {
      float s = 0.f;
      for (int k = 0; k < 32; ++k) s += out_proj_w[tid * 64 + 32 + k] * post_b[k];
      ws[OFF_CB + tid] = s;
    }
  }
}

// ---------------- K0b: bf16 weight tables (parallel) + FLAG from okslots ----------------
__global__ __launch_bounds__(256) void k0b_tables(
    const float* __restrict__ in_proj_w, const float* __restrict__ ffn_in_w,
    const float* __restrict__ ffn_out_w, float* __restrict__ ws)
{
  const int idx = blockIdx.x * 256 + threadIdx.x;
  if (idx == 0) {
    float f = 1.f;
#pragma unroll
    for (int k = 0; k < 8; ++k)
      if (ws[OFF_A + k] < 0.5f) f = 0.f;
    ws[OFF_FLAG] = f;
  }
  if (idx < 11264) {                       // WK1: 176x64
    int o = idx >> 6, c = idx & 63;
    float v = (o < 32) ? in_proj_w[o * 64 + c]
            : (o < 128) ? ws[OFF_MQKV + (o - 32) * 64 + c]
            : (o < 160) ? ws[OFF_MPRE + (o - 128) * 64 + c]
                        : ws[OFF_MG1 + (o - 160) * 64 + c];
    ((unsigned short*)(ws + OFF_WK1))[idx] = f2bf(v);
  } else if (idx < 11264 + 6144) {         // WB96: 64x96
    int i = idx - 11264;
    ((unsigned short*)(ws + OFF_WB96))[i] = f2bf(ws[OFF_W96 + i]);
  } else if (idx < 11264 + 6144 + 16384) { // WF5: 256x64
    int i = idx - 11264 - 6144;
    ((unsigned short*)(ws + OFF_WF5))[i] = f2bf(ffn_in_w[i]);
  } else {                                 // WF6: 64x128
    int i = idx - 11264 - 6144 - 16384;
    ((unsigned short*)(ws + OFF_WF6))[i] = f2bf(ffn_out_w[i]);
  }
}

// ---------------- K1 (MFMA, 128px blocks, gate via MFMA tile 10, bf16 weight table) ----------------
__global__ __launch_bounds__(256) void k1_mfma(
    const float* __restrict__ x, const float* __restrict__ ln1_w, const float* __restrict__ ln1_b,
    const unsigned short* __restrict__ wk1, const float* __restrict__ pre_b,
    const float* __restrict__ g1b, const float* __restrict__ g2w, const float* __restrict__ g2b,
    unsigned short* __restrict__ qkvl, unsigned short* __restrict__ LOCB,
    unsigned short* __restrict__ PREB, float* __restrict__ pooled, float* __restrict__ gsum)
{
  __shared__ unsigned short sXnb[128][68];   // 17.4 KB
  __shared__ unsigned short sStg[4][16][68]; // 8.7 KB
  __shared__ float sGateH[16][65];           // 4.2 KB  fp32 gate h staging
  __shared__ float sPoolL[32];
  const int tid = threadIdx.x;
  const int p0 = blockIdx.x * 128;
  const int b = p0 >> 16;
  const int hw0 = p0 & (HW - 1);
  if (tid < 32) sPoolL[tid] = 0.f;
  // ---- Phase A: register LN, float4 loads ----
  {
    const int px4 = tid >> 3;
    const int e8 = tid & 7;
    const float* xb = x + (size_t)(b * 64 + e8 * 8) * HW + hw0 + px4 * 4;
    float xv[8][4];
    float mu[4] = {0.f, 0.f, 0.f, 0.f};
#pragma unroll
    for (int j = 0; j < 8; ++j) {
      float4 v = *reinterpret_cast<const float4*>(xb + (size_t)j * HW);
      xv[j][0] = v.x; xv[j][1] = v.y; xv[j][2] = v.z; xv[j][3] = v.w;
      mu[0] += v.x; mu[1] += v.y; mu[2] += v.z; mu[3] += v.w;
    }
#pragma unroll
    for (int p = 0; p < 4; ++p) {
      mu[p] += __shfl_xor(mu[p], 1);
      mu[p] += __shfl_xor(mu[p], 2);
      mu[p] += __shfl_xor(mu[p], 4);
      mu[p] *= (1.f / 64.f);
    }
    float var[4] = {0.f, 0.f, 0.f, 0.f};
#pragma unroll
    for (int j = 0; j < 8; ++j)
#pragma unroll
      for (int p = 0; p < 4; ++p) {
        float d = xv[j][p] - mu[p];
        var[p] += d * d;
      }
    float rs[4];
#pragma unroll
    for (int p = 0; p < 4; ++p) {
      var[p] += __shfl_xor(var[p], 1);
      var[p] += __shfl_xor(var[p], 2);
      var[p] += __shfl_xor(var[p], 4);
      rs[p] = rsqrtf(var[p] * (1.f / 64.f) + 1e-5f);
    }
    float lw[8], lb[8];
#pragma unroll
    for (int j = 0; j < 8; ++j) { lw[j] = ln1_w[e8 * 8 + j]; lb[j] = ln1_b[e8 * 8 + j]; }
#pragma unroll
    for (int p = 0; p < 4; ++p) {
      union { short8v v; unsigned short s[8]; } u;
#pragma unroll
      for (int j = 0; j < 8; ++j)
        u.s[j] = f2bf((xv[j][p] - mu[p]) * rs[p] * lw[j] + lb[j]);
      *reinterpret_cast<short8v*>(&sXnb[px4 * 4 + p][e8 * 8]) = u.v;
    }
  }
  __syncthreads();
  const int w = tid >> 6, lane = tid & 63;
  const int col = lane & 15, kgrp = lane >> 4;
  float gateAcc = 0.f;
#pragma unroll
  for (int pass = 0; pass < 3; ++pass) {
    const int tile = pass * 4 + w;
    if (tile >= 11) continue;                 // wave-uniform
    const int og = tile * 16 + col;           // 0..175
    const unsigned short* wr = wk1 + og * 64;
    union { short8v v; unsigned short s[8]; } bw[2];
#pragma unroll
    for (int kk = 0; kk < 2; ++kk)
      bw[kk].v = *reinterpret_cast<const short8v*>(wr + kk * 32 + kgrp * 8);
    const float bias = (og >= 128 && og < 160) ? pre_b[og - 128] : 0.f;
    float poolAcc = 0.f;
#pragma unroll
    for (int pxsub = 0; pxsub < 2; ++pxsub) {
      f32x4 acc[4];
#pragma unroll
      for (int s = 0; s < 4; ++s) acc[s] = (f32x4){0.f, 0.f, 0.f, 0.f};
#pragma unroll
      for (int kk = 0; kk < 2; ++kk) {
        const int c0 = kk * 32 + kgrp * 8;
#pragma unroll
        for (int s = 0; s < 4; ++s) {
          short8v av = *reinterpret_cast<const short8v*>(&sXnb[pxsub * 64 + s * 16 + col][c0]);
          acc[s] = __builtin_amdgcn_mfma_f32_16x16x32_bf16(av, bw[kk].v, acc[s], 0, 0, 0);
        }
      }
      if (tile == 10) {
        const float gb = g1b[col];
#pragma unroll
        for (int s = 0; s < 4; ++s)
#pragma unroll
          for (int r = 0; r < 4; ++r)
            sGateH[col][s * 16 + kgrp * 4 + r] = acc[s][r] + gb;
        float gacc = g2b[0];
#pragma unroll
        for (int i = 0; i < 16; ++i)
          gacc += g2w[i] * fmaxf(sGateH[i][lane], 0.f);
        gateAcc += sigm(gacc);
      } else {
#pragma unroll
        for (int s = 0; s < 4; ++s) {
#pragma unroll
          for (int r = 0; r < 4; ++r) {
            float v = acc[s][r] + bias;
            sStg[w][col][s * 16 + kgrp * 4 + r] = f2bf(v);
            if (og < 32) poolAcc += v;
          }
        }
        if (og >= 32 && og < 128) {
          const int row = lane >> 2, seg = lane & 3;
          const unsigned short* src = &sStg[w][row][seg * 16];
          unsigned short* dst = qkvl + (size_t)(b * 96 + (tile - 2) * 16 + row) * HW
                                + hw0 + pxsub * 64 + seg * 16;
          *reinterpret_cast<short8v*>(dst) = *reinterpret_cast<const short8v*>(src);
          *reinterpret_cast<short8v*>(dst + 8) = *reinterpret_cast<const short8v*>(src + 8);
        } else {
          const int pxl = lane;
          union { short8v v; unsigned short s[8]; } u0, u1;
#pragma unroll
          for (int o = 0; o < 8; ++o) { u0.s[o] = sStg[w][o][pxl]; u1.s[o] = sStg[w][8 + o][pxl]; }
          unsigned short* base = (og < 32) ? LOCB : PREB;
          const int choff = (og < 32) ? (tile * 16) : ((tile - 8) * 16);
          unsigned short* dst = base + ((size_t)b * HW + hw0 + pxsub * 64 + pxl) * 32 + choff;
          *reinterpret_cast<short8v*>(dst) = u0.v;
          *reinterpret_cast<short8v*>(dst + 8) = u1.v;
        }
      }
    }
    if (og < 32) {
      poolAcc += __shfl_xor(poolAcc, 16);
      poolAcc += __shfl_xor(poolAcc, 32);
      if (kgrp == 0) sPoolL[og] = poolAcc;
    }
  }
  if (w == 2) {
    float gv = wredsum(gateAcc);
    if (lane == 0) atomicAdd(gsum, gv);
  }
  __syncthreads();
  if (tid < 32) atomicAdd(&pooled[b * 32 + tid], sPoolL[tid]);
}

// ---------------- K1 checker (parallel): 256 blocks x 1 sampled px ----------------
__global__ __launch_bounds__(256) void k1_check(
    const float* __restrict__ x, const float* __restrict__ ln1_w, const float* __restrict__ ln1_b,
    const float* __restrict__ in_proj_w, const float* __restrict__ qkv_w,
    const float* __restrict__ pre_w, const float* __restrict__ pre_b,
    const unsigned short* __restrict__ LOCB, const unsigned short* __restrict__ qkvl,
    const unsigned short* __restrict__ PREB, float* __restrict__ bad)
{
  __shared__ float sXv[64];
  __shared__ float sLc[32], sGl[32];
  const int blk = blockIdx.x;
  const int b = blk & 3;
  const int px = (blk * 1031) & (HW - 1);
  const int tid = threadIdx.x;
  if (tid < 64) sXv[tid] = x[(size_t)(b * 64 + tid) * HW + px];
  __syncthreads();
  if (tid < 64) {
    float v = sXv[tid];
    float mu = wredsum(v) * (1.f / 64.f);
    float d = v - mu;
    float var = wredsum(d * d) * (1.f / 64.f);
    float rs = rsqrtf(var + 1e-5f);
    sXv[tid] = d * rs * ln1_w[tid] + ln1_b[tid];
  }
  __syncthreads();
  if (tid < 64) {
    const int o = tid & 31;
    const int hi = tid >> 5;
    float s = 0.f;
#pragma unroll
    for (int c = 0; c < 64; ++c) s += in_proj_w[(hi * 32 + o) * 64 + c] * sXv[c];
    if (hi) sGl[o] = s; else sLc[o] = s;
  }
  __syncthreads();
  bool fail = false;
  if (tid < 32) {
    float s = sLc[tid];
    float got = bf2f(LOCB[((size_t)b * HW + px) * 32 + tid]);
    if (fabsf(got - s) > 0.05f + 0.05f * fabsf(s)) fail = true;
  } else if (tid < 128) {
    const int o = tid - 32;
    float s = 0.f;
#pragma unroll
    for (int j = 0; j < 32; ++j) s += qkv_w[o * 32 + j] * sGl[j];
    float got = bf2f(qkvl[(size_t)(b * 96 + o) * HW + px]);
    if (fabsf(got - s) > 0.05f + 0.05f * fabsf(s)) fail = true;
  } else if (tid < 160) {
    const int o = tid - 128;
    float s = pre_b[o];
#pragma unroll
    for (int j = 0; j < 32; ++j) s += pre_w[o * 32 + j] * sLc[j];
    float got = bf2f(PREB[((size_t)b * HW + px) * 32 + o]);
    if (fabsf(got - s) > 0.05f + 0.05f * fabsf(s)) fail = true;
  }
  if (fail) atomicExch(bad, 1.f);
}

// ---------------- K1 reset (only if checker failed) ----------------
__global__ __launch_bounds__(256) void k1r_reset(const float* __restrict__ bad, float* __restrict__ gsum)
{
  if (bad[0] < 0.5f) return;
  const int tid = threadIdx.x;
  if (tid < 129) gsum[tid] = 0.f;
}

// ---------------- K1 fallback (only if checker failed) ----------------
__global__ __launch_bounds__(256) void k1_fb(
    const float* __restrict__ x, const float* __restrict__ ln1_w, const float* __restrict__ ln1_b,
    const float* __restrict__ in_proj_w, const float* __restrict__ qkv_w,
    const float* __restrict__ pre_w, const float* __restrict__ pre_b,
    const float* __restrict__ g1w, const float* __restrict__ g1b,
    const float* __restrict__ g2w, const float* __restrict__ g2b,
    const float* __restrict__ bad,
    unsigned short* __restrict__ qkvl, unsigned short* __restrict__ LOCB,
    unsigned short* __restrict__ PREB, float* __restrict__ pooled, float* __restrict__ gsum)
{
  if (bad[0] < 0.5f) return;
  __shared__ float sPool[4][32];
  __shared__ float sRed[4];
  const int tid = threadIdx.x;
  const int p = blockIdx.x * 256 + tid;
  const int b = p >> 16;
  const int hw = p & (HW - 1);
  const int wave = tid >> 6, lane = tid & 63;
  const float* xb = x + (size_t)(b * 64) * HW + hw;
  float xv[64];
  float mu = 0.f;
#pragma unroll
  for (int c = 0; c < 64; ++c) { xv[c] = xb[(size_t)c * HW]; mu += xv[c]; }
  mu *= (1.f / 64.f);
  float var = 0.f;
#pragma unroll
  for (int c = 0; c < 64; ++c) { float d = xv[c] - mu; var += d * d; }
  var *= (1.f / 64.f);
  const float rs = rsqrtf(var + 1e-5f);
#pragma unroll
  for (int c = 0; c < 64; ++c) xv[c] = (xv[c] - mu) * rs * ln1_w[c] + ln1_b[c];
  float loc[32];
  for (int o = 0; o < 32; ++o) {
    float s = 0.f;
#pragma unroll
    for (int c = 0; c < 64; ++c) s += in_proj_w[o * 64 + c] * xv[c];
    loc[o] = s;
    LOCB[((size_t)b * HW + hw) * 32 + o] = f2bf(s);
    float r = wredsum(s);
    if (lane == 0) sPool[wave][o] = r;
  }
  for (int o = 0; o < 32; ++o) {
    float s = pre_b[o];
#pragma unroll
    for (int j = 0; j < 32; ++j) s += pre_w[o * 32 + j] * loc[j];
    PREB[((size_t)b * HW + hw) * 32 + o] = f2bf(s);
  }
  float gl[32];
  for (int o = 0; o < 32; ++o) {
    float s = 0.f;
#pragma unroll
    for (int c = 0; c < 64; ++c) s += in_proj_w[(32 + o) * 64 + c] * xv[c];
    gl[o] = s;
  }
  for (int o = 0; o < 96; ++o) {
    float s = 0.f;
#pragma unroll
    for (int j = 0; j < 32; ++j) s += qkv_w[o * 32 + j] * gl[j];
    qkvl[(size_t)(b * 96 + o) * HW + hw] = f2bf(s);
  }
  float gacc = g2b[0];
  for (int o = 0; o < 16; ++o) {
    float h = g1b[o];
#pragma unroll
    for (int j = 0; j < 32; ++j) h += g1w[o * 32 + j] * gl[j];
    gacc += g2w[o] * fmaxf(h, 0.f);
  }
  float gv = wredsum(sigm(gacc));
  if (lane == 0) sRed[wave] = gv;
  __syncthreads();
  if (tid == 0) atomicAdd(gsum, sRed[0] + sRed[1] + sRed[2] + sRed[3]);
  if (tid < 32) {
    float s = sPool[0][tid] + sPool[1][tid] + sPool[2][tid] + sPool[3][tid];
    atomicAdd(&pooled[b * 32 + tid], s);
  }
}

// ---------------- K2 (MFMA): dwconv(q,k) + Gram via V·V^T — 2 vertically-adjacent rows/lane ----------------
// slab = 2 image rows (512 px). Per lane: 2 x-steps, each loading 4 input rows and
// producing 2 row-fragments (outputs y0,y0+1) -> 8 row-loads vs 12 (old mapping).
// px partition across (w,t,grp) covers each px exactly once; gram is px-order-independent.
__global__ __launch_bounds__(256) void k2_mfma(
    const unsigned short* __restrict__ qkvl, const float* __restrict__ qkv_dw, float* __restrict__ gram)
{
  __shared__ float sred[4][256];
  const int tid = threadIdx.x;
  const int slab = blockIdx.x;          // 128 slabs x 2 rows
  const int h = blockIdx.y, b = blockIdx.z;
  const int w = tid >> 6, lane = tid & 63;
  const int ch = lane & 15, grp = lane >> 4;
  const int gch = (ch < 8) ? (h * 8 + ch) : (32 + h * 8 + (ch - 8));
  const unsigned short* plane = qkvl + (size_t)(b * 96 + gch) * HW;
  const float* wt = qkv_dw + gch * 9;
  float w9[9];
#pragma unroll
  for (int t = 0; t < 9; ++t) w9[t] = wt[t];
  f32x4 acc = (f32x4){0.f, 0.f, 0.f, 0.f};
  const int y0 = slab * 2;
#pragma unroll
  for (int t = 0; t < 2; ++t) {
    const int x0 = w * 64 + t * 32 + grp * 8;
    float row[4][10];
#pragma unroll
    for (int r = 0; r < 4; ++r) {
      const int yy = y0 + r - 1;
      if ((unsigned)yy >= 256u) {
#pragma unroll
        for (int j = 0; j < 10; ++j) row[r][j] = 0.f;
        continue;
      }
      const unsigned short* rp = plane + yy * 256;
      union { short8v v; unsigned short s[8]; } cu;
      cu.v = *reinterpret_cast<const short8v*>(rp + x0);
#pragma unroll
      for (int j = 0; j < 8; ++j) row[r][j + 1] = bf2f(cu.s[j]);
      row[r][0] = (x0 > 0) ? bf2f(rp[x0 - 1]) : 0.f;
      row[r][9] = (x0 < 248) ? bf2f(rp[x0 + 8]) : 0.f;
    }
#pragma unroll
    for (int rr = 0; rr < 2; ++rr) {
      union { short8v v; unsigned short s[8]; } frag;
#pragma unroll
      for (int j = 0; j < 8; ++j) {
        float a = 0.f;
#pragma unroll
        for (int dy = 0; dy < 3; ++dy)
#pragma unroll
          for (int dx = 0; dx < 3; ++dx)
            a += row[rr + dy][j + dx] * w9[dy * 3 + dx];
        frag.s[j] = f2bf(a);
      }
      acc = __builtin_amdgcn_mfma_f32_16x16x32_bf16(frag.v, frag.v, acc, 0, 0, 0);
    }
  }
#pragma unroll
  for (int r = 0; r < 4; ++r) sred[w][(grp * 4 + r) * 16 + ch] = acc[r];
  __syncthreads();
  if (tid < 256) {
    float g = sred[0][tid] + sred[1][tid] + sred[2][tid] + sred[3][tid];
    const int row_ = tid >> 4, col_ = tid & 15;
    int idx = -1;
    if (row_ < 8 && col_ >= 8) idx = row_ * 8 + (col_ - 8);
    else if (row_ == col_ && row_ < 8) idx = 64 + row_;
    else if (row_ == col_) idx = 72 + (row_ - 8);
    if (idx >= 0) atomicAdd(&gram[(b * 4 + h) * 80 + idx], g);
  }
}

// ---------------- K3: dk, CBAM weights, attention matrices ----------------
__global__ __launch_bounds__(256) void k3_final(
    const float* __restrict__ m1w, const float* __restrict__ m1b,
    const float* __restrict__ m2w, const float* __restrict__ m2b,
    const float* __restrict__ temperature, const float* __restrict__ attn_scales,
    const float* __restrict__ pre_w, const float* __restrict__ pre_b,
    const float* __restrict__ gsum, const float* __restrict__ pooled,
    const float* __restrict__ gram, float* __restrict__ Abuf, float* __restrict__ cwbuf)
{
  __shared__ int s_dk;
  __shared__ float s_scale;
  const int tid = threadIdx.x;
  if (tid == 0) {
    float gmean = gsum[0] / (float)NPIX;
    int dk = (int)floorf(8.f * gmean);
    if (dk < 1) dk = 1;
    if (dk > 8) dk = 8;
    s_dk = dk;
    s_scale = attn_scales[0] + attn_scales[1] + attn_scales[2] + attn_scales[3];
  }
  __syncthreads();
  if (tid < 128) {
    int b = tid >> 5, ch = tid & 31, g = ch >> 2, c = ch & 3;
    float h1 = m1b[g];
#pragma unroll
    for (int cc = 0; cc < 4; ++cc) {
      int row = g * 4 + cc;
      float pp = pre_b[row];
#pragma unroll
      for (int j = 0; j < 32; ++j)
        pp += pre_w[row * 32 + j] * (pooled[b * 32 + j] * (1.f / 65536.f));
      h1 += pp * m1w[g * 4 + cc];
    }
    h1 = fmaxf(h1, 0.f);
    cwbuf[tid] = sigm(h1 * m2w[g * 4 + c] + m2b[g * 4 + c]);

    int r = tid, h = (r >> 3) & 3, c8 = r & 7;
    const float* gm = gram + (b * 4 + h) * 80;
    float qn = fmaxf(sqrtf(gm[64 + c8]), 1e-12f);
    float temp = temperature[h];
    float a[8];
#pragma unroll
    for (int d = 0; d < 8; ++d) {
      float kn = fmaxf(sqrtf(gm[72 + d]), 1e-12f);
      a[d] = gm[c8 * 8 + d] / (qn * kn) * temp;
    }
    float t[8];
#pragma unroll
    for (int d = 0; d < 8; ++d) t[d] = a[d];
#pragma unroll
    for (int i = 0; i < 8; ++i)
#pragma unroll
      for (int j = 0; j < 8; ++j)
        if (j > i && t[j] > t[i]) { float tmp = t[i]; t[i] = t[j]; t[j] = tmp; }
    float kth = t[s_dk - 1];
    float mx = t[0];
    float e[8]; float sum = 0.f;
#pragma unroll
    for (int d = 0; d < 8; ++d) {
      e[d] = (a[d] >= kth) ? expf(a[d] - mx) : 0.f;
      sum += e[d];
    }
    float inv = s_scale / sum;
#pragma unroll
    for (int d = 0; d < 8; ++d) Abuf[r * 8 + d] = e[d] * inv;
  }
}

// ---------------- K4a: resp partial sums (atomic-free), PREB bf16 ----------------
__global__ __launch_bounds__(256) void k4a_thr(
    const float* __restrict__ spw, const float* __restrict__ spb,
    const float* __restrict__ cwbuf, const unsigned short* __restrict__ PREB,
    float* __restrict__ wpart)
{
  const int tid = threadIdx.x;
  const int pxb = blockIdx.x >> 1;
  const int gh = blockIdx.x & 1;
  const int px = pxb * 256 + tid;
  const int b = px >> 16, hw = px & (HW - 1);
  const int w = tid >> 6, lane = tid & 63;
  const float* cw = cwbuf + b * 32;
  const unsigned short* pp = PREB + ((size_t)b * HW + hw) * 32 + gh * 16;
  union { short8v v; unsigned short s[8]; } u0, u1;
  u0.v = *reinterpret_cast<const short8v*>(pp);
  u1.v = *reinterpret_cast<const short8v*>(pp + 8);
  float pv[16];
#pragma unroll
  for (int k = 0; k < 8; ++k) { pv[k] = bf2f(u0.s[k]); pv[8 + k] = bf2f(u1.s[k]); }
  float racc[4];
#pragma unroll
  for (int g4 = 0; g4 < 4; ++g4) {
    const int g = gh * 4 + g4;
    float xa[4];
    float sdot = spb[g];
#pragma unroll
    for (int c = 0; c < 4; ++c) {
      xa[c] = pv[g4 * 4 + c] * cw[g * 4 + c];
      sdot += xa[c] * spw[g * 4 + c];
    }
    float sgv = sigm(sdot);
    float r = 0.f;
#pragma unroll
    for (int c = 0; c < 4; ++c) r += sigm(xa[c] * sgv);
    racc[g4] = r;
  }
#pragma unroll
  for (int g4 = 0; g4 < 4; ++g4) {
    float v = wredsum(racc[g4]);
    if (lane == 0) wpart[(blockIdx.x * 4 + w) * 4 + g4] = v;
  }
}

// ---------------- K4a_red: reduce wpart -> thrbuf ----------------
__global__ __launch_bounds__(256) void k4a_red(
    const float* __restrict__ wpart, float* __restrict__ thrbuf)
{
  __shared__ float sr[256];
  const int tid = threadIdx.x;
  const int b = blockIdx.x >> 3, g = blockIdx.x & 7;
  const int gh = g >> 2, gl = g & 3;
  float s = 0.f;
#pragma unroll
  for (int w = 0; w < 4; ++w)
    s += wpart[((((size_t)(b * 256 + tid) * 2 + gh) * 4) + w) * 4 + gl];
  sr[tid] = s;
  __syncthreads();
  for (int st = 128; st >= 1; st >>= 1) {
    if (tid < st) sr[tid] += sr[tid + st];
    __syncthreads();
  }
  if (tid == 0) thrbuf[b * 8 + g] = sr[0];
}

// ---------------- K4b (MFMA): V-dwconv + LGCE finish + attn -> A96 MFMA (bf16 W96 table) ----------------
__global__ __launch_bounds__(256) void k4b_fuse(
    const float* __restrict__ x, const float* __restrict__ spw, const float* __restrict__ spb,
    const float* __restrict__ qkv_dw, const unsigned short* __restrict__ qkvl,
    const unsigned short* __restrict__ LOCB, const unsigned short* __restrict__ PREB,
    const float* __restrict__ Abuf, const float* __restrict__ cwbuf, const float* __restrict__ thrbuf,
    const unsigned short* __restrict__ wb96, const float* __restrict__ cb,
    float* __restrict__ dout)
{
  __shared__ float sV[64][33];
  __shared__ unsigned short sA[64][104];
  __shared__ float sOut[64][65];
  const int tid = threadIdx.x;
  const int p0 = blockIdx.x * 64;
  const int b = p0 >> 16;
  const int hw0 = p0 & (HW - 1);
  const int yrow = hw0 >> 8;
  const int x0b = hw0 & 255;
  {
    const int j = tid >> 3;
    const int seg = tid & 7;
    const int x0 = x0b + seg * 8;
    const unsigned short* plane = qkvl + (size_t)(b * 96 + 64 + j) * HW;
    const float* wt = qkv_dw + (64 + j) * 9;
    float w9[9];
#pragma unroll
    for (int t = 0; t < 9; ++t) w9[t] = wt[t];
    float row[3][10];
#pragma unroll
    for (int dy = 0; dy < 3; ++dy) {
      const int yy = yrow + dy - 1;
      if ((unsigned)yy >= 256u) {
#pragma unroll
        for (int k = 0; k < 10; ++k) row[dy][k] = 0.f;
        continue;
      }
      const unsigned short* rp = plane + yy * 256;
      union { short8v v; unsigned short s[8]; } cu;
      cu.v = *reinterpret_cast<const short8v*>(rp + x0);
#pragma unroll
      for (int k = 0; k < 8; ++k) row[dy][k + 1] = bf2f(cu.s[k]);
      row[dy][0] = (x0 > 0) ? bf2f(rp[x0 - 1]) : 0.f;
      row[dy][9] = (x0 < 248) ? bf2f(rp[x0 + 8]) : 0.f;
    }
#pragma unroll
    for (int p = 0; p < 8; ++p) {
      float s = 0.f;
#pragma unroll
      for (int dy = 0; dy < 3; ++dy)
#pragma unroll
        for (int dx = 0; dx < 3; ++dx)
          s += row[dy][p + dx] * w9[dy * 3 + dx];
      sV[seg * 8 + p][j] = s;
    }
  }
  __syncthreads();
  const int px_l = tid & 63, q = tid >> 6;
  const int hw = hw0 + px_l;
  const float* cw = cwbuf + b * 32;
  const float* A = Abuf + b * 256;
  union { short8v v; unsigned short s[8]; } lv, pvv;
  lv.v = *reinterpret_cast<const short8v*>(LOCB + ((size_t)b * HW + hw) * 32 + q * 8);
  pvv.v = *reinterpret_cast<const short8v*>(PREB + ((size_t)b * HW + hw) * 32 + q * 8);
  float pre8[8];
#pragma unroll
  for (int j = 0; j < 8; ++j) pre8[j] = bf2f(pvv.s[j]);
  union { short8v v; unsigned short s[8]; } mxv;
#pragma unroll
  for (int g2 = 0; g2 < 2; ++g2) {
    const int g = 2 * q + g2;
    float xa[4];
    float sdot = spb[g];
#pragma unroll
    for (int c = 0; c < 4; ++c) {
      xa[c] = pre8[g2 * 4 + c] * cw[g * 4 + c];
      sdot += xa[c] * spw[g * 4 + c];
    }
    float sgv = sigm(sdot);
    float thr = thrbuf[b * 8 + g] * (1.f / (4.f * 65536.f));
#pragma unroll
    for (int c = 0; c < 4; ++c) {
      float resp = sigm(xa[c] * sgv);
      float m = (resp > thr) ? 1.f : resp;
      mxv.s[g2 * 4 + c] = f2bf(pre8[g2 * 4 + c] * m);
    }
  }
  float v8[8];
#pragma unroll
  for (int j = 0; j < 8; ++j) v8[j] = sV[px_l][q * 8 + j];
  union { short8v v; unsigned short s[8]; } attv;
#pragma unroll
  for (int j = 0; j < 8; ++j) {
    float s = 0.f;
#pragma unroll
    for (int d = 0; d < 8; ++d) s += A[(q * 8 + j) * 8 + d] * v8[d];
    attv.s[j] = f2bf(s);
  }
  *reinterpret_cast<short8v*>(&sA[px_l][q * 8]) = attv.v;
  *reinterpret_cast<short8v*>(&sA[px_l][32 + q * 8]) = mxv.v;
  *reinterpret_cast<short8v*>(&sA[px_l][64 + q * 8]) = lv.v;
  __syncthreads();
  const int w = q, lane = tid & 63;
  const int col = lane & 15, kgrp = lane >> 4;
  const int og = w * 16 + col;
  f32x4 acc[4];
#pragma unroll
  for (int s = 0; s < 4; ++s) acc[s] = (f32x4){0.f, 0.f, 0.f, 0.f};
#pragma unroll
  for (int kk = 0; kk < 3; ++kk) {
    const int c0 = kk * 32 + kgrp * 8;
    union { short8v v; unsigned short s[8]; } bw;
    bw.v = *reinterpret_cast<const short8v*>(wb96 + og * 96 + c0);
#pragma unroll
    for (int s = 0; s < 4; ++s) {
      short8v av = *reinterpret_cast<const short8v*>(&sA[s * 16 + col][c0]);
      acc[s] = __builtin_amdgcn_mfma_f32_16x16x32_bf16(av, bw.v, acc[s], 0, 0, 0);
    }
  }
#pragma unroll
  for (int s = 0; s < 4; ++s) {
#pragma unroll
    for (int r = 0; r < 4; ++r) {
      int pxl = s * 16 + kgrp * 4 + r;
      sOut[og][pxl] = acc[s][r];
    }
  }
  __syncthreads();
  const float* xb = x + (size_t)(b * 64) * HW + hw0;
  float* db = dout + (size_t)(b * 64) * HW + hw0;
#pragma unroll
  for (int i = 0; i < 16; ++i) {
    int idx = tid + i * 256;
    int o = idx >> 6, px = idx & 63;
    db[(size_t)o * HW + px] = sOut[o][px] + cb[o] + xb[(size_t)o * HW + px];
  }
}

// ---------------- K5 (MFMA): LN2 + ffn_in (64->256), bf16 weight table on identity path ----------------
__global__ __launch_bounds__(256) void k5_mfma(
    const float* __restrict__ ln2_w, const float* __restrict__ ln2_b,
    const float* __restrict__ ffn_in_w, const unsigned short* __restrict__ wf5,
    const float* __restrict__ flag, const float* __restrict__ dout,
    unsigned short* __restrict__ Tb, int b)
{
  __shared__ float sShared[4352];            // sStage (fp32), later reused as sOutB (bf16, 128 rows)
  __shared__ unsigned short sXnb[64][68];
  __shared__ float sMu[64], sRs[64];
  float (*sStage)[65] = reinterpret_cast<float(*)[65]>(sShared);
  unsigned short (*sOutB)[68] = reinterpret_cast<unsigned short(*)[68]>(sShared);
  const int tid = threadIdx.x;
  const int px0 = blockIdx.x * 64;
  const bool idf = flag[0] > 0.5f;
  const float* db = dout + (size_t)(b * 64) * HW + px0;
#pragma unroll
  for (int i = 0; i < 4; ++i) {
    int idx = tid + i * 256;                 // 0..1023
    int c = idx >> 4, px4 = (idx & 15) * 4;
    float4 v = *reinterpret_cast<const float4*>(db + (size_t)c * HW + px4);
    sStage[px4][c] = v.x;
    sStage[px4 + 1][c] = v.y;
    sStage[px4 + 2][c] = v.z;
    sStage[px4 + 3][c] = v.w;
  }
  __syncthreads();
  if (tid < 64) {
    float mu = 0.f;
#pragma unroll
    for (int c = 0; c < 64; ++c) mu += sStage[tid][c];
    mu *= (1.f / 64.f);
    float var = 0.f;
#pragma unroll
    for (int c = 0; c < 64; ++c) { float d = sStage[tid][c] - mu; var += d * d; }
    var *= (1.f / 64.f);
    sMu[tid] = mu;
    sRs[tid] = rsqrtf(var + 1e-5f);
  }
  __syncthreads();
#pragma unroll
  for (int i = 0; i < 16; ++i) {
    int idx = tid + i * 256;
    int px = idx >> 6, c = idx & 63;
    float xn = (sStage[px][c] - sMu[px]) * sRs[px] * ln2_w[c] + ln2_b[c];
    sXnb[px][c] = f2bf(xn);
  }
  __syncthreads();   // sStage dead; sOutB takes over the region
  const int w = tid >> 6, lane = tid & 63;
  const int col = lane & 15, kgrp = lane >> 4;
#pragma unroll
  for (int mp = 0; mp < 2; ++mp) {
#pragma unroll
    for (int pass = 0; pass < 2; ++pass) {
      const int o_l = pass * 64 + w * 16 + col;   // 0..127 within macro-pass
      const int og = mp * 128 + o_l;
      f32x4 acc[4];
#pragma unroll
      for (int s = 0; s < 4; ++s) acc[s] = (f32x4){0.f, 0.f, 0.f, 0.f};
#pragma unroll
      for (int kk = 0; kk < 2; ++kk) {
        const int c0 = kk * 32 + kgrp * 8;
        union { short8v v; unsigned short s[8]; } bw;
        if (idf) {
          bw.v = *reinterpret_cast<const short8v*>(wf5 + (size_t)og * 64 + c0);
        } else {
          const float* wp = ffn_in_w + (size_t)og * 64 + c0;
#pragma unroll
          for (int j = 0; j < 8; ++j) bw.s[j] = f2bf(wp[j]);
        }
#pragma unroll
        for (int s = 0; s < 4; ++s) {
          short8v av = *reinterpret_cast<const short8v*>(&sXnb[s * 16 + col][c0]);
          acc[s] = __builtin_amdgcn_mfma_f32_16x16x32_bf16(av, bw.v, acc[s], 0, 0, 0);
        }
      }
#pragma unroll
      for (int s = 0; s < 4; ++s) {
#pragma unroll
        for (int r = 0; r < 4; ++r) {
          int px_l = s * 16 + kgrp * 4 + r;
          sOutB[o_l][px_l] = f2bf(acc[s][r]);
        }
      }
    }
    __syncthreads();
    for (int i = tid; i < 1024; i += 256) {
      int o = i >> 3, seg = i & 7;
      *reinterpret_cast<short8v*>(Tb + (size_t)(mp * 128 + o) * HW + px0 + seg * 8) =
          *reinterpret_cast<const short8v*>(&sOutB[o][seg * 8]);
    }
    __syncthreads();   // before next macro-pass overwrites sOutB
  }
}

// ---------------- K6a: dwconv3/dwconv5 + gelu*mul -> Y (bf16), 1 ch x 2 rows per thread ----------------
__global__ __launch_bounds__(256) void k6a_dw(
    const float* __restrict__ dw3_w, const float* __restrict__ dw5_w,
    const unsigned short* __restrict__ T, unsigned short* __restrict__ Y)
{
  const int idx = blockIdx.x * 256 + threadIdx.x;  // 524288 threads (grid 2048)
  const int j = idx >> 12;          // channel 0..127 (wave-uniform)
  const int rem = idx & 4095;
  const int y0 = (rem >> 5) * 2;    // output row pair base 0,2,..,254
  const int x0 = (rem & 31) * 8;    // col start, multiple of 8
  float m[2][8];
  const unsigned short* pm = T + (size_t)(128 + j) * HW;
  if (j < 64) {
    const float* wt = dw3_w + (128 + j) * 9;
    float w9[9];
#pragma unroll
    for (int t = 0; t < 9; ++t) w9[t] = wt[t];
    float row[4][10];
#pragma unroll
    for (int r = 0; r < 4; ++r) {
      const int yy = y0 + r - 1;
      if ((unsigned)yy >= 256u) {
#pragma unroll
        for (int k = 0; k < 10; ++k) row[r][k] = 0.f;
        continue;
      }
      const unsigned short* rp = pm + yy * 256;
      union { short8v v; unsigned short s[8]; } cu;
      cu.v = *reinterpret_cast<const short8v*>(rp + x0);
#pragma unroll
      for (int k = 0; k < 8; ++k) row[r][k + 1] = bf2f(cu.s[k]);
      row[r][0] = (x0 > 0) ? bf2f(rp[x0 - 1]) : 0.f;
      row[r][9] = (x0 < 248) ? bf2f(rp[x0 + 8]) : 0.f;
    }
#pragma unroll
    for (int t = 0; t < 2; ++t)
#pragma unroll
      for (int p = 0; p < 8; ++p) {
        float s = 0.f;
#pragma unroll
        for (int dy = 0; dy < 3; ++dy)
#pragma unroll
          for (int dx = 0; dx < 3; ++dx)
            s += row[t + dy][p + dx] * w9[dy * 3 + dx];
        m[t][p] = s;
      }
  } else {
    const float* wt = dw5_w + (j - 64) * 25;
    float w25[25];
#pragma unroll
    for (int t = 0; t < 25; ++t) w25[t] = wt[t];
    float row[6][12];
#pragma unroll
    for (int r = 0; r < 6; ++r) {
      const int yy = y0 + r - 2;
      if ((unsigned)yy >= 256u) {
#pragma unroll
        for (int k = 0; k < 12; ++k) row[r][k] = 0.f;
        continue;
      }
      const unsigned short* rp = pm + yy * 256;
      union { short8v v; unsigned short s[8]; } cu;
      cu.v = *reinterpret_cast<const short8v*>(rp + x0);
#pragma unroll
      for (int k = 0; k < 8; ++k) row[r][k + 2] = bf2f(cu.s[k]);
      row[r][0] = (x0 > 0) ? bf2f(rp[x0 - 2]) : 0.f;
      row[r][1] = (x0 > 0) ? bf2f(rp[x0 - 1]) : 0.f;
      row[r][10] = (x0 < 248) ? bf2f(rp[x0 + 8]) : 0.f;
      row[r][11] = (x0 < 248) ? bf2f(rp[x0 + 9]) : 0.f;
    }
#pragma unroll
    for (int t = 0; t < 2; ++t)
#pragma unroll
      for (int p = 0; p < 8; ++p) {
        float s = 0.f;
#pragma unroll
        for (int dy = 0; dy < 5; ++dy)
#pragma unroll
          for (int dx = 0; dx < 5; ++dx)
            s += row[t + dy][p + dx] * w25[dy * 5 + dx];
        m[t][p] = s;
      }
  }
  float a[2][8];
  {
    const unsigned short* pa = T + (size_t)j * HW;
    const float* wt = dw3_w + j * 9;
    float w9[9];
#pragma unroll
    for (int t = 0; t < 9; ++t) w9[t] = wt[t];
    float row[4][10];
#pragma unroll
    for (int r = 0; r < 4; ++r) {
      const int yy = y0 + r - 1;
      if ((unsigned)yy >= 256u) {
#pragma unroll
        for (int k = 0; k < 10; ++k) row[r][k] = 0.f;
        continue;
      }
      const unsigned short* rp = pa + yy * 256;
      union { short8v v; unsigned short s[8]; } cu;
      cu.v = *reinterpret_cast<const short8v*>(rp + x0);
#pragma unroll
      for (int k = 0; k < 8; ++k) row[r][k + 1] = bf2f(cu.s[k]);
      row[r][0] = (x0 > 0) ? bf2f(rp[x0 - 1]) : 0.f;
      row[r][9] = (x0 < 248) ? bf2f(rp[x0 + 8]) : 0.f;
    }
#pragma unroll
    for (int t = 0; t < 2; ++t)
#pragma unroll
      for (int p = 0; p < 8; ++p) {
        float s = 0.f;
#pragma unroll
        for (int dy = 0; dy < 3; ++dy)
#pragma unroll
          for (int dx = 0; dx < 3; ++dx)
            s += row[t + dy][p + dx] * w9[dy * 3 + dx];
        a[t][p] = s;
      }
  }
#pragma unroll
  for (int t = 0; t < 2; ++t) {
    union { short8v v; unsigned short s[8]; } out;
#pragma unroll
    for (int p = 0; p < 8; ++p) {
      float gl = 0.5f * a[t][p] * (1.f + erff(a[t][p] * 0.70710678118654752f));
      out.s[p] = f2bf(gl * m[t][p]);
    }
    *reinterpret_cast<short8v*>(Y + (size_t)j * HW + (y0 + t) * 256 + x0) = out.v;
  }
}

// ---------------- K6b (MFMA): ffn_out (128->64), Y staged once in LDS, K=128 ----------------
__global__ __launch_bounds__(256) void k6b_mfma(
    const float* __restrict__ ffn_out_w, const unsigned short* __restrict__ wf6,
    const unsigned short* __restrict__ Y,
    const float* __restrict__ flag, float* __restrict__ dout, float* __restrict__ Z, int b)
{
  __shared__ unsigned short sY[64][136];   // 17.4 KB [px][128ch]
  __shared__ float sOut[64][65];           // 16.6 KB
  const int tid = threadIdx.x;
  const int px0 = blockIdx.x * 64;
  const bool idf = flag[0] > 0.5f;
#pragma unroll
  for (int i = 0; i < 4; ++i) {
    const int t = tid + i * 256;
    const int ch = t >> 3, seg = t & 7;
    union { short8v v; unsigned short s[8]; } u;
    u.v = *reinterpret_cast<const short8v*>(Y + (size_t)ch * HW + px0 + seg * 8);
#pragma unroll
    for (int p = 0; p < 8; ++p) sY[seg * 8 + p][ch] = u.s[p];
  }
  __syncthreads();
  const int w = tid >> 6, lane = tid & 63;
  const int col = lane & 15, kgrp = lane >> 4;
  const int og = w * 16 + col;               // 0..63
  f32x4 acc[4];
#pragma unroll
  for (int s = 0; s < 4; ++s) acc[s] = (f32x4){0.f, 0.f, 0.f, 0.f};
#pragma unroll
  for (int kk = 0; kk < 4; ++kk) {
    const int c0 = kk * 32 + kgrp * 8;
    union { short8v v; unsigned short s[8]; } bw;
    if (idf) {
      bw.v = *reinterpret_cast<const short8v*>(wf6 + (size_t)og * 128 + c0);
    } else {
      const float* wp = ffn_out_w + (size_t)og * 128 + c0;
#pragma unroll
      for (int j = 0; j < 8; ++j) bw.s[j] = f2bf(wp[j]);
    }
#pragma unroll
    for (int s = 0; s < 4; ++s) {
      short8v av = *reinterpret_cast<const short8v*>(&sY[s * 16 + col][c0]);
      acc[s] = __builtin_amdgcn_mfma_f32_16x16x32_bf16(av, bw.v, acc[s], 0, 0, 0);
    }
  }
#pragma unroll
  for (int s = 0; s < 4; ++s) {
#pragma unroll
    for (int r = 0; r < 4; ++r) {
      int pxl = s * 16 + kgrp * 4 + r;
      sOut[og][pxl] = acc[s][r];
    }
  }
  __syncthreads();
  if (idf) {
    float* db = dout + (size_t)(b * 64) * HW + px0;
#pragma unroll
    for (int i = 0; i < 16; ++i) {
      int idx = tid + i * 256;
      int o = idx >> 6, px = idx & 63;
      db[(size_t)o * HW + px] += sOut[o][px];
    }
  } else {
    float* zb = Z + px0;
#pragma unroll
    for (int i = 0; i < 16; ++i) {
      int idx = tid + i * 256;
      int o = idx >> 6, px = idx & 63;
      zb[(size_t)o * HW + px] = sOut[o][px];
    }
  }
}

// ---------------- K7: general fft path, 8 patch-groups per block (early-exit if identity) ----------------
__global__ __launch_bounds__(256) void k7_fft(
    const float* __restrict__ fftw, const float* __restrict__ flag,
    const float* __restrict__ Z, float* __restrict__ dout, int b)
{
  if (flag[0] > 0.5f) return;
  __shared__ float swv[64];
  __shared__ float spatch[4][64];
  const int tid = threadIdx.x;
  const int c = blockIdx.x >> 5;        // channel 0..63 (grid 2048)
  const int pblk0 = (blockIdx.x & 31) * 8;
  if (tid < 64) swv[tid] = fftw[c * 64 + tid];
  const int lp = tid >> 6, e = tid & 63;
  const int i = e >> 3, jj = e & 7;
  for (int pg = 0; pg < 8; ++pg) {
    const int patch = (pblk0 + pg) * 4 + lp;
    const int pi = patch >> 5, pj = patch & 31;
    const int gidx = (pi * 8 + i) * 256 + pj * 8 + jj;
    const float zv = Z[(size_t)c * HW + gidx];
    spatch[lp][e] = zv;
    __syncthreads();
    float s = 0.f;
#pragma unroll
    for (int a = 0; a < 8; ++a)
#pragma unroll
      for (int b2 = 0; b2 < 8; ++b2)
        s += swv[a * 8 + b2] * spatch[lp][((i - a) & 7) * 8 + ((jj - b2) & 7)];
    dout[(size_t)(b * 64 + c) * HW + gidx] += s;
    __syncthreads();
  }
}

extern "C" void kernel_launch(void* const* d_in, const int* in_sizes, int n_in,
                              void* d_out, int out_size, void* d_ws, size_t ws_size,
                              hipStream_t stream) {
  const float* x          = (const float*)d_in[0];
  const float* ln1_w      = (const float*)d_in[1];
  const float* ln1_b      = (const float*)d_in[2];
  const float* in_proj_w  = (const float*)d_in[3];
  const float* qkv_w      = (const float*)d_in[4];
  const float* qkv_dw     = (const float*)d_in[5];
  const float* out_proj_w = (const float*)d_in[6];
  const float* temperature= (const float*)d_in[7];
  const float* attn_scales= (const float*)d_in[8];
  const float* gate_w1    = (const float*)d_in[9];
  const float* gate_b1    = (const float*)d_in[10];
  const float* gate_w2    = (const float*)d_in[11];
  const float* gate_b2    = (const float*)d_in[12];
  const float* lgce_pre_w = (const float*)d_in[13];
  const float* lgce_pre_b = (const float*)d_in[14];
  const float* lgce_post_w= (const float*)d_in[15];
  const float* lgce_post_b= (const float*)d_in[16];
  const float* cbam_m1w   = (const float*)d_in[17];
  const float* cbam_m1b   = (const float*)d_in[18];
  const float* cbam_m2w   = (const float*)d_in[19];
  const float* cbam_m2b   = (const float*)d_in[20];
  const float* cbam_spw   = (const float*)d_in[21];
  const float* cbam_spb   = (const float*)d_in[22];
  const float* ln2_w      = (const float*)d_in[23];
  const float* ln2_b      = (const float*)d_in[24];
  const float* ffn_in_w   = (const float*)d_in[25];
  const float* dw3_w      = (const float*)d_in[26];
  const float* dw5_w      = (const float*)d_in[27];
  const float* ffn_out_w  = (const float*)d_in[28];
  const float* fft_W      = (const float*)d_in[29];
  float* ws = (float*)d_ws;
  float* out = (float*)d_out;
  unsigned short* qkvlp = (unsigned short*)(ws + OFF_QKVL);
  unsigned short* LOCB = (unsigned short*)(ws + OFF_LOCB);
  unsigned short* PREB = (unsigned short*)(ws + OFF_PREB);
  unsigned short* Tb = (unsigned short*)(ws + OFF_T);
  unsigned short* Ybuf = (unsigned short*)(ws + OFF_Y);

  hipLaunchKernelGGL(k0_par, dim3(15), dim3(256), 0, stream,
                     fft_W, in_proj_w, qkv_w, gate_w1, lgce_pre_w,
                     out_proj_w, lgce_post_w, lgce_post_b, ws);
  hipLaunchKernelGGL(k0b_tables, dim3(164), dim3(256), 0, stream,
                     in_proj_w, ffn_in_w, ffn_out_w, ws);
  hipLaunchKernelGGL(k1_mfma, dim3(2048), dim3(256), 0, stream,
                     x, ln1_w, ln1_b, (unsigned short*)(ws + OFF_WK1), lgce_pre_b,
                     gate_b1, gate_w2, gate_b2,
                     qkvlp, LOCB, PREB, ws + OFF_POOL, ws + OFF_GSUM);
  hipLaunchKernelGGL(k1_check, dim3(256), dim3(256), 0, stream,
                     x, ln1_w, ln1_b, in_proj_w, qkv_w, lgce_pre_w, lgce_pre_b,
                     LOCB, qkvlp, PREB, ws + OFF_BAD);
  hipLaunchKernelGGL(k1r_reset, dim3(1), dim3(256), 0, stream,
                     ws + OFF_BAD, ws + OFF_GSUM);
  hipLaunchKernelGGL(k1_fb, dim3(1024), dim3(256), 0, stream,
                     x, ln1_w, ln1_b, in_proj_w, qkv_w, lgce_pre_w, lgce_pre_b,
                     gate_w1, gate_b1, gate_w2, gate_b2,
                     ws + OFF_BAD, qkvlp, LOCB, PREB, ws + OFF_POOL, ws + OFF_GSUM);
  hipLaunchKernelGGL(k2_mfma, dim3(128, 4, 4), dim3(256), 0, stream,
                     qkvlp, qkv_dw, ws + OFF_GRAM);
  hipLaunchKernelGGL(k3_final, dim3(1), dim3(256), 0, stream,
                     cbam_m1w, cbam_m1b, cbam_m2w, cbam_m2b, temperature, attn_scales,
                     lgce_pre_w, lgce_pre_b,
                     ws + OFF_GSUM, ws + OFF_POOL, ws + OFF_GRAM, ws + OFF_A, ws + OFF_CW);
  hipLaunchKernelGGL(k4a_thr, dim3(2048), dim3(256), 0, stream,
                     cbam_spw, cbam_spb, ws + OFF_CW, PREB, ws + OFF_PART);
  hipLaunchKernelGGL(k4a_red, dim3(32), dim3(256), 0, stream,
                     ws + OFF_PART, ws + OFF_THR);
  hipLaunchKernelGGL(k4b_fuse, dim3(4096), dim3(256), 0, stream,
                     x, cbam_spw, cbam_spb, qkv_dw, qkvlp, LOCB, PREB,
                     ws + OFF_A, ws + OFF_CW, ws + OFF_THR,
                     (unsigned short*)(ws + OFF_WB96), ws + OFF_CB, out);

  for (int b = 0; b < 4; ++b) {
    hipLaunchKernelGGL(k5_mfma, dim3(1024), dim3(256), 0, stream,
                       ln2_w, ln2_b, ffn_in_w, (unsigned short*)(ws + OFF_WF5),
                       ws + OFF_FLAG, out, Tb, b);
    hipLaunchKernelGGL(k6a_dw, dim3(2048), dim3(256), 0, stream,
                       dw3_w, dw5_w, Tb, Ybuf);
    hipLaunchKernelGGL(k6b_mfma, dim3(1024), dim3(256), 0, stream,
                       ffn_out_w, (unsigned short*)(ws + OFF_WF6), Ybuf,
                       ws + OFF_FLAG, out, ws + OFF_Z, b);
    hipLaunchKernelGGL(k7_fft, dim3(2048), dim3(256), 0, stream,
                       ws + OFF_FFTW, ws + OFF_FLAG, ws + OFF_Z, out, b);
  }
}